// Round 1
// baseline (625.041 us; speedup 1.0000x reference)
//
#include <hip/hip_runtime.h>
#include <cstdint>
#include <cstddef>

// ---------------------------------------------------------------------------
// GATv2 3-layer forward on MI355X.
// Structure per layer:
//   k_gemm  : xlr[N,512] = [x@Wl+bl | x@Wr+br]      (fp32 SGEMM, 128x128 tile)
//   k_edge  : fused per-dst-node online-softmax aggregation + bias + ELU
// Graph CSR (dst-sorted incoming edges) built once, reused for all layers.
// Layer 3 (heads=1, out=2) uses skinny kernels + fused log_softmax.
// ---------------------------------------------------------------------------

__device__ __forceinline__ float lrelu(float v) { return v >= 0.f ? v : 0.2f * v; }
__device__ __forceinline__ float elu1(float v)  { return v > 0.f ? v : expm1f(v); }

// ---------------- CSR build ----------------

__global__ void k_count(const int* __restrict__ dst, int* __restrict__ deg, int E) {
  int e = blockIdx.x * blockDim.x + threadIdx.x;
  if (e < E) atomicAdd(&deg[dst[e]], 1);
}

__global__ __launch_bounds__(1024) void k_scan(const int* __restrict__ deg,
                                               int* __restrict__ offs,
                                               int* __restrict__ cursor, int n) {
  __shared__ int part[1024];
  int t = threadIdx.x;
  int CH = (n + 1023) >> 10;
  int s = 0;
  for (int i = 0; i < CH; ++i) {
    int idx = t * CH + i;
    if (idx < n) s += deg[idx];
  }
  part[t] = s;
  __syncthreads();
  // Hillis-Steele inclusive scan over 1024 partials
  for (int off = 1; off < 1024; off <<= 1) {
    int v = (t >= off) ? part[t - off] : 0;
    __syncthreads();
    part[t] += v;
    __syncthreads();
  }
  int run = (t == 0) ? 0 : part[t - 1];
  for (int i = 0; i < CH; ++i) {
    int idx = t * CH + i;
    if (idx < n) { offs[idx] = run; cursor[idx] = run; run += deg[idx]; }
  }
  if (t == 0) offs[n] = part[1023];
}

__global__ void k_scatter(const int* __restrict__ src, const int* __restrict__ dst,
                          int* __restrict__ cursor, int* __restrict__ csr_src, int E) {
  int e = blockIdx.x * blockDim.x + threadIdx.x;
  if (e < E) {
    int pos = atomicAdd(&cursor[dst[e]], 1);
    csr_src[pos] = src[e];
  }
}

// ---------------- SGEMM: C[M,512] = A[M,K] @ [Wl|Wr][K,512] + [bl|br] -------

__global__ __launch_bounds__(256) void k_gemm(
    const float* __restrict__ A, int M, int K,
    const float* __restrict__ Wl, const float* __restrict__ Wr,
    const float* __restrict__ bl, const float* __restrict__ br,
    float* __restrict__ C) {
  __shared__ float As[16][128];  // transposed: As[k][m]
  __shared__ float Bs[16][128];
  int bm = blockIdx.x * 128;
  int bn = blockIdx.y * 128;  // 0,128,256,384
  int tid = threadIdx.x;
  int tx = tid & 15, ty = tid >> 4;
  const float* W = (bn < 256) ? Wl : Wr;
  const float* bias = (bn < 256) ? bl : br;
  int wn = bn & 255;

  float acc[8][8];
#pragma unroll
  for (int i = 0; i < 8; ++i)
#pragma unroll
    for (int j = 0; j < 8; ++j) acc[i][j] = 0.f;

  int ar = tid >> 2, ac = (tid & 3) << 2;   // A-load: row ar(+64), cols ac..ac+3
  int kb = tid >> 4, cb = (tid & 15) << 3;  // B-load: row kb, cols cb..cb+7

  for (int k0 = 0; k0 < K; k0 += 16) {
#pragma unroll
    for (int half = 0; half < 2; ++half) {
      int row = bm + ar + half * 64;
      float4 a4 = make_float4(0.f, 0.f, 0.f, 0.f);
      if (row < M) a4 = *(const float4*)&A[(size_t)row * K + k0 + ac];
      As[ac + 0][ar + half * 64] = a4.x;
      As[ac + 1][ar + half * 64] = a4.y;
      As[ac + 2][ar + half * 64] = a4.z;
      As[ac + 3][ar + half * 64] = a4.w;
    }
    {
      const float* bp = &W[(size_t)(k0 + kb) * 256 + wn + cb];
      float4 b0 = *(const float4*)bp;
      float4 b1 = *(const float4*)(bp + 4);
      *(float4*)&Bs[kb][cb] = b0;
      *(float4*)&Bs[kb][cb + 4] = b1;
    }
    __syncthreads();
#pragma unroll
    for (int k = 0; k < 16; ++k) {
      float a[8], b[8];
      *(float4*)&a[0] = *(const float4*)&As[k][ty * 8];
      *(float4*)&a[4] = *(const float4*)&As[k][ty * 8 + 4];
      *(float4*)&b[0] = *(const float4*)&Bs[k][tx * 8];
      *(float4*)&b[4] = *(const float4*)&Bs[k][tx * 8 + 4];
#pragma unroll
      for (int i = 0; i < 8; ++i)
#pragma unroll
        for (int j = 0; j < 8; ++j) acc[i][j] = fmaf(a[i], b[j], acc[i][j]);
    }
    __syncthreads();
  }

#pragma unroll
  for (int i = 0; i < 8; ++i) {
    int row = bm + ty * 8 + i;
    if (row < M) {
#pragma unroll
      for (int j = 0; j < 8; j += 4) {
        float4 o;
        o.x = acc[i][j + 0] + bias[wn + tx * 8 + j + 0];
        o.y = acc[i][j + 1] + bias[wn + tx * 8 + j + 1];
        o.z = acc[i][j + 2] + bias[wn + tx * 8 + j + 2];
        o.w = acc[i][j + 3] + bias[wn + tx * 8 + j + 3];
        *(float4*)&C[(size_t)row * 512 + bn + tx * 8 + j] = o;
      }
    }
  }
}

// ---------------- fused GATv2 edge pass (H=8, C=32), wave per dst node ------
// Online softmax per head: running max m, denom d, rescaled accumulator.
// Lane l holds hid elements 4l..4l+3, all within head h = l>>3.

__global__ __launch_bounds__(256) void k_edge(
    const float* __restrict__ xlr,   // [N,512] = [xl | xr]
    const int* __restrict__ offs, const int* __restrict__ csr_src,
    const float* __restrict__ att,   // [8*32]
    const float* __restrict__ bias,  // [256]
    float* __restrict__ hout,        // [N,256]
    int n) {
  int lane = threadIdx.x & 63;
  int node = blockIdx.x * (blockDim.x >> 6) + (threadIdx.x >> 6);
  if (node >= n) return;

  float4 att4 = *(const float4*)&att[lane * 4];
  float4 xr4  = *(const float4*)&xlr[(size_t)node * 512 + 256 + lane * 4];

  float m = -INFINITY, d = 0.f;
  float ax = 0.f, ay = 0.f, az = 0.f, aw = 0.f;

  int e0 = offs[node], e1 = offs[node + 1];
  for (int e = e0 - 1; e < e1; ++e) {
    int j = (e < e0) ? node : csr_src[e];  // self-loop first
    float4 xl4 = *(const float4*)&xlr[(size_t)j * 512 + lane * 4];
    float p = lrelu(xl4.x + xr4.x) * att4.x
            + lrelu(xl4.y + xr4.y) * att4.y
            + lrelu(xl4.z + xr4.z) * att4.z
            + lrelu(xl4.w + xr4.w) * att4.w;
    p += __shfl_xor(p, 1);
    p += __shfl_xor(p, 2);
    p += __shfl_xor(p, 4);  // per-head score, replicated over the 8-lane group
    if (p <= m) {
      float w = __expf(p - m);
      d += w;
      ax = fmaf(w, xl4.x, ax); ay = fmaf(w, xl4.y, ay);
      az = fmaf(w, xl4.z, az); aw = fmaf(w, xl4.w, aw);
    } else {
      float r = __expf(m - p);  // first edge: m=-inf -> r=0
      d = fmaf(d, r, 1.f);
      ax = fmaf(ax, r, xl4.x); ay = fmaf(ay, r, xl4.y);
      az = fmaf(az, r, xl4.z); aw = fmaf(aw, r, xl4.w);
      m = p;
    }
  }
  float inv = 1.f / (d + 1e-16f);
  float4 b4 = *(const float4*)&bias[lane * 4];
  float4 o;
  o.x = elu1(fmaf(ax, inv, b4.x));
  o.y = elu1(fmaf(ay, inv, b4.y));
  o.z = elu1(fmaf(az, inv, b4.z));
  o.w = elu1(fmaf(aw, inv, b4.w));
  *(float4*)&hout[(size_t)node * 256 + lane * 4] = o;
}

// ---------------- layer 3: skinny linear (256->2 twice), wave per node ------

__global__ __launch_bounds__(256) void k_lin3(
    const float* __restrict__ h,  // [N,256]
    const float* __restrict__ Wl, const float* __restrict__ bl,
    const float* __restrict__ Wr, const float* __restrict__ br,
    float* __restrict__ xlr3,  // [N,4] = {xl0,xl1,xr0,xr1}
    int n) {
  int lane = threadIdx.x & 63;
  int node = blockIdx.x * (blockDim.x >> 6) + (threadIdx.x >> 6);
  if (node >= n) return;
  float4 h4 = *(const float4*)&h[(size_t)node * 256 + lane * 4];
  float hv[4] = {h4.x, h4.y, h4.z, h4.w};
  float al0 = 0.f, al1 = 0.f, ar0 = 0.f, ar1 = 0.f;
#pragma unroll
  for (int j = 0; j < 4; ++j) {
    int k = lane * 4 + j;
    al0 = fmaf(hv[j], Wl[k * 2 + 0], al0);
    al1 = fmaf(hv[j], Wl[k * 2 + 1], al1);
    ar0 = fmaf(hv[j], Wr[k * 2 + 0], ar0);
    ar1 = fmaf(hv[j], Wr[k * 2 + 1], ar1);
  }
#pragma unroll
  for (int s = 1; s < 64; s <<= 1) {
    al0 += __shfl_xor(al0, s);
    al1 += __shfl_xor(al1, s);
    ar0 += __shfl_xor(ar0, s);
    ar1 += __shfl_xor(ar1, s);
  }
  if (lane == 0) {
    float4 o = make_float4(al0 + bl[0], al1 + bl[1], ar0 + br[0], ar1 + br[1]);
    *(float4*)&xlr3[(size_t)node * 4] = o;
  }
}

// ---------------- layer 3 edge pass + log_softmax, thread per node ----------

__global__ void k_edge3(const float* __restrict__ xlr3,
                        const int* __restrict__ offs, const int* __restrict__ csr_src,
                        const float* __restrict__ att,  // [2]
                        const float* __restrict__ b,    // [2]
                        float* __restrict__ out, int n) {
  int i = blockIdx.x * blockDim.x + threadIdx.x;
  if (i >= n) return;
  float a0 = att[0], a1 = att[1];
  float xr0 = xlr3[(size_t)i * 4 + 2], xr1 = xlr3[(size_t)i * 4 + 3];
  float m = -INFINITY, d = 0.f, ac0 = 0.f, ac1 = 0.f;
  int e0 = offs[i], e1 = offs[i + 1];
  for (int e = e0 - 1; e < e1; ++e) {
    int j = (e < e0) ? i : csr_src[e];
    float xl0 = xlr3[(size_t)j * 4 + 0], xl1 = xlr3[(size_t)j * 4 + 1];
    float p = lrelu(xl0 + xr0) * a0 + lrelu(xl1 + xr1) * a1;
    if (p <= m) {
      float w = __expf(p - m);
      d += w; ac0 = fmaf(w, xl0, ac0); ac1 = fmaf(w, xl1, ac1);
    } else {
      float r = __expf(m - p);
      d = fmaf(d, r, 1.f);
      ac0 = fmaf(ac0, r, xl0); ac1 = fmaf(ac1, r, xl1);
      m = p;
    }
  }
  float inv = 1.f / (d + 1e-16f);
  float o0 = fmaf(ac0, inv, b[0]);
  float o1 = fmaf(ac1, inv, b[1]);
  float mx = fmaxf(o0, o1);
  float lse = mx + logf(expf(o0 - mx) + expf(o1 - mx));
  out[(size_t)i * 2 + 0] = o0 - lse;
  out[(size_t)i * 2 + 1] = o1 - lse;
}

// ---------------------------------------------------------------------------

static inline size_t align_up(size_t v, size_t a) { return (v + a - 1) & ~(a - 1); }

extern "C" void kernel_launch(void* const* d_in, const int* in_sizes, int n_in,
                              void* d_out, int out_size, void* d_ws, size_t ws_size,
                              hipStream_t stream) {
  const float* x    = (const float*)d_in[0];
  const int*   ei   = (const int*)d_in[1];
  const float* Wl1  = (const float*)d_in[2];
  const float* bl1  = (const float*)d_in[3];
  const float* Wr1  = (const float*)d_in[4];
  const float* br1  = (const float*)d_in[5];
  const float* att1 = (const float*)d_in[6];
  const float* b1   = (const float*)d_in[7];
  const float* Wl3  = (const float*)d_in[8];
  const float* bl3  = (const float*)d_in[9];
  const float* Wr3  = (const float*)d_in[10];
  const float* br3  = (const float*)d_in[11];
  const float* att3 = (const float*)d_in[12];
  const float* b3   = (const float*)d_in[13];
  const float* Wl2  = (const float*)d_in[14];
  const float* bl2  = (const float*)d_in[15];
  const float* Wr2  = (const float*)d_in[16];
  const float* br2  = (const float*)d_in[17];
  const float* att2 = (const float*)d_in[18];
  const float* b2   = (const float*)d_in[19];

  const int N = in_sizes[0] / 128;  // 50000
  const int E = in_sizes[1] / 2;    // 400000
  const int* srcp = ei;
  const int* dstp = ei + E;

  // workspace layout
  char* w = (char*)d_ws;
  size_t off = 0;
  int* deg     = (int*)(w + off); off = align_up(off + (size_t)N * 4, 256);
  int* offs    = (int*)(w + off); off = align_up(off + (size_t)(N + 1) * 4, 256);
  int* cursor  = (int*)(w + off); off = align_up(off + (size_t)N * 4, 256);
  int* csr_src = (int*)(w + off); off = align_up(off + (size_t)E * 4, 256);
  float* xlr   = (float*)(w + off); off = align_up(off + (size_t)N * 512 * 4, 256);
  float* hbuf  = (float*)(w + off); off = align_up(off + (size_t)N * 256 * 4, 256);
  float* xlr3  = (float*)(w + off); off = align_up(off + (size_t)N * 4 * 4, 256);
  (void)ws_size;

  // ---- build CSR (incoming edges per dst), reused by all 3 layers ----
  hipMemsetAsync(deg, 0, (size_t)N * 4, stream);
  k_count<<<(E + 255) / 256, 256, 0, stream>>>(dstp, deg, E);
  k_scan<<<1, 1024, 0, stream>>>(deg, offs, cursor, N);
  k_scatter<<<(E + 255) / 256, 256, 0, stream>>>(srcp, dstp, cursor, csr_src, E);

  dim3 ggrid((N + 127) / 128, 4);
  int nodeBlocks = (N + 3) / 4;  // 4 waves (nodes) per 256-thread block

  // ---- layer 1: 128 -> 8x32, concat, ELU ----
  k_gemm<<<ggrid, 256, 0, stream>>>(x, N, 128, Wl1, Wr1, bl1, br1, xlr);
  k_edge<<<nodeBlocks, 256, 0, stream>>>(xlr, offs, csr_src, att1, b1, hbuf, N);

  // ---- layer 2: 256 -> 8x32, concat, ELU ----
  k_gemm<<<ggrid, 256, 0, stream>>>(hbuf, N, 256, Wl3, Wr3, bl3, br3, xlr);
  k_edge<<<nodeBlocks, 256, 0, stream>>>(xlr, offs, csr_src, att3, b3, hbuf, N);

  // ---- layer 3: 256 -> 1x2, mean(=identity), log_softmax ----
  k_lin3<<<nodeBlocks, 256, 0, stream>>>(hbuf, Wl2, bl2, Wr2, br2, xlr3, N);
  k_edge3<<<(N + 255) / 256, 256, 0, stream>>>(xlr3, offs, csr_src, att2, b2,
                                               (float*)d_out, N);
}

// Round 2
// 500.716 us; speedup vs baseline: 1.2483x; 1.2483x over previous
//
#include <hip/hip_runtime.h>
#include <cstdint>
#include <cstddef>

// ---------------------------------------------------------------------------
// GATv2 3-layer forward on MI355X.
//   k_split     : pre-split [Wl|Wr] into transposed bf16 hi/lo (W^T, [512][K])
//   k_gemm_mfma : xlr[N,512] = [x@Wl+bl | x@Wr+br] via split-bf16 3-product
//                 MFMA (16x16x32), fp32-equivalent precision at bf16 rate
//   k_edge      : fused per-dst-node online-softmax aggregation + bias + ELU
// Graph CSR built once, reused 3x. Layer 3 skinny + fused log_softmax.
// ---------------------------------------------------------------------------

typedef __attribute__((ext_vector_type(8))) short v8s;
typedef __attribute__((ext_vector_type(4))) float v4f;

__device__ __forceinline__ float lrelu(float v) { return v >= 0.f ? v : 0.2f * v; }
__device__ __forceinline__ float elu1(float v)  { return v > 0.f ? v : expm1f(v); }

__device__ __forceinline__ unsigned short f2bf(float f) {  // RTNE fp32->bf16
  unsigned int u = __float_as_uint(f);
  unsigned int r = (u + 0x7FFFu + ((u >> 16) & 1u)) >> 16;
  return (unsigned short)r;
}
__device__ __forceinline__ float bf2f(unsigned short s) {
  return __uint_as_float(((unsigned int)s) << 16);
}

// ---------------- CSR build ----------------

__global__ void k_count(const int* __restrict__ dst, int* __restrict__ deg, int E) {
  int e = blockIdx.x * blockDim.x + threadIdx.x;
  if (e < E) atomicAdd(&deg[dst[e]], 1);
}

__global__ __launch_bounds__(1024) void k_scan(const int* __restrict__ deg,
                                               int* __restrict__ offs,
                                               int* __restrict__ cursor, int n) {
  __shared__ int part[1024];
  int t = threadIdx.x;
  int CH = (n + 1023) >> 10;
  int s = 0;
  for (int i = 0; i < CH; ++i) {
    int idx = t * CH + i;
    if (idx < n) s += deg[idx];
  }
  part[t] = s;
  __syncthreads();
  for (int off = 1; off < 1024; off <<= 1) {
    int v = (t >= off) ? part[t - off] : 0;
    __syncthreads();
    part[t] += v;
    __syncthreads();
  }
  int run = (t == 0) ? 0 : part[t - 1];
  for (int i = 0; i < CH; ++i) {
    int idx = t * CH + i;
    if (idx < n) { offs[idx] = run; cursor[idx] = run; run += deg[idx]; }
  }
  if (t == 0) offs[n] = part[1023];
}

__global__ void k_scatter(const int* __restrict__ src, const int* __restrict__ dst,
                          int* __restrict__ cursor, int* __restrict__ csr_src, int E) {
  int e = blockIdx.x * blockDim.x + threadIdx.x;
  if (e < E) {
    int pos = atomicAdd(&cursor[dst[e]], 1);
    csr_src[pos] = src[e];
  }
}

// ---------------- weight pre-split: Bt[n][k] = W[k][n] as bf16 hi/lo --------

__global__ void k_split(const float* __restrict__ Wl, const float* __restrict__ Wr,
                        int K, int logK,
                        unsigned short* __restrict__ Bth,
                        unsigned short* __restrict__ Btl) {
  int idx = blockIdx.x * blockDim.x + threadIdx.x;
  if (idx >= 512 * K) return;
  int n = idx >> logK;
  int k = idx & (K - 1);
  float w = (n < 256) ? Wl[(size_t)k * 256 + n] : Wr[(size_t)k * 256 + (n - 256)];
  unsigned short h = f2bf(w);
  Bth[idx] = h;
  Btl[idx] = f2bf(w - bf2f(h));
}

// ---------------- split-bf16 MFMA GEMM: C[M,512] = A[M,K] @ Bt^T + bias -----
// Block 128x128, 4 waves (2x2), each wave 64x64 = 4x4 frags of 16x16.
// BK=32 (one MFMA-K per tile). LDS slot-XOR swizzle: slot = oct ^ ((row>>1)&3)
// makes every wave-wide ds_read/write a bijective cover of a 1KB region.

__global__ __launch_bounds__(256) void k_gemm_mfma(
    const float* __restrict__ A, int M, int K,
    const unsigned short* __restrict__ Bth, const unsigned short* __restrict__ Btl,
    const float* __restrict__ bl, const float* __restrict__ br,
    float* __restrict__ C) {
  __shared__ __align__(16) short As_hi[128 * 32];
  __shared__ __align__(16) short As_lo[128 * 32];
  __shared__ __align__(16) short Bs_hi[128 * 32];
  __shared__ __align__(16) short Bs_lo[128 * 32];

  const int tid = threadIdx.x;
  const int lane = tid & 63;
  const int wid = tid >> 6;
  const int wr = wid >> 1, wc = wid & 1;
  const int bm = blockIdx.x * 128;
  const int bn = blockIdx.y * 128;

  v4f acc[4][4];
#pragma unroll
  for (int m = 0; m < 4; ++m)
#pragma unroll
    for (int n = 0; n < 4; ++n) acc[m][n] = (v4f)(0.f);

  const int l15 = lane & 15, g = lane >> 4;

  for (int k0 = 0; k0 < K; k0 += 32) {
    // ---- stage A: fp32 -> bf16 hi/lo, swizzled LDS ----
#pragma unroll
    for (int it = 0; it < 2; ++it) {
      int task = tid + it * 256;           // 128 rows x 4 octs
      int row = task >> 2, oct = task & 3;
      int grow = bm + row;
      float f[8];
      if (grow < M) {
        const float* ap = &A[(size_t)grow * K + k0 + oct * 8];
        float4 p0 = *(const float4*)ap;
        float4 p1 = *(const float4*)(ap + 4);
        f[0] = p0.x; f[1] = p0.y; f[2] = p0.z; f[3] = p0.w;
        f[4] = p1.x; f[5] = p1.y; f[6] = p1.z; f[7] = p1.w;
      } else {
#pragma unroll
        for (int j = 0; j < 8; ++j) f[j] = 0.f;
      }
      v8s hi, lo;
#pragma unroll
      for (int j = 0; j < 8; ++j) {
        unsigned short h = f2bf(f[j]);
        hi[j] = (short)h;
        lo[j] = (short)f2bf(f[j] - bf2f(h));
      }
      int slot = oct ^ ((row >> 1) & 3);
      *(v8s*)&As_hi[row * 32 + slot * 8] = hi;
      *(v8s*)&As_lo[row * 32 + slot * 8] = lo;
    }
    // ---- stage B: pre-split bf16, swizzled LDS ----
#pragma unroll
    for (int it = 0; it < 2; ++it) {
      int task = tid + it * 256;           // 128 cols x 4 octs
      int col = task >> 2, oct = task & 3;
      int slot = oct ^ ((col >> 1) & 3);
      size_t gb = (size_t)(bn + col) * K + k0 + oct * 8;
      *(v8s*)&Bs_hi[col * 32 + slot * 8] = *(const v8s*)&Bth[gb];
      *(v8s*)&Bs_lo[col * 32 + slot * 8] = *(const v8s*)&Btl[gb];
    }
    __syncthreads();

    // ---- fragments (8 contiguous k per lane; swizzled slot) ----
    v8s ah[4], al[4], bh[4], bo[4];
#pragma unroll
    for (int m = 0; m < 4; ++m) {
      int r = wr * 64 + m * 16 + l15;
      int s = g ^ ((r >> 1) & 3);
      ah[m] = *(const v8s*)&As_hi[r * 32 + s * 8];
      al[m] = *(const v8s*)&As_lo[r * 32 + s * 8];
    }
#pragma unroll
    for (int n = 0; n < 4; ++n) {
      int c = wc * 64 + n * 16 + l15;
      int s = g ^ ((c >> 1) & 3);
      bh[n] = *(const v8s*)&Bs_hi[c * 32 + s * 8];
      bo[n] = *(const v8s*)&Bs_lo[c * 32 + s * 8];
    }
#pragma unroll
    for (int m = 0; m < 4; ++m)
#pragma unroll
      for (int n = 0; n < 4; ++n) {
        acc[m][n] = __builtin_amdgcn_mfma_f32_16x16x32_bf16(ah[m], bh[n], acc[m][n], 0, 0, 0);
        acc[m][n] = __builtin_amdgcn_mfma_f32_16x16x32_bf16(ah[m], bo[n], acc[m][n], 0, 0, 0);
        acc[m][n] = __builtin_amdgcn_mfma_f32_16x16x32_bf16(al[m], bh[n], acc[m][n], 0, 0, 0);
      }
    __syncthreads();
  }

  // ---- epilogue: + bias, fp32 store (C/D: col=lane&15, row=(lane>>4)*4+r) --
#pragma unroll
  for (int n = 0; n < 4; ++n) {
    int col = bn + wc * 64 + n * 16 + l15;
    float bv = (col < 256) ? bl[col] : br[col - 256];
#pragma unroll
    for (int m = 0; m < 4; ++m) {
      v4f fr = acc[m][n];
#pragma unroll
      for (int r = 0; r < 4; ++r) {
        int row = bm + wr * 64 + m * 16 + g * 4 + r;
        if (row < M) C[(size_t)row * 512 + col] = fr[r] + bv;
      }
    }
  }
}

// ---------------- fused GATv2 edge pass (H=8, C=32), wave per dst node ------

__global__ __launch_bounds__(256) void k_edge(
    const float* __restrict__ xlr,   // [N,512] = [xl | xr]
    const int* __restrict__ offs, const int* __restrict__ csr_src,
    const float* __restrict__ att,   // [8*32]
    const float* __restrict__ bias,  // [256]
    float* __restrict__ hout,        // [N,256]
    int n) {
  int lane = threadIdx.x & 63;
  int node = blockIdx.x * (blockDim.x >> 6) + (threadIdx.x >> 6);
  if (node >= n) return;

  float4 att4 = *(const float4*)&att[lane * 4];
  float4 xr4  = *(const float4*)&xlr[(size_t)node * 512 + 256 + lane * 4];

  float m = -INFINITY, d = 0.f;
  float ax = 0.f, ay = 0.f, az = 0.f, aw = 0.f;

  int e0 = offs[node], e1 = offs[node + 1];
  for (int e = e0 - 1; e < e1; ++e) {
    int j = (e < e0) ? node : csr_src[e];  // self-loop first
    float4 xl4 = *(const float4*)&xlr[(size_t)j * 512 + lane * 4];
    float p = lrelu(xl4.x + xr4.x) * att4.x
            + lrelu(xl4.y + xr4.y) * att4.y
            + lrelu(xl4.z + xr4.z) * att4.z
            + lrelu(xl4.w + xr4.w) * att4.w;
    p += __shfl_xor(p, 1);
    p += __shfl_xor(p, 2);
    p += __shfl_xor(p, 4);  // per-head score, replicated over the 8-lane group
    if (p <= m) {
      float w = __expf(p - m);
      d += w;
      ax = fmaf(w, xl4.x, ax); ay = fmaf(w, xl4.y, ay);
      az = fmaf(w, xl4.z, az); aw = fmaf(w, xl4.w, aw);
    } else {
      float r = __expf(m - p);  // first edge: m=-inf -> r=0
      d = fmaf(d, r, 1.f);
      ax = fmaf(ax, r, xl4.x); ay = fmaf(ay, r, xl4.y);
      az = fmaf(az, r, xl4.z); aw = fmaf(aw, r, xl4.w);
      m = p;
    }
  }
  float inv = 1.f / (d + 1e-16f);
  float4 b4 = *(const float4*)&bias[lane * 4];
  float4 o;
  o.x = elu1(fmaf(ax, inv, b4.x));
  o.y = elu1(fmaf(ay, inv, b4.y));
  o.z = elu1(fmaf(az, inv, b4.z));
  o.w = elu1(fmaf(aw, inv, b4.w));
  *(float4*)&hout[(size_t)node * 256 + lane * 4] = o;
}

// ---------------- layer 3: skinny linear (256->2 twice), wave per node ------

__global__ __launch_bounds__(256) void k_lin3(
    const float* __restrict__ h,  // [N,256]
    const float* __restrict__ Wl, const float* __restrict__ bl,
    const float* __restrict__ Wr, const float* __restrict__ br,
    float* __restrict__ xlr3,  // [N,4] = {xl0,xl1,xr0,xr1}
    int n) {
  int lane = threadIdx.x & 63;
  int node = blockIdx.x * (blockDim.x >> 6) + (threadIdx.x >> 6);
  if (node >= n) return;
  float4 h4 = *(const float4*)&h[(size_t)node * 256 + lane * 4];
  float hv[4] = {h4.x, h4.y, h4.z, h4.w};
  float al0 = 0.f, al1 = 0.f, ar0 = 0.f, ar1 = 0.f;
#pragma unroll
  for (int j = 0; j < 4; ++j) {
    int k = lane * 4 + j;
    al0 = fmaf(hv[j], Wl[k * 2 + 0], al0);
    al1 = fmaf(hv[j], Wl[k * 2 + 1], al1);
    ar0 = fmaf(hv[j], Wr[k * 2 + 0], ar0);
    ar1 = fmaf(hv[j], Wr[k * 2 + 1], ar1);
  }
#pragma unroll
  for (int s = 1; s < 64; s <<= 1) {
    al0 += __shfl_xor(al0, s);
    al1 += __shfl_xor(al1, s);
    ar0 += __shfl_xor(ar0, s);
    ar1 += __shfl_xor(ar1, s);
  }
  if (lane == 0) {
    float4 o = make_float4(al0 + bl[0], al1 + bl[1], ar0 + br[0], ar1 + br[1]);
    *(float4*)&xlr3[(size_t)node * 4] = o;
  }
}

// ---------------- layer 3 edge pass + log_softmax, thread per node ----------

__global__ void k_edge3(const float* __restrict__ xlr3,
                        const int* __restrict__ offs, const int* __restrict__ csr_src,
                        const float* __restrict__ att,  // [2]
                        const float* __restrict__ b,    // [2]
                        float* __restrict__ out, int n) {
  int i = blockIdx.x * blockDim.x + threadIdx.x;
  if (i >= n) return;
  float a0 = att[0], a1 = att[1];
  float xr0 = xlr3[(size_t)i * 4 + 2], xr1 = xlr3[(size_t)i * 4 + 3];
  float m = -INFINITY, d = 0.f, ac0 = 0.f, ac1 = 0.f;
  int e0 = offs[i], e1 = offs[i + 1];
  for (int e = e0 - 1; e < e1; ++e) {
    int j = (e < e0) ? i : csr_src[e];
    float xl0 = xlr3[(size_t)j * 4 + 0], xl1 = xlr3[(size_t)j * 4 + 1];
    float p = lrelu(xl0 + xr0) * a0 + lrelu(xl1 + xr1) * a1;
    if (p <= m) {
      float w = __expf(p - m);
      d += w; ac0 = fmaf(w, xl0, ac0); ac1 = fmaf(w, xl1, ac1);
    } else {
      float r = __expf(m - p);
      d = fmaf(d, r, 1.f);
      ac0 = fmaf(ac0, r, xl0); ac1 = fmaf(ac1, r, xl1);
      m = p;
    }
  }
  float inv = 1.f / (d + 1e-16f);
  float o0 = fmaf(ac0, inv, b[0]);
  float o1 = fmaf(ac1, inv, b[1]);
  float mx = fmaxf(o0, o1);
  float lse = mx + logf(expf(o0 - mx) + expf(o1 - mx));
  out[(size_t)i * 2 + 0] = o0 - lse;
  out[(size_t)i * 2 + 1] = o1 - lse;
}

// ---------------------------------------------------------------------------

static inline size_t align_up(size_t v, size_t a) { return (v + a - 1) & ~(a - 1); }

extern "C" void kernel_launch(void* const* d_in, const int* in_sizes, int n_in,
                              void* d_out, int out_size, void* d_ws, size_t ws_size,
                              hipStream_t stream) {
  const float* x    = (const float*)d_in[0];
  const int*   ei   = (const int*)d_in[1];
  const float* Wl1  = (const float*)d_in[2];
  const float* bl1  = (const float*)d_in[3];
  const float* Wr1  = (const float*)d_in[4];
  const float* br1  = (const float*)d_in[5];
  const float* att1 = (const float*)d_in[6];
  const float* b1   = (const float*)d_in[7];
  const float* Wl3  = (const float*)d_in[8];
  const float* bl3  = (const float*)d_in[9];
  const float* Wr3  = (const float*)d_in[10];
  const float* br3  = (const float*)d_in[11];
  const float* att3 = (const float*)d_in[12];
  const float* b3   = (const float*)d_in[13];
  const float* Wl2  = (const float*)d_in[14];
  const float* bl2  = (const float*)d_in[15];
  const float* Wr2  = (const float*)d_in[16];
  const float* br2  = (const float*)d_in[17];
  const float* att2 = (const float*)d_in[18];
  const float* b2   = (const float*)d_in[19];

  const int N = in_sizes[0] / 128;  // 50000
  const int E = in_sizes[1] / 2;    // 400000
  const int* srcp = ei;
  const int* dstp = ei + E;

  // workspace layout
  char* w = (char*)d_ws;
  size_t off = 0;
  int* deg     = (int*)(w + off); off = align_up(off + (size_t)N * 4, 256);
  int* offs    = (int*)(w + off); off = align_up(off + (size_t)(N + 1) * 4, 256);
  int* cursor  = (int*)(w + off); off = align_up(off + (size_t)N * 4, 256);
  int* csr_src = (int*)(w + off); off = align_up(off + (size_t)E * 4, 256);
  float* xlr   = (float*)(w + off); off = align_up(off + (size_t)N * 512 * 4, 256);
  float* hbuf  = (float*)(w + off); off = align_up(off + (size_t)N * 256 * 4, 256);
  float* xlr3  = (float*)(w + off); off = align_up(off + (size_t)N * 4 * 4, 256);
  unsigned short* Bt1h = (unsigned short*)(w + off); off = align_up(off + (size_t)512 * 128 * 2, 256);
  unsigned short* Bt1l = (unsigned short*)(w + off); off = align_up(off + (size_t)512 * 128 * 2, 256);
  unsigned short* Bt2h = (unsigned short*)(w + off); off = align_up(off + (size_t)512 * 256 * 2, 256);
  unsigned short* Bt2l = (unsigned short*)(w + off); off = align_up(off + (size_t)512 * 256 * 2, 256);
  (void)ws_size;

  // ---- build CSR (incoming edges per dst), reused by all 3 layers ----
  hipMemsetAsync(deg, 0, (size_t)N * 4, stream);
  k_count<<<(E + 255) / 256, 256, 0, stream>>>(dstp, deg, E);
  k_scan<<<1, 1024, 0, stream>>>(deg, offs, cursor, N);
  k_scatter<<<(E + 255) / 256, 256, 0, stream>>>(srcp, dstp, cursor, csr_src, E);

  // ---- pre-split weights into transposed bf16 hi/lo ----
  k_split<<<(512 * 128 + 255) / 256, 256, 0, stream>>>(Wl1, Wr1, 128, 7, Bt1h, Bt1l);
  k_split<<<(512 * 256 + 255) / 256, 256, 0, stream>>>(Wl3, Wr3, 256, 8, Bt2h, Bt2l);

  dim3 ggrid((N + 127) / 128, 4);
  int nodeBlocks = (N + 3) / 4;  // 4 waves (nodes) per 256-thread block

  // ---- layer 1: 128 -> 8x32, concat, ELU ----
  k_gemm_mfma<<<ggrid, 256, 0, stream>>>(x, N, 128, Bt1h, Bt1l, bl1, br1, xlr);
  k_edge<<<nodeBlocks, 256, 0, stream>>>(xlr, offs, csr_src, att1, b1, hbuf, N);

  // ---- layer 2: 256 -> 8x32, concat, ELU ----
  k_gemm_mfma<<<ggrid, 256, 0, stream>>>(hbuf, N, 256, Bt2h, Bt2l, bl3, br3, xlr);
  k_edge<<<nodeBlocks, 256, 0, stream>>>(xlr, offs, csr_src, att3, b3, hbuf, N);

  // ---- layer 3: 256 -> 1x2, mean(=identity), log_softmax ----
  k_lin3<<<nodeBlocks, 256, 0, stream>>>(hbuf, Wl2, bl2, Wr2, br2, xlr3, N);
  k_edge3<<<(N + 255) / 256, 256, 0, stream>>>(xlr3, offs, csr_src, att2, b2,
                                               (float*)d_out, N);
}

// Round 3
// 384.177 us; speedup vs baseline: 1.6270x; 1.3033x over previous
//
#include <hip/hip_runtime.h>
#include <cstdint>
#include <cstddef>

// ---------------------------------------------------------------------------
// GATv2 3-layer forward on MI355X.
//   k_split     : pre-split [Wl|Wr] into transposed bf16 hi/lo (W^T, [512][K])
//   k_gemm_mfma : xlr[N,512] = [x@Wl+bl | x@Wr+br] via split-bf16 3-product
//                 MFMA (16x16x32), fp32-equivalent precision at bf16 rate
//   k_edge      : fused per-dst-node online-softmax aggregation + bias + ELU
// Graph CSR built once (device-wide 3-phase scan), reused 3x.
// Layer 3 skinny + fused log_softmax.
// ---------------------------------------------------------------------------

typedef __attribute__((ext_vector_type(8))) short v8s;
typedef __attribute__((ext_vector_type(4))) float v4f;

__device__ __forceinline__ float lrelu(float v) { return v >= 0.f ? v : 0.2f * v; }
__device__ __forceinline__ float elu1(float v)  { return v > 0.f ? v : expm1f(v); }

__device__ __forceinline__ unsigned short f2bf(float f) {  // RTNE fp32->bf16
  unsigned int u = __float_as_uint(f);
  unsigned int r = (u + 0x7FFFu + ((u >> 16) & 1u)) >> 16;
  return (unsigned short)r;
}
__device__ __forceinline__ float bf2f(unsigned short s) {
  return __uint_as_float(((unsigned int)s) << 16);
}

// ---------------- CSR build ----------------

__global__ void k_count(const int* __restrict__ dst, int* __restrict__ deg, int E) {
  int e = blockIdx.x * blockDim.x + threadIdx.x;
  if (e < E) atomicAdd(&deg[dst[e]], 1);
}

// per-block (1024-entry) sums of deg
__global__ __launch_bounds__(256) void k_bsum(const int* __restrict__ deg, int n,
                                              int* __restrict__ bsum) {
  __shared__ int red[256];
  int t = threadIdx.x, bid = blockIdx.x;
  int i0 = bid * 1024 + t * 4;
  int s = 0;
  if (i0 + 3 < n) {
    int4 v = *(const int4*)&deg[i0];
    s = v.x + v.y + v.z + v.w;
  } else {
#pragma unroll
    for (int j = 0; j < 4; ++j)
      if (i0 + j < n) s += deg[i0 + j];
  }
  red[t] = s;
  __syncthreads();
  for (int off = 128; off > 0; off >>= 1) {
    if (t < off) red[t] += red[t + off];
    __syncthreads();
  }
  if (t == 0) bsum[bid] = red[0];
}

// exclusive offsets: base from bsum, intra-block LDS scan
__global__ __launch_bounds__(256) void k_offsets(const int* __restrict__ deg,
                                                 const int* __restrict__ bsum,
                                                 int nb, int n,
                                                 int* __restrict__ offs,
                                                 int* __restrict__ cursor) {
  __shared__ int sc[256];
  int t = threadIdx.x, bid = blockIdx.x;
  int base = 0;
  for (int b = 0; b < bid; ++b) base += bsum[b];
  int i0 = bid * 1024 + t * 4;
  int v0 = 0, v1 = 0, v2 = 0, v3 = 0;
  if (i0 + 3 < n) {
    int4 v = *(const int4*)&deg[i0];
    v0 = v.x; v1 = v.y; v2 = v.z; v3 = v.w;
  } else {
    if (i0 < n)     v0 = deg[i0];
    if (i0 + 1 < n) v1 = deg[i0 + 1];
    if (i0 + 2 < n) v2 = deg[i0 + 2];
    if (i0 + 3 < n) v3 = deg[i0 + 3];
  }
  int s = v0 + v1 + v2 + v3;
  sc[t] = s;
  __syncthreads();
  for (int off = 1; off < 256; off <<= 1) {
    int x = (t >= off) ? sc[t - off] : 0;
    __syncthreads();
    sc[t] += x;
    __syncthreads();
  }
  int run = base + sc[t] - s;
  int o0 = run, o1 = run + v0, o2 = o1 + v1, o3 = o2 + v2;
  if (i0 + 3 < n) {
    *(int4*)&offs[i0] = make_int4(o0, o1, o2, o3);
    *(int4*)&cursor[i0] = make_int4(o0, o1, o2, o3);
  } else {
    if (i0 < n)     { offs[i0] = o0;     cursor[i0] = o0; }
    if (i0 + 1 < n) { offs[i0 + 1] = o1; cursor[i0 + 1] = o1; }
    if (i0 + 2 < n) { offs[i0 + 2] = o2; cursor[i0 + 2] = o2; }
    if (i0 + 3 < n) { offs[i0 + 3] = o3; cursor[i0 + 3] = o3; }
  }
  if (bid == nb - 1 && t == 255) offs[n] = base + sc[255];
}

__global__ void k_scatter(const int* __restrict__ src, const int* __restrict__ dst,
                          int* __restrict__ cursor, int* __restrict__ csr_src, int E) {
  int e = blockIdx.x * blockDim.x + threadIdx.x;
  if (e < E) {
    int pos = atomicAdd(&cursor[dst[e]], 1);
    csr_src[pos] = src[e];
  }
}

// ---------------- weight pre-split: Bt[n][k] = W[k][n] as bf16 hi/lo --------

__global__ void k_split(const float* __restrict__ Wl, const float* __restrict__ Wr,
                        int K, int logK,
                        unsigned short* __restrict__ Bth,
                        unsigned short* __restrict__ Btl) {
  int idx = blockIdx.x * blockDim.x + threadIdx.x;
  if (idx >= 512 * K) return;
  int n = idx >> logK;
  int k = idx & (K - 1);
  float w = (n < 256) ? Wl[(size_t)k * 256 + n] : Wr[(size_t)k * 256 + (n - 256)];
  unsigned short h = f2bf(w);
  Bth[idx] = h;
  Btl[idx] = f2bf(w - bf2f(h));
}

// ---------------- split-bf16 MFMA GEMM: C[M,512] = A[M,K] @ Bt^T + bias -----
// Block 128x128, 4 waves (2x2), each wave 64x64 = 4x4 frags of 16x16.
// BK=32. LDS slot-XOR swizzle: slot = oct ^ ((row>>1)&3).

__global__ __launch_bounds__(256) void k_gemm_mfma(
    const float* __restrict__ A, int M, int K,
    const unsigned short* __restrict__ Bth, const unsigned short* __restrict__ Btl,
    const float* __restrict__ bl, const float* __restrict__ br,
    float* __restrict__ C) {
  __shared__ __align__(16) short As_hi[128 * 32];
  __shared__ __align__(16) short As_lo[128 * 32];
  __shared__ __align__(16) short Bs_hi[128 * 32];
  __shared__ __align__(16) short Bs_lo[128 * 32];

  const int tid = threadIdx.x;
  const int lane = tid & 63;
  const int wid = tid >> 6;
  const int wr = wid >> 1, wc = wid & 1;
  const int bm = blockIdx.x * 128;
  const int bn = blockIdx.y * 128;

  v4f acc[4][4];
#pragma unroll
  for (int m = 0; m < 4; ++m)
#pragma unroll
    for (int n = 0; n < 4; ++n) acc[m][n] = (v4f)(0.f);

  const int l15 = lane & 15, g = lane >> 4;

  for (int k0 = 0; k0 < K; k0 += 32) {
    // ---- stage A: fp32 -> bf16 hi/lo, swizzled LDS ----
#pragma unroll
    for (int it = 0; it < 2; ++it) {
      int task = tid + it * 256;           // 128 rows x 4 octs
      int row = task >> 2, oct = task & 3;
      int grow = bm + row;
      float f[8];
      if (grow < M) {
        const float* ap = &A[(size_t)grow * K + k0 + oct * 8];
        float4 p0 = *(const float4*)ap;
        float4 p1 = *(const float4*)(ap + 4);
        f[0] = p0.x; f[1] = p0.y; f[2] = p0.z; f[3] = p0.w;
        f[4] = p1.x; f[5] = p1.y; f[6] = p1.z; f[7] = p1.w;
      } else {
#pragma unroll
        for (int j = 0; j < 8; ++j) f[j] = 0.f;
      }
      v8s hi, lo;
#pragma unroll
      for (int j = 0; j < 8; ++j) {
        unsigned short h = f2bf(f[j]);
        hi[j] = (short)h;
        lo[j] = (short)f2bf(f[j] - bf2f(h));
      }
      int slot = oct ^ ((row >> 1) & 3);
      *(v8s*)&As_hi[row * 32 + slot * 8] = hi;
      *(v8s*)&As_lo[row * 32 + slot * 8] = lo;
    }
    // ---- stage B: pre-split bf16, swizzled LDS ----
#pragma unroll
    for (int it = 0; it < 2; ++it) {
      int task = tid + it * 256;           // 128 cols x 4 octs
      int col = task >> 2, oct = task & 3;
      int slot = oct ^ ((col >> 1) & 3);
      size_t gb = (size_t)(bn + col) * K + k0 + oct * 8;
      *(v8s*)&Bs_hi[col * 32 + slot * 8] = *(const v8s*)&Bth[gb];
      *(v8s*)&Bs_lo[col * 32 + slot * 8] = *(const v8s*)&Btl[gb];
    }
    __syncthreads();

    // ---- fragments (8 contiguous k per lane; swizzled slot) ----
    v8s ah[4], al[4], bh[4], bo[4];
#pragma unroll
    for (int m = 0; m < 4; ++m) {
      int r = wr * 64 + m * 16 + l15;
      int s = g ^ ((r >> 1) & 3);
      ah[m] = *(const v8s*)&As_hi[r * 32 + s * 8];
      al[m] = *(const v8s*)&As_lo[r * 32 + s * 8];
    }
#pragma unroll
    for (int n = 0; n < 4; ++n) {
      int c = wc * 64 + n * 16 + l15;
      int s = g ^ ((c >> 1) & 3);
      bh[n] = *(const v8s*)&Bs_hi[c * 32 + s * 8];
      bo[n] = *(const v8s*)&Bs_lo[c * 32 + s * 8];
    }
#pragma unroll
    for (int m = 0; m < 4; ++m)
#pragma unroll
      for (int n = 0; n < 4; ++n) {
        acc[m][n] = __builtin_amdgcn_mfma_f32_16x16x32_bf16(ah[m], bh[n], acc[m][n], 0, 0, 0);
        acc[m][n] = __builtin_amdgcn_mfma_f32_16x16x32_bf16(ah[m], bo[n], acc[m][n], 0, 0, 0);
        acc[m][n] = __builtin_amdgcn_mfma_f32_16x16x32_bf16(al[m], bh[n], acc[m][n], 0, 0, 0);
      }
    __syncthreads();
  }

  // ---- epilogue: + bias, fp32 store (C/D: col=lane&15, row=(lane>>4)*4+r) --
#pragma unroll
  for (int n = 0; n < 4; ++n) {
    int col = bn + wc * 64 + n * 16 + l15;
    float bv = (col < 256) ? bl[col] : br[col - 256];
#pragma unroll
    for (int m = 0; m < 4; ++m) {
      v4f fr = acc[m][n];
#pragma unroll
      for (int r = 0; r < 4; ++r) {
        int row = bm + wr * 64 + m * 16 + g * 4 + r;
        if (row < M) C[(size_t)row * 512 + col] = fr[r] + bv;
      }
    }
  }
}

// ---------------- fused GATv2 edge pass (H=8, C=32), wave per dst node ------

__global__ __launch_bounds__(256) void k_edge(
    const float* __restrict__ xlr,   // [N,512] = [xl | xr]
    const int* __restrict__ offs, const int* __restrict__ csr_src,
    const float* __restrict__ att,   // [8*32]
    const float* __restrict__ bias,  // [256]
    float* __restrict__ hout,        // [N,256]
    int n) {
  int lane = threadIdx.x & 63;
  int node = blockIdx.x * (blockDim.x >> 6) + (threadIdx.x >> 6);
  if (node >= n) return;

  float4 att4 = *(const float4*)&att[lane * 4];
  float4 xr4  = *(const float4*)&xlr[(size_t)node * 512 + 256 + lane * 4];

  float m = -INFINITY, d = 0.f;
  float ax = 0.f, ay = 0.f, az = 0.f, aw = 0.f;

  int e0 = offs[node], e1 = offs[node + 1];
  for (int e = e0 - 1; e < e1; ++e) {
    int j = (e < e0) ? node : csr_src[e];  // self-loop first
    float4 xl4 = *(const float4*)&xlr[(size_t)j * 512 + lane * 4];
    float p = lrelu(xl4.x + xr4.x) * att4.x
            + lrelu(xl4.y + xr4.y) * att4.y
            + lrelu(xl4.z + xr4.z) * att4.z
            + lrelu(xl4.w + xr4.w) * att4.w;
    p += __shfl_xor(p, 1);
    p += __shfl_xor(p, 2);
    p += __shfl_xor(p, 4);  // per-head score, replicated over the 8-lane group
    if (p <= m) {
      float w = __expf(p - m);
      d += w;
      ax = fmaf(w, xl4.x, ax); ay = fmaf(w, xl4.y, ay);
      az = fmaf(w, xl4.z, az); aw = fmaf(w, xl4.w, aw);
    } else {
      float r = __expf(m - p);  // first edge: m=-inf -> r=0
      d = fmaf(d, r, 1.f);
      ax = fmaf(ax, r, xl4.x); ay = fmaf(ay, r, xl4.y);
      az = fmaf(az, r, xl4.z); aw = fmaf(aw, r, xl4.w);
      m = p;
    }
  }
  float inv = 1.f / (d + 1e-16f);
  float4 b4 = *(const float4*)&bias[lane * 4];
  float4 o;
  o.x = elu1(fmaf(ax, inv, b4.x));
  o.y = elu1(fmaf(ay, inv, b4.y));
  o.z = elu1(fmaf(az, inv, b4.z));
  o.w = elu1(fmaf(aw, inv, b4.w));
  *(float4*)&hout[(size_t)node * 256 + lane * 4] = o;
}

// ---------------- layer 3: skinny linear (256->2 twice), wave per node ------

__global__ __launch_bounds__(256) void k_lin3(
    const float* __restrict__ h,  // [N,256]
    const float* __restrict__ Wl, const float* __restrict__ bl,
    const float* __restrict__ Wr, const float* __restrict__ br,
    float* __restrict__ xlr3,  // [N,4] = {xl0,xl1,xr0,xr1}
    int n) {
  int lane = threadIdx.x & 63;
  int node = blockIdx.x * (blockDim.x >> 6) + (threadIdx.x >> 6);
  if (node >= n) return;
  float4 h4 = *(const float4*)&h[(size_t)node * 256 + lane * 4];
  float hv[4] = {h4.x, h4.y, h4.z, h4.w};
  float al0 = 0.f, al1 = 0.f, ar0 = 0.f, ar1 = 0.f;
#pragma unroll
  for (int j = 0; j < 4; ++j) {
    int k = lane * 4 + j;
    al0 = fmaf(hv[j], Wl[k * 2 + 0], al0);
    al1 = fmaf(hv[j], Wl[k * 2 + 1], al1);
    ar0 = fmaf(hv[j], Wr[k * 2 + 0], ar0);
    ar1 = fmaf(hv[j], Wr[k * 2 + 1], ar1);
  }
#pragma unroll
  for (int s = 1; s < 64; s <<= 1) {
    al0 += __shfl_xor(al0, s);
    al1 += __shfl_xor(al1, s);
    ar0 += __shfl_xor(ar0, s);
    ar1 += __shfl_xor(ar1, s);
  }
  if (lane == 0) {
    float4 o = make_float4(al0 + bl[0], al1 + bl[1], ar0 + br[0], ar1 + br[1]);
    *(float4*)&xlr3[(size_t)node * 4] = o;
  }
}

// ---------------- layer 3 edge pass + log_softmax, thread per node ----------

__global__ void k_edge3(const float* __restrict__ xlr3,
                        const int* __restrict__ offs, const int* __restrict__ csr_src,
                        const float* __restrict__ att,  // [2]
                        const float* __restrict__ b,    // [2]
                        float* __restrict__ out, int n) {
  int i = blockIdx.x * blockDim.x + threadIdx.x;
  if (i >= n) return;
  float a0 = att[0], a1 = att[1];
  float xr0 = xlr3[(size_t)i * 4 + 2], xr1 = xlr3[(size_t)i * 4 + 3];
  float m = -INFINITY, d = 0.f, ac0 = 0.f, ac1 = 0.f;
  int e0 = offs[i], e1 = offs[i + 1];
  for (int e = e0 - 1; e < e1; ++e) {
    int j = (e < e0) ? i : csr_src[e];
    float xl0 = xlr3[(size_t)j * 4 + 0], xl1 = xlr3[(size_t)j * 4 + 1];
    float p = lrelu(xl0 + xr0) * a0 + lrelu(xl1 + xr1) * a1;
    if (p <= m) {
      float w = __expf(p - m);
      d += w; ac0 = fmaf(w, xl0, ac0); ac1 = fmaf(w, xl1, ac1);
    } else {
      float r = __expf(m - p);
      d = fmaf(d, r, 1.f);
      ac0 = fmaf(ac0, r, xl0); ac1 = fmaf(ac1, r, xl1);
      m = p;
    }
  }
  float inv = 1.f / (d + 1e-16f);
  float o0 = fmaf(ac0, inv, b[0]);
  float o1 = fmaf(ac1, inv, b[1]);
  float mx = fmaxf(o0, o1);
  float lse = mx + logf(expf(o0 - mx) + expf(o1 - mx));
  out[(size_t)i * 2 + 0] = o0 - lse;
  out[(size_t)i * 2 + 1] = o1 - lse;
}

// ---------------------------------------------------------------------------

static inline size_t align_up(size_t v, size_t a) { return (v + a - 1) & ~(a - 1); }

extern "C" void kernel_launch(void* const* d_in, const int* in_sizes, int n_in,
                              void* d_out, int out_size, void* d_ws, size_t ws_size,
                              hipStream_t stream) {
  const float* x    = (const float*)d_in[0];
  const int*   ei   = (const int*)d_in[1];
  const float* Wl1  = (const float*)d_in[2];
  const float* bl1  = (const float*)d_in[3];
  const float* Wr1  = (const float*)d_in[4];
  const float* br1  = (const float*)d_in[5];
  const float* att1 = (const float*)d_in[6];
  const float* b1   = (const float*)d_in[7];
  const float* Wl3  = (const float*)d_in[8];
  const float* bl3  = (const float*)d_in[9];
  const float* Wr3  = (const float*)d_in[10];
  const float* br3  = (const float*)d_in[11];
  const float* att3 = (const float*)d_in[12];
  const float* b3   = (const float*)d_in[13];
  const float* Wl2  = (const float*)d_in[14];
  const float* bl2  = (const float*)d_in[15];
  const float* Wr2  = (const float*)d_in[16];
  const float* br2  = (const float*)d_in[17];
  const float* att2 = (const float*)d_in[18];
  const float* b2   = (const float*)d_in[19];

  const int N = in_sizes[0] / 128;  // 50000
  const int E = in_sizes[1] / 2;    // 400000
  const int* srcp = ei;
  const int* dstp = ei + E;

  // workspace layout
  char* w = (char*)d_ws;
  size_t off = 0;
  int* deg     = (int*)(w + off); off = align_up(off + (size_t)N * 4, 256);
  int* offs    = (int*)(w + off); off = align_up(off + (size_t)(N + 1) * 4, 256);
  int* cursor  = (int*)(w + off); off = align_up(off + (size_t)N * 4, 256);
  int* csr_src = (int*)(w + off); off = align_up(off + (size_t)E * 4, 256);
  int* bsum    = (int*)(w + off); off = align_up(off + (size_t)256 * 4, 256);
  float* xlr   = (float*)(w + off); off = align_up(off + (size_t)N * 512 * 4, 256);
  float* hbuf  = (float*)(w + off); off = align_up(off + (size_t)N * 256 * 4, 256);
  float* xlr3  = (float*)(w + off); off = align_up(off + (size_t)N * 4 * 4, 256);
  unsigned short* Bt1h = (unsigned short*)(w + off); off = align_up(off + (size_t)512 * 128 * 2, 256);
  unsigned short* Bt1l = (unsigned short*)(w + off); off = align_up(off + (size_t)512 * 128 * 2, 256);
  unsigned short* Bt2h = (unsigned short*)(w + off); off = align_up(off + (size_t)512 * 256 * 2, 256);
  unsigned short* Bt2l = (unsigned short*)(w + off); off = align_up(off + (size_t)512 * 256 * 2, 256);
  (void)ws_size;

  const int nb = (N + 1023) / 1024;  // scan blocks

  // ---- build CSR (incoming edges per dst), reused by all 3 layers ----
  hipMemsetAsync(deg, 0, (size_t)N * 4, stream);
  k_count<<<(E + 255) / 256, 256, 0, stream>>>(dstp, deg, E);
  k_bsum<<<nb, 256, 0, stream>>>(deg, N, bsum);
  k_offsets<<<nb, 256, 0, stream>>>(deg, bsum, nb, N, offs, cursor);
  k_scatter<<<(E + 255) / 256, 256, 0, stream>>>(srcp, dstp, cursor, csr_src, E);

  // ---- pre-split weights into transposed bf16 hi/lo ----
  k_split<<<(512 * 128 + 255) / 256, 256, 0, stream>>>(Wl1, Wr1, 128, 7, Bt1h, Bt1l);
  k_split<<<(512 * 256 + 255) / 256, 256, 0, stream>>>(Wl3, Wr3, 256, 8, Bt2h, Bt2l);

  dim3 ggrid((N + 127) / 128, 4);
  int nodeBlocks = (N + 3) / 4;  // 4 waves (nodes) per 256-thread block

  // ---- layer 1: 128 -> 8x32, concat, ELU ----
  k_gemm_mfma<<<ggrid, 256, 0, stream>>>(x, N, 128, Bt1h, Bt1l, bl1, br1, xlr);
  k_edge<<<nodeBlocks, 256, 0, stream>>>(xlr, offs, csr_src, att1, b1, hbuf, N);

  // ---- layer 2: 256 -> 8x32, concat, ELU ----
  k_gemm_mfma<<<ggrid, 256, 0, stream>>>(hbuf, N, 256, Bt2h, Bt2l, bl3, br3, xlr);
  k_edge<<<nodeBlocks, 256, 0, stream>>>(xlr, offs, csr_src, att3, b3, hbuf, N);

  // ---- layer 3: 256 -> 1x2, mean(=identity), log_softmax ----
  k_lin3<<<nodeBlocks, 256, 0, stream>>>(hbuf, Wl2, bl2, Wr2, br2, xlr3, N);
  k_edge3<<<(N + 255) / 256, 256, 0, stream>>>(xlr3, offs, csr_src, att2, b2,
                                               (float*)d_out, N);
}

// Round 4
// 372.515 us; speedup vs baseline: 1.6779x; 1.0313x over previous
//
#include <hip/hip_runtime.h>
#include <cstdint>
#include <cstddef>

// ---------------------------------------------------------------------------
// GATv2 3-layer forward on MI355X.
//   k_split     : pre-split [Wl|Wr] into transposed bf16 hi/lo (W^T, [512][K])
//   k_gemm_mfma : [xl_bf(bf16) | xr_f(f32)] = [x@Wl+bl | x@Wr+br] via
//                 split-bf16 3-product MFMA (16x16x32)
//   k_edge      : fused per-dst-node online-softmax aggregation + bias + ELU,
//                 gathers bf16 xl rows (512B/edge) to halve HBM gather bytes
// Graph CSR built once (device-wide 3-phase scan), reused 3x.
// Layer 3 skinny + fused log_softmax.
// ---------------------------------------------------------------------------

typedef __attribute__((ext_vector_type(8))) short v8s;
typedef __attribute__((ext_vector_type(4))) float v4f;

__device__ __forceinline__ float lrelu(float v) { return v >= 0.f ? v : 0.2f * v; }
__device__ __forceinline__ float elu1(float v)  { return v > 0.f ? v : expm1f(v); }

__device__ __forceinline__ unsigned short f2bf(float f) {  // RTNE fp32->bf16
  unsigned int u = __float_as_uint(f);
  unsigned int r = (u + 0x7FFFu + ((u >> 16) & 1u)) >> 16;
  return (unsigned short)r;
}
__device__ __forceinline__ float bf2f(unsigned short s) {
  return __uint_as_float(((unsigned int)s) << 16);
}

// ---------------- CSR build ----------------

__global__ void k_count(const int* __restrict__ dst, int* __restrict__ deg, int E) {
  int e = blockIdx.x * blockDim.x + threadIdx.x;
  if (e < E) atomicAdd(&deg[dst[e]], 1);
}

// per-block (1024-entry) sums of deg
__global__ __launch_bounds__(256) void k_bsum(const int* __restrict__ deg, int n,
                                              int* __restrict__ bsum) {
  __shared__ int red[256];
  int t = threadIdx.x, bid = blockIdx.x;
  int i0 = bid * 1024 + t * 4;
  int s = 0;
  if (i0 + 3 < n) {
    int4 v = *(const int4*)&deg[i0];
    s = v.x + v.y + v.z + v.w;
  } else {
#pragma unroll
    for (int j = 0; j < 4; ++j)
      if (i0 + j < n) s += deg[i0 + j];
  }
  red[t] = s;
  __syncthreads();
  for (int off = 128; off > 0; off >>= 1) {
    if (t < off) red[t] += red[t + off];
    __syncthreads();
  }
  if (t == 0) bsum[bid] = red[0];
}

// exclusive offsets: base from bsum, intra-block LDS scan
__global__ __launch_bounds__(256) void k_offsets(const int* __restrict__ deg,
                                                 const int* __restrict__ bsum,
                                                 int nb, int n,
                                                 int* __restrict__ offs,
                                                 int* __restrict__ cursor) {
  __shared__ int sc[256];
  int t = threadIdx.x, bid = blockIdx.x;
  int base = 0;
  for (int b = 0; b < bid; ++b) base += bsum[b];
  int i0 = bid * 1024 + t * 4;
  int v0 = 0, v1 = 0, v2 = 0, v3 = 0;
  if (i0 + 3 < n) {
    int4 v = *(const int4*)&deg[i0];
    v0 = v.x; v1 = v.y; v2 = v.z; v3 = v.w;
  } else {
    if (i0 < n)     v0 = deg[i0];
    if (i0 + 1 < n) v1 = deg[i0 + 1];
    if (i0 + 2 < n) v2 = deg[i0 + 2];
    if (i0 + 3 < n) v3 = deg[i0 + 3];
  }
  int s = v0 + v1 + v2 + v3;
  sc[t] = s;
  __syncthreads();
  for (int off = 1; off < 256; off <<= 1) {
    int x = (t >= off) ? sc[t - off] : 0;
    __syncthreads();
    sc[t] += x;
    __syncthreads();
  }
  int run = base + sc[t] - s;
  int o0 = run, o1 = run + v0, o2 = o1 + v1, o3 = o2 + v2;
  if (i0 + 3 < n) {
    *(int4*)&offs[i0] = make_int4(o0, o1, o2, o3);
    *(int4*)&cursor[i0] = make_int4(o0, o1, o2, o3);
  } else {
    if (i0 < n)     { offs[i0] = o0;     cursor[i0] = o0; }
    if (i0 + 1 < n) { offs[i0 + 1] = o1; cursor[i0 + 1] = o1; }
    if (i0 + 2 < n) { offs[i0 + 2] = o2; cursor[i0 + 2] = o2; }
    if (i0 + 3 < n) { offs[i0 + 3] = o3; cursor[i0 + 3] = o3; }
  }
  if (bid == nb - 1 && t == 255) offs[n] = base + sc[255];
}

__global__ void k_scatter(const int* __restrict__ src, const int* __restrict__ dst,
                          int* __restrict__ cursor, int* __restrict__ csr_src, int E) {
  int e = blockIdx.x * blockDim.x + threadIdx.x;
  if (e < E) {
    int pos = atomicAdd(&cursor[dst[e]], 1);
    csr_src[pos] = src[e];
  }
}

// ---------------- weight pre-split: Bt[n][k] = W[k][n] as bf16 hi/lo --------

__global__ void k_split(const float* __restrict__ Wl, const float* __restrict__ Wr,
                        int K, int logK,
                        unsigned short* __restrict__ Bth,
                        unsigned short* __restrict__ Btl) {
  int idx = blockIdx.x * blockDim.x + threadIdx.x;
  if (idx >= 512 * K) return;
  int n = idx >> logK;
  int k = idx & (K - 1);
  float w = (n < 256) ? Wl[(size_t)k * 256 + n] : Wr[(size_t)k * 256 + (n - 256)];
  unsigned short h = f2bf(w);
  Bth[idx] = h;
  Btl[idx] = f2bf(w - bf2f(h));
}

// ---------------- split-bf16 MFMA GEMM ---------------------------------------
// Block 128x128, 4 waves (2x2), each wave 64x64 = 4x4 frags of 16x16.
// BK=32. LDS slot-XOR swizzle: slot = oct ^ ((row>>1)&3).
// Output: cols 0..255 -> xl_bf (bf16), cols 256..511 -> xr_f (fp32).

__global__ __launch_bounds__(256) void k_gemm_mfma(
    const float* __restrict__ A, int M, int K,
    const unsigned short* __restrict__ Bth, const unsigned short* __restrict__ Btl,
    const float* __restrict__ bl, const float* __restrict__ br,
    unsigned short* __restrict__ xl_bf, float* __restrict__ xr_f) {
  __shared__ __align__(16) short As_hi[128 * 32];
  __shared__ __align__(16) short As_lo[128 * 32];
  __shared__ __align__(16) short Bs_hi[128 * 32];
  __shared__ __align__(16) short Bs_lo[128 * 32];

  const int tid = threadIdx.x;
  const int lane = tid & 63;
  const int wid = tid >> 6;
  const int wr = wid >> 1, wc = wid & 1;
  const int bm = blockIdx.x * 128;
  const int bn = blockIdx.y * 128;

  v4f acc[4][4];
#pragma unroll
  for (int m = 0; m < 4; ++m)
#pragma unroll
    for (int n = 0; n < 4; ++n) acc[m][n] = (v4f)(0.f);

  const int l15 = lane & 15, g = lane >> 4;

  for (int k0 = 0; k0 < K; k0 += 32) {
    // ---- stage A: fp32 -> bf16 hi/lo, swizzled LDS ----
#pragma unroll
    for (int it = 0; it < 2; ++it) {
      int task = tid + it * 256;           // 128 rows x 4 octs
      int row = task >> 2, oct = task & 3;
      int grow = bm + row;
      float f[8];
      if (grow < M) {
        const float* ap = &A[(size_t)grow * K + k0 + oct * 8];
        float4 p0 = *(const float4*)ap;
        float4 p1 = *(const float4*)(ap + 4);
        f[0] = p0.x; f[1] = p0.y; f[2] = p0.z; f[3] = p0.w;
        f[4] = p1.x; f[5] = p1.y; f[6] = p1.z; f[7] = p1.w;
      } else {
#pragma unroll
        for (int j = 0; j < 8; ++j) f[j] = 0.f;
      }
      v8s hi, lo;
#pragma unroll
      for (int j = 0; j < 8; ++j) {
        unsigned short h = f2bf(f[j]);
        hi[j] = (short)h;
        lo[j] = (short)f2bf(f[j] - bf2f(h));
      }
      int slot = oct ^ ((row >> 1) & 3);
      *(v8s*)&As_hi[row * 32 + slot * 8] = hi;
      *(v8s*)&As_lo[row * 32 + slot * 8] = lo;
    }
    // ---- stage B: pre-split bf16, swizzled LDS ----
#pragma unroll
    for (int it = 0; it < 2; ++it) {
      int task = tid + it * 256;           // 128 cols x 4 octs
      int col = task >> 2, oct = task & 3;
      int slot = oct ^ ((col >> 1) & 3);
      size_t gb = (size_t)(bn + col) * K + k0 + oct * 8;
      *(v8s*)&Bs_hi[col * 32 + slot * 8] = *(const v8s*)&Bth[gb];
      *(v8s*)&Bs_lo[col * 32 + slot * 8] = *(const v8s*)&Btl[gb];
    }
    __syncthreads();

    // ---- fragments (8 contiguous k per lane; swizzled slot) ----
    v8s ah[4], al[4], bh[4], bo[4];
#pragma unroll
    for (int m = 0; m < 4; ++m) {
      int r = wr * 64 + m * 16 + l15;
      int s = g ^ ((r >> 1) & 3);
      ah[m] = *(const v8s*)&As_hi[r * 32 + s * 8];
      al[m] = *(const v8s*)&As_lo[r * 32 + s * 8];
    }
#pragma unroll
    for (int n = 0; n < 4; ++n) {
      int c = wc * 64 + n * 16 + l15;
      int s = g ^ ((c >> 1) & 3);
      bh[n] = *(const v8s*)&Bs_hi[c * 32 + s * 8];
      bo[n] = *(const v8s*)&Bs_lo[c * 32 + s * 8];
    }
#pragma unroll
    for (int m = 0; m < 4; ++m)
#pragma unroll
      for (int n = 0; n < 4; ++n) {
        acc[m][n] = __builtin_amdgcn_mfma_f32_16x16x32_bf16(ah[m], bh[n], acc[m][n], 0, 0, 0);
        acc[m][n] = __builtin_amdgcn_mfma_f32_16x16x32_bf16(ah[m], bo[n], acc[m][n], 0, 0, 0);
        acc[m][n] = __builtin_amdgcn_mfma_f32_16x16x32_bf16(al[m], bh[n], acc[m][n], 0, 0, 0);
      }
    __syncthreads();
  }

  // ---- epilogue: + bias; xl half -> bf16, xr half -> fp32 ----
  // C/D layout: col=lane&15, row=(lane>>4)*4+r. bn<256 -> whole block is xl.
#pragma unroll
  for (int n = 0; n < 4; ++n) {
    int col = bn + wc * 64 + n * 16 + l15;  // 0..511, block-uniform half
    float bv = (col < 256) ? bl[col] : br[col - 256];
#pragma unroll
    for (int m = 0; m < 4; ++m) {
      v4f fr = acc[m][n];
#pragma unroll
      for (int r = 0; r < 4; ++r) {
        int row = bm + wr * 64 + m * 16 + g * 4 + r;
        if (row < M) {
          float val = fr[r] + bv;
          if (col < 256) xl_bf[(size_t)row * 256 + col] = f2bf(val);
          else           xr_f[(size_t)row * 256 + (col - 256)] = val;
        }
      }
    }
  }
}

// ---------------- fused GATv2 edge pass (H=8, C=32), wave per dst node ------
// Gathers bf16 xl rows (512B/edge); xr read once per node in fp32.

__global__ __launch_bounds__(256) void k_edge(
    const unsigned short* __restrict__ xl_bf,  // [N,256] bf16
    const float* __restrict__ xr_f,            // [N,256] f32
    const int* __restrict__ offs, const int* __restrict__ csr_src,
    const float* __restrict__ att,   // [8*32]
    const float* __restrict__ bias,  // [256]
    float* __restrict__ hout,        // [N,256]
    int n) {
  int lane = threadIdx.x & 63;
  int node = blockIdx.x * (blockDim.x >> 6) + (threadIdx.x >> 6);
  if (node >= n) return;

  float4 att4 = *(const float4*)&att[lane * 4];
  float4 xr4  = *(const float4*)&xr_f[(size_t)node * 256 + lane * 4];

  float m = -INFINITY, d = 0.f;
  float ax = 0.f, ay = 0.f, az = 0.f, aw = 0.f;

  int e0 = offs[node], e1 = offs[node + 1];
  for (int e = e0 - 1; e < e1; ++e) {
    int j = (e < e0) ? node : csr_src[e];  // self-loop first
    ushort4 u = *(const ushort4*)&xl_bf[(size_t)j * 256 + lane * 4];
    float x0 = bf2f(u.x), x1 = bf2f(u.y), x2 = bf2f(u.z), x3 = bf2f(u.w);
    float p = lrelu(x0 + xr4.x) * att4.x
            + lrelu(x1 + xr4.y) * att4.y
            + lrelu(x2 + xr4.z) * att4.z
            + lrelu(x3 + xr4.w) * att4.w;
    p += __shfl_xor(p, 1);
    p += __shfl_xor(p, 2);
    p += __shfl_xor(p, 4);  // per-head score, replicated over the 8-lane group
    if (p <= m) {
      float w = __expf(p - m);
      d += w;
      ax = fmaf(w, x0, ax); ay = fmaf(w, x1, ay);
      az = fmaf(w, x2, az); aw = fmaf(w, x3, aw);
    } else {
      float r = __expf(m - p);  // first edge: m=-inf -> r=0
      d = fmaf(d, r, 1.f);
      ax = fmaf(ax, r, x0); ay = fmaf(ay, r, x1);
      az = fmaf(az, r, x2); aw = fmaf(aw, r, x3);
      m = p;
    }
  }
  float inv = 1.f / (d + 1e-16f);
  float4 b4 = *(const float4*)&bias[lane * 4];
  float4 o;
  o.x = elu1(fmaf(ax, inv, b4.x));
  o.y = elu1(fmaf(ay, inv, b4.y));
  o.z = elu1(fmaf(az, inv, b4.z));
  o.w = elu1(fmaf(aw, inv, b4.w));
  *(float4*)&hout[(size_t)node * 256 + lane * 4] = o;
}

// ---------------- layer 3: skinny linear (256->2 twice), wave per node ------

__global__ __launch_bounds__(256) void k_lin3(
    const float* __restrict__ h,  // [N,256]
    const float* __restrict__ Wl, const float* __restrict__ bl,
    const float* __restrict__ Wr, const float* __restrict__ br,
    float* __restrict__ xlr3,  // [N,4] = {xl0,xl1,xr0,xr1}
    int n) {
  int lane = threadIdx.x & 63;
  int node = blockIdx.x * (blockDim.x >> 6) + (threadIdx.x >> 6);
  if (node >= n) return;
  float4 h4 = *(const float4*)&h[(size_t)node * 256 + lane * 4];
  float hv[4] = {h4.x, h4.y, h4.z, h4.w};
  float al0 = 0.f, al1 = 0.f, ar0 = 0.f, ar1 = 0.f;
#pragma unroll
  for (int j = 0; j < 4; ++j) {
    int k = lane * 4 + j;
    al0 = fmaf(hv[j], Wl[k * 2 + 0], al0);
    al1 = fmaf(hv[j], Wl[k * 2 + 1], al1);
    ar0 = fmaf(hv[j], Wr[k * 2 + 0], ar0);
    ar1 = fmaf(hv[j], Wr[k * 2 + 1], ar1);
  }
#pragma unroll
  for (int s = 1; s < 64; s <<= 1) {
    al0 += __shfl_xor(al0, s);
    al1 += __shfl_xor(al1, s);
    ar0 += __shfl_xor(ar0, s);
    ar1 += __shfl_xor(ar1, s);
  }
  if (lane == 0) {
    float4 o = make_float4(al0 + bl[0], al1 + bl[1], ar0 + br[0], ar1 + br[1]);
    *(float4*)&xlr3[(size_t)node * 4] = o;
  }
}

// ---------------- layer 3 edge pass + log_softmax, thread per node ----------

__global__ void k_edge3(const float* __restrict__ xlr3,
                        const int* __restrict__ offs, const int* __restrict__ csr_src,
                        const float* __restrict__ att,  // [2]
                        const float* __restrict__ b,    // [2]
                        float* __restrict__ out, int n) {
  int i = blockIdx.x * blockDim.x + threadIdx.x;
  if (i >= n) return;
  float a0 = att[0], a1 = att[1];
  float xr0 = xlr3[(size_t)i * 4 + 2], xr1 = xlr3[(size_t)i * 4 + 3];
  float m = -INFINITY, d = 0.f, ac0 = 0.f, ac1 = 0.f;
  int e0 = offs[i], e1 = offs[i + 1];
  for (int e = e0 - 1; e < e1; ++e) {
    int j = (e < e0) ? i : csr_src[e];
    float xl0 = xlr3[(size_t)j * 4 + 0], xl1 = xlr3[(size_t)j * 4 + 1];
    float p = lrelu(xl0 + xr0) * a0 + lrelu(xl1 + xr1) * a1;
    if (p <= m) {
      float w = __expf(p - m);
      d += w; ac0 = fmaf(w, xl0, ac0); ac1 = fmaf(w, xl1, ac1);
    } else {
      float r = __expf(m - p);
      d = fmaf(d, r, 1.f);
      ac0 = fmaf(ac0, r, xl0); ac1 = fmaf(ac1, r, xl1);
      m = p;
    }
  }
  float inv = 1.f / (d + 1e-16f);
  float o0 = fmaf(ac0, inv, b[0]);
  float o1 = fmaf(ac1, inv, b[1]);
  float mx = fmaxf(o0, o1);
  float lse = mx + logf(expf(o0 - mx) + expf(o1 - mx));
  out[(size_t)i * 2 + 0] = o0 - lse;
  out[(size_t)i * 2 + 1] = o1 - lse;
}

// ---------------------------------------------------------------------------

static inline size_t align_up(size_t v, size_t a) { return (v + a - 1) & ~(a - 1); }

extern "C" void kernel_launch(void* const* d_in, const int* in_sizes, int n_in,
                              void* d_out, int out_size, void* d_ws, size_t ws_size,
                              hipStream_t stream) {
  const float* x    = (const float*)d_in[0];
  const int*   ei   = (const int*)d_in[1];
  const float* Wl1  = (const float*)d_in[2];
  const float* bl1  = (const float*)d_in[3];
  const float* Wr1  = (const float*)d_in[4];
  const float* br1  = (const float*)d_in[5];
  const float* att1 = (const float*)d_in[6];
  const float* b1   = (const float*)d_in[7];
  const float* Wl3  = (const float*)d_in[8];
  const float* bl3  = (const float*)d_in[9];
  const float* Wr3  = (const float*)d_in[10];
  const float* br3  = (const float*)d_in[11];
  const float* att3 = (const float*)d_in[12];
  const float* b3   = (const float*)d_in[13];
  const float* Wl2  = (const float*)d_in[14];
  const float* bl2  = (const float*)d_in[15];
  const float* Wr2  = (const float*)d_in[16];
  const float* br2  = (const float*)d_in[17];
  const float* att2 = (const float*)d_in[18];
  const float* b2   = (const float*)d_in[19];

  const int N = in_sizes[0] / 128;  // 50000
  const int E = in_sizes[1] / 2;    // 400000
  const int* srcp = ei;
  const int* dstp = ei + E;

  // workspace layout
  char* w = (char*)d_ws;
  size_t off = 0;
  int* deg     = (int*)(w + off); off = align_up(off + (size_t)N * 4, 256);
  int* offs    = (int*)(w + off); off = align_up(off + (size_t)(N + 1) * 4, 256);
  int* cursor  = (int*)(w + off); off = align_up(off + (size_t)N * 4, 256);
  int* csr_src = (int*)(w + off); off = align_up(off + (size_t)E * 4, 256);
  int* bsum    = (int*)(w + off); off = align_up(off + (size_t)256 * 4, 256);
  unsigned short* xl_bf = (unsigned short*)(w + off); off = align_up(off + (size_t)N * 256 * 2, 256);
  float* xr_f  = (float*)(w + off); off = align_up(off + (size_t)N * 256 * 4, 256);
  float* hbuf  = (float*)(w + off); off = align_up(off + (size_t)N * 256 * 4, 256);
  float* xlr3  = (float*)(w + off); off = align_up(off + (size_t)N * 4 * 4, 256);
  unsigned short* Bt1h = (unsigned short*)(w + off); off = align_up(off + (size_t)512 * 128 * 2, 256);
  unsigned short* Bt1l = (unsigned short*)(w + off); off = align_up(off + (size_t)512 * 128 * 2, 256);
  unsigned short* Bt2h = (unsigned short*)(w + off); off = align_up(off + (size_t)512 * 256 * 2, 256);
  unsigned short* Bt2l = (unsigned short*)(w + off); off = align_up(off + (size_t)512 * 256 * 2, 256);
  (void)ws_size;

  const int nb = (N + 1023) / 1024;  // scan blocks

  // ---- build CSR (incoming edges per dst), reused by all 3 layers ----
  hipMemsetAsync(deg, 0, (size_t)N * 4, stream);
  k_count<<<(E + 255) / 256, 256, 0, stream>>>(dstp, deg, E);
  k_bsum<<<nb, 256, 0, stream>>>(deg, N, bsum);
  k_offsets<<<nb, 256, 0, stream>>>(deg, bsum, nb, N, offs, cursor);
  k_scatter<<<(E + 255) / 256, 256, 0, stream>>>(srcp, dstp, cursor, csr_src, E);

  // ---- pre-split weights into transposed bf16 hi/lo ----
  k_split<<<(512 * 128 + 255) / 256, 256, 0, stream>>>(Wl1, Wr1, 128, 7, Bt1h, Bt1l);
  k_split<<<(512 * 256 + 255) / 256, 256, 0, stream>>>(Wl3, Wr3, 256, 8, Bt2h, Bt2l);

  dim3 ggrid((N + 127) / 128, 4);
  int nodeBlocks = (N + 3) / 4;  // 4 waves (nodes) per 256-thread block

  // ---- layer 1: 128 -> 8x32, concat, ELU ----
  k_gemm_mfma<<<ggrid, 256, 0, stream>>>(x, N, 128, Bt1h, Bt1l, bl1, br1, xl_bf, xr_f);
  k_edge<<<nodeBlocks, 256, 0, stream>>>(xl_bf, xr_f, offs, csr_src, att1, b1, hbuf, N);

  // ---- layer 2: 256 -> 8x32, concat, ELU ----
  k_gemm_mfma<<<ggrid, 256, 0, stream>>>(hbuf, N, 256, Bt2h, Bt2l, bl3, br3, xl_bf, xr_f);
  k_edge<<<nodeBlocks, 256, 0, stream>>>(xl_bf, xr_f, offs, csr_src, att3, b3, hbuf, N);

  // ---- layer 3: 256 -> 1x2, mean(=identity), log_softmax ----
  k_lin3<<<nodeBlocks, 256, 0, stream>>>(hbuf, Wl2, bl2, Wr2, br2, xlr3, N);
  k_edge3<<<(N + 255) / 256, 256, 0, stream>>>(xlr3, offs, csr_src, att2, b2,
                                               (float*)d_out, N);
}

// Round 5
// 349.370 us; speedup vs baseline: 1.7891x; 1.0662x over previous
//
#include <hip/hip_runtime.h>
#include <cstdint>
#include <cstddef>

// ---------------------------------------------------------------------------
// GATv2 3-layer forward on MI355X.
//   A kept as bf16 hi/lo planes (fp32-equivalent via 3-product MFMA).
//   k_gemm_mfma : tile 64x256, global_load_lds staging (pre-swizzled source),
//                 LDS-transpose vectorized epilogue, bf16 outputs.
//   k_edge      : fused online-softmax aggregation; emits hi/lo bf16 planes.
// Graph CSR built once (device-wide scan), reused 3x.
// ---------------------------------------------------------------------------

typedef __attribute__((ext_vector_type(8))) short v8s;
typedef __attribute__((ext_vector_type(4))) float v4f;

__device__ __forceinline__ float lrelu(float v) { return v >= 0.f ? v : 0.2f * v; }
__device__ __forceinline__ float elu1(float v)  { return v > 0.f ? v : expm1f(v); }

__device__ __forceinline__ unsigned short f2bf(float f) {  // RTNE fp32->bf16
  unsigned int u = __float_as_uint(f);
  unsigned int r = (u + 0x7FFFu + ((u >> 16) & 1u)) >> 16;
  return (unsigned short)r;
}
__device__ __forceinline__ float bf2f(unsigned short s) {
  return __uint_as_float(((unsigned int)s) << 16);
}

__device__ __forceinline__ void gl_lds16(const void* g, void* l) {
  __builtin_amdgcn_global_load_lds(
      (const __attribute__((address_space(1))) unsigned int*)g,
      (__attribute__((address_space(3))) unsigned int*)l, 16, 0, 0);
}

// ---------------- CSR build ----------------

__global__ void k_count(const int* __restrict__ dst, int* __restrict__ deg, int E) {
  int e = blockIdx.x * blockDim.x + threadIdx.x;
  if (e < E) atomicAdd(&deg[dst[e]], 1);
}

__global__ __launch_bounds__(256) void k_bsum(const int* __restrict__ deg, int n,
                                              int* __restrict__ bsum) {
  __shared__ int red[256];
  int t = threadIdx.x, bid = blockIdx.x;
  int i0 = bid * 1024 + t * 4;
  int s = 0;
  if (i0 + 3 < n) {
    int4 v = *(const int4*)&deg[i0];
    s = v.x + v.y + v.z + v.w;
  } else {
#pragma unroll
    for (int j = 0; j < 4; ++j)
      if (i0 + j < n) s += deg[i0 + j];
  }
  red[t] = s;
  __syncthreads();
  for (int off = 128; off > 0; off >>= 1) {
    if (t < off) red[t] += red[t + off];
    __syncthreads();
  }
  if (t == 0) bsum[bid] = red[0];
}

__global__ __launch_bounds__(256) void k_offsets(const int* __restrict__ deg,
                                                 const int* __restrict__ bsum,
                                                 int nb, int n,
                                                 int* __restrict__ offs,
                                                 int* __restrict__ cursor) {
  __shared__ int sc[256];
  int t = threadIdx.x, bid = blockIdx.x;
  int base = 0;
  for (int b = 0; b < bid; ++b) base += bsum[b];
  int i0 = bid * 1024 + t * 4;
  int v0 = 0, v1 = 0, v2 = 0, v3 = 0;
  if (i0 + 3 < n) {
    int4 v = *(const int4*)&deg[i0];
    v0 = v.x; v1 = v.y; v2 = v.z; v3 = v.w;
  } else {
    if (i0 < n)     v0 = deg[i0];
    if (i0 + 1 < n) v1 = deg[i0 + 1];
    if (i0 + 2 < n) v2 = deg[i0 + 2];
    if (i0 + 3 < n) v3 = deg[i0 + 3];
  }
  int s = v0 + v1 + v2 + v3;
  sc[t] = s;
  __syncthreads();
  for (int off = 1; off < 256; off <<= 1) {
    int x = (t >= off) ? sc[t - off] : 0;
    __syncthreads();
    sc[t] += x;
    __syncthreads();
  }
  int run = base + sc[t] - s;
  int o0 = run, o1 = run + v0, o2 = o1 + v1, o3 = o2 + v2;
  if (i0 + 3 < n) {
    *(int4*)&offs[i0] = make_int4(o0, o1, o2, o3);
    *(int4*)&cursor[i0] = make_int4(o0, o1, o2, o3);
  } else {
    if (i0 < n)     { offs[i0] = o0;     cursor[i0] = o0; }
    if (i0 + 1 < n) { offs[i0 + 1] = o1; cursor[i0 + 1] = o1; }
    if (i0 + 2 < n) { offs[i0 + 2] = o2; cursor[i0 + 2] = o2; }
    if (i0 + 3 < n) { offs[i0 + 3] = o3; cursor[i0 + 3] = o3; }
  }
  if (bid == nb - 1 && t == 255) offs[n] = base + sc[255];
}

__global__ void k_scatter(const int* __restrict__ src, const int* __restrict__ dst,
                          int* __restrict__ cursor, int* __restrict__ csr_src, int E) {
  int e = blockIdx.x * blockDim.x + threadIdx.x;
  if (e < E) {
    int pos = atomicAdd(&cursor[dst[e]], 1);
    csr_src[pos] = src[e];
  }
}

// ---------------- weight pre-split: Bt[n][k] = W[k][n] as bf16 hi/lo --------

__global__ void k_split(const float* __restrict__ Wl, const float* __restrict__ Wr,
                        int K, int logK,
                        unsigned short* __restrict__ Bth,
                        unsigned short* __restrict__ Btl) {
  int idx = blockIdx.x * blockDim.x + threadIdx.x;
  if (idx >= 512 * K) return;
  int n = idx >> logK;
  int k = idx & (K - 1);
  float w = (n < 256) ? Wl[(size_t)k * 256 + n] : Wr[(size_t)k * 256 + (n - 256)];
  unsigned short h = f2bf(w);
  Bth[idx] = h;
  Btl[idx] = f2bf(w - bf2f(h));
}

// ---------------- input pre-split: x[N,128] -> hi/lo bf16 planes [Npad,128] -

__global__ void k_splitA(const float* __restrict__ X, int Nreal, int total4,
                         unsigned short* __restrict__ Hh,
                         unsigned short* __restrict__ Hl) {
  int idx = blockIdx.x * blockDim.x + threadIdx.x;  // each handles 4 elems
  if (idx >= total4) return;
  int row = idx >> 5;  // K=128: (idx*4)>>7
  ushort4 uh, ul;
  if (row < Nreal) {
    float4 v = *(const float4*)&X[(size_t)idx * 4];
    uh.x = f2bf(v.x); ul.x = f2bf(v.x - bf2f(uh.x));
    uh.y = f2bf(v.y); ul.y = f2bf(v.y - bf2f(uh.y));
    uh.z = f2bf(v.z); ul.z = f2bf(v.z - bf2f(uh.z));
    uh.w = f2bf(v.w); ul.w = f2bf(v.w - bf2f(uh.w));
  } else {
    uh = make_ushort4(0, 0, 0, 0); ul = make_ushort4(0, 0, 0, 0);
  }
  *(ushort4*)&Hh[(size_t)idx * 4] = uh;
  *(ushort4*)&Hl[(size_t)idx * 4] = ul;
}

// ---------------- split-bf16 MFMA GEMM, tile 64x256 -------------------------
// grid (Npad/64, 2): y=0 -> xl half (cols 0..255), y=1 -> xr half.
// 4 waves, wave w owns cols w*64..w*64+63 (4x4 frags of 16x16x32).
// Staging: global_load_lds(16B), linear LDS dest, slot-XOR on global source.
// Epilogue: per-wave LDS transpose -> 8B bf16 stores.

__global__ __launch_bounds__(256) void k_gemm_mfma(
    const unsigned short* __restrict__ Ah_g,  // [Npad,K] bf16 hi
    const unsigned short* __restrict__ Al_g,  // [Npad,K] bf16 lo
    int Nreal, int K,
    const unsigned short* __restrict__ Bth, const unsigned short* __restrict__ Btl,
    const float* __restrict__ bl, const float* __restrict__ br,
    unsigned short* __restrict__ xl_bf, unsigned short* __restrict__ xr_bf) {
  __shared__ __align__(16) short Ah[64 * 32];
  __shared__ __align__(16) short Al[64 * 32];
  __shared__ __align__(16) short Bh[256 * 32];
  __shared__ __align__(16) short Bl[256 * 32];

  const int tid = threadIdx.x;
  const int lane = tid & 63;
  const int wid = tid >> 6;
  const int l15 = lane & 15, g = lane >> 4;
  const int bm = blockIdx.x * 64;
  const int half = blockIdx.y;           // 0: xl, 1: xr
  const int bn = half * 256;

  v4f acc[4][4];
#pragma unroll
  for (int m = 0; m < 4; ++m)
#pragma unroll
    for (int n = 0; n < 4; ++n) acc[m][n] = (v4f)(0.f);

  // A staging: 256 tasks (64 rows x 4 slots); source oct pre-swizzled
  const int arow = tid >> 2, aslot = tid & 3;
  const int aoct = aslot ^ ((arow >> 1) & 3);
  const size_t gaBase = (size_t)(bm + arow) * K + aoct * 8;
  short* AhW = Ah + wid * 512;  // linear dest: base + lane*16B
  short* AlW = Al + wid * 512;

  for (int k0 = 0; k0 < K; k0 += 32) {
    gl_lds16(Ah_g + gaBase + k0, AhW);
    gl_lds16(Al_g + gaBase + k0, AlW);
#pragma unroll
    for (int it = 0; it < 4; ++it) {
      int task = it * 256 + tid;
      int col = task >> 2, slot = task & 3;
      int oct = slot ^ ((col >> 1) & 3);
      size_t gb = (size_t)(bn + col) * K + k0 + oct * 8;
      gl_lds16(Bth + gb, Bh + it * 2048 + wid * 512);
      gl_lds16(Btl + gb, Bl + it * 2048 + wid * 512);
    }
    __syncthreads();

    v8s a_h[4], a_l[4], b_h[4], b_l[4];
#pragma unroll
    for (int m = 0; m < 4; ++m) {
      int r = m * 16 + l15;
      int s = g ^ ((r >> 1) & 3);
      a_h[m] = *(const v8s*)&Ah[r * 32 + s * 8];
    }
#pragma unroll
    for (int n = 0; n < 4; ++n) {
      int c = wid * 64 + n * 16 + l15;
      int s = g ^ ((c >> 1) & 3);
      b_h[n] = *(const v8s*)&Bh[c * 32 + s * 8];
    }
#pragma unroll
    for (int m = 0; m < 4; ++m)
#pragma unroll
      for (int n = 0; n < 4; ++n)
        acc[m][n] = __builtin_amdgcn_mfma_f32_16x16x32_bf16(a_h[m], b_h[n], acc[m][n], 0, 0, 0);
#pragma unroll
    for (int n = 0; n < 4; ++n) {
      int c = wid * 64 + n * 16 + l15;
      int s = g ^ ((c >> 1) & 3);
      b_l[n] = *(const v8s*)&Bl[c * 32 + s * 8];
    }
#pragma unroll
    for (int m = 0; m < 4; ++m)
#pragma unroll
      for (int n = 0; n < 4; ++n)
        acc[m][n] = __builtin_amdgcn_mfma_f32_16x16x32_bf16(a_h[m], b_l[n], acc[m][n], 0, 0, 0);
#pragma unroll
    for (int m = 0; m < 4; ++m) {
      int r = m * 16 + l15;
      int s = g ^ ((r >> 1) & 3);
      a_l[m] = *(const v8s*)&Al[r * 32 + s * 8];
    }
#pragma unroll
    for (int m = 0; m < 4; ++m)
#pragma unroll
      for (int n = 0; n < 4; ++n)
        acc[m][n] = __builtin_amdgcn_mfma_f32_16x16x32_bf16(a_l[m], b_h[n], acc[m][n], 0, 0, 0);
    __syncthreads();
  }

  // ---- epilogue: per-wave LDS transpose, vectorized bf16 stores ----
  float* scr = (float*)Bh + wid * 320;       // 16 rows x stride 20 floats
  const int erow = lane >> 2, ecq = lane & 3;
  unsigned short* outp = half ? xr_bf : xl_bf;
  const float* bias = half ? br : bl;
#pragma unroll
  for (int m = 0; m < 4; ++m) {
#pragma unroll
    for (int n = 0; n < 4; ++n) {
#pragma unroll
      for (int r = 0; r < 4; ++r) scr[(g * 4 + r) * 20 + l15] = acc[m][n][r];
      float4 v = *(const float4*)&scr[erow * 20 + ecq * 4];
      int row = bm + m * 16 + erow;
      if (row < Nreal) {
        int col = wid * 64 + n * 16 + ecq * 4;
        float4 bv = *(const float4*)&bias[col];
        ushort4 u;
        u.x = f2bf(v.x + bv.x); u.y = f2bf(v.y + bv.y);
        u.z = f2bf(v.z + bv.z); u.w = f2bf(v.w + bv.w);
        *(ushort4*)&outp[(size_t)row * 256 + col] = u;
      }
    }
  }
}

// ---------------- fused GATv2 edge pass (H=8, C=32), wave per dst node ------
// Gathers bf16 xl rows (512B/edge); emits hi/lo bf16 planes for next GEMM.

__global__ __launch_bounds__(256) void k_edge(
    const unsigned short* __restrict__ xl_bf,  // [N,256] bf16
    const unsigned short* __restrict__ xr_bf,  // [N,256] bf16
    const int* __restrict__ offs, const int* __restrict__ csr_src,
    const float* __restrict__ att,   // [8*32]
    const float* __restrict__ bias,  // [256]
    unsigned short* __restrict__ hh,  // [Npad,256] bf16 hi
    unsigned short* __restrict__ hl,  // [Npad,256] bf16 lo
    int n) {
  int lane = threadIdx.x & 63;
  int node = blockIdx.x * (blockDim.x >> 6) + (threadIdx.x >> 6);
  if (node >= n) return;

  float4 att4 = *(const float4*)&att[lane * 4];
  ushort4 ur = *(const ushort4*)&xr_bf[(size_t)node * 256 + lane * 4];
  float xr0 = bf2f(ur.x), xr1 = bf2f(ur.y), xr2 = bf2f(ur.z), xr3 = bf2f(ur.w);

  float m = -INFINITY, d = 0.f;
  float ax = 0.f, ay = 0.f, az = 0.f, aw = 0.f;

  int e0 = offs[node], e1 = offs[node + 1];
  for (int e = e0 - 1; e < e1; ++e) {
    int j = (e < e0) ? node : csr_src[e];  // self-loop first
    ushort4 u = *(const ushort4*)&xl_bf[(size_t)j * 256 + lane * 4];
    float x0 = bf2f(u.x), x1 = bf2f(u.y), x2 = bf2f(u.z), x3 = bf2f(u.w);
    float p = lrelu(x0 + xr0) * att4.x
            + lrelu(x1 + xr1) * att4.y
            + lrelu(x2 + xr2) * att4.z
            + lrelu(x3 + xr3) * att4.w;
    p += __shfl_xor(p, 1);
    p += __shfl_xor(p, 2);
    p += __shfl_xor(p, 4);  // per-head score, replicated over the 8-lane group
    if (p <= m) {
      float w = __expf(p - m);
      d += w;
      ax = fmaf(w, x0, ax); ay = fmaf(w, x1, ay);
      az = fmaf(w, x2, az); aw = fmaf(w, x3, aw);
    } else {
      float r = __expf(m - p);  // first edge: m=-inf -> r=0
      d = fmaf(d, r, 1.f);
      ax = fmaf(ax, r, x0); ay = fmaf(ay, r, x1);
      az = fmaf(az, r, x2); aw = fmaf(aw, r, x3);
      m = p;
    }
  }
  float inv = 1.f / (d + 1e-16f);
  float4 b4 = *(const float4*)&bias[lane * 4];
  float o0 = elu1(fmaf(ax, inv, b4.x));
  float o1 = elu1(fmaf(ay, inv, b4.y));
  float o2 = elu1(fmaf(az, inv, b4.z));
  float o3 = elu1(fmaf(aw, inv, b4.w));
  ushort4 uh, ul;
  uh.x = f2bf(o0); ul.x = f2bf(o0 - bf2f(uh.x));
  uh.y = f2bf(o1); ul.y = f2bf(o1 - bf2f(uh.y));
  uh.z = f2bf(o2); ul.z = f2bf(o2 - bf2f(uh.z));
  uh.w = f2bf(o3); ul.w = f2bf(o3 - bf2f(uh.w));
  *(ushort4*)&hh[(size_t)node * 256 + lane * 4] = uh;
  *(ushort4*)&hl[(size_t)node * 256 + lane * 4] = ul;
}

// ---------------- layer 3: skinny linear (256->2 twice), wave per node ------

__global__ __launch_bounds__(256) void k_lin3(
    const unsigned short* __restrict__ hh, const unsigned short* __restrict__ hl,
    const float* __restrict__ Wl, const float* __restrict__ bl,
    const float* __restrict__ Wr, const float* __restrict__ br,
    float* __restrict__ xlr3,  // [N,4] = {xl0,xl1,xr0,xr1}
    int n) {
  int lane = threadIdx.x & 63;
  int node = blockIdx.x * (blockDim.x >> 6) + (threadIdx.x >> 6);
  if (node >= n) return;
  ushort4 uh = *(const ushort4*)&hh[(size_t)node * 256 + lane * 4];
  ushort4 ul = *(const ushort4*)&hl[(size_t)node * 256 + lane * 4];
  float hv[4] = {bf2f(uh.x) + bf2f(ul.x), bf2f(uh.y) + bf2f(ul.y),
                 bf2f(uh.z) + bf2f(ul.z), bf2f(uh.w) + bf2f(ul.w)};
  float al0 = 0.f, al1 = 0.f, ar0 = 0.f, ar1 = 0.f;
#pragma unroll
  for (int j = 0; j < 4; ++j) {
    int k = lane * 4 + j;
    al0 = fmaf(hv[j], Wl[k * 2 + 0], al0);
    al1 = fmaf(hv[j], Wl[k * 2 + 1], al1);
    ar0 = fmaf(hv[j], Wr[k * 2 + 0], ar0);
    ar1 = fmaf(hv[j], Wr[k * 2 + 1], ar1);
  }
#pragma unroll
  for (int s = 1; s < 64; s <<= 1) {
    al0 += __shfl_xor(al0, s);
    al1 += __shfl_xor(al1, s);
    ar0 += __shfl_xor(ar0, s);
    ar1 += __shfl_xor(ar1, s);
  }
  if (lane == 0) {
    float4 o = make_float4(al0 + bl[0], al1 + bl[1], ar0 + br[0], ar1 + br[1]);
    *(float4*)&xlr3[(size_t)node * 4] = o;
  }
}

// ---------------- layer 3 edge pass + log_softmax, thread per node ----------

__global__ void k_edge3(const float* __restrict__ xlr3,
                        const int* __restrict__ offs, const int* __restrict__ csr_src,
                        const float* __restrict__ att,  // [2]
                        const float* __restrict__ b,    // [2]
                        float* __restrict__ out, int n) {
  int i = blockIdx.x * blockDim.x + threadIdx.x;
  if (i >= n) return;
  float a0 = att[0], a1 = att[1];
  float xr0 = xlr3[(size_t)i * 4 + 2], xr1 = xlr3[(size_t)i * 4 + 3];
  float m = -INFINITY, d = 0.f, ac0 = 0.f, ac1 = 0.f;
  int e0 = offs[i], e1 = offs[i + 1];
  for (int e = e0 - 1; e < e1; ++e) {
    int j = (e < e0) ? i : csr_src[e];
    float xl0 = xlr3[(size_t)j * 4 + 0], xl1 = xlr3[(size_t)j * 4 + 1];
    float p = lrelu(xl0 + xr0) * a0 + lrelu(xl1 + xr1) * a1;
    if (p <= m) {
      float w = __expf(p - m);
      d += w; ac0 = fmaf(w, xl0, ac0); ac1 = fmaf(w, xl1, ac1);
    } else {
      float r = __expf(m - p);
      d = fmaf(d, r, 1.f);
      ac0 = fmaf(ac0, r, xl0); ac1 = fmaf(ac1, r, xl1);
      m = p;
    }
  }
  float inv = 1.f / (d + 1e-16f);
  float o0 = fmaf(ac0, inv, b[0]);
  float o1 = fmaf(ac1, inv, b[1]);
  float mx = fmaxf(o0, o1);
  float lse = mx + logf(expf(o0 - mx) + expf(o1 - mx));
  out[(size_t)i * 2 + 0] = o0 - lse;
  out[(size_t)i * 2 + 1] = o1 - lse;
}

// ---------------------------------------------------------------------------

static inline size_t align_up(size_t v, size_t a) { return (v + a - 1) & ~(a - 1); }

extern "C" void kernel_launch(void* const* d_in, const int* in_sizes, int n_in,
                              void* d_out, int out_size, void* d_ws, size_t ws_size,
                              hipStream_t stream) {
  const float* x    = (const float*)d_in[0];
  const int*   ei   = (const int*)d_in[1];
  const float* Wl1  = (const float*)d_in[2];
  const float* bl1  = (const float*)d_in[3];
  const float* Wr1  = (const float*)d_in[4];
  const float* br1  = (const float*)d_in[5];
  const float* att1 = (const float*)d_in[6];
  const float* b1   = (const float*)d_in[7];
  const float* Wl3  = (const float*)d_in[8];
  const float* bl3  = (const float*)d_in[9];
  const float* Wr3  = (const float*)d_in[10];
  const float* br3  = (const float*)d_in[11];
  const float* att3 = (const float*)d_in[12];
  const float* b3   = (const float*)d_in[13];
  const float* Wl2  = (const float*)d_in[14];
  const float* bl2  = (const float*)d_in[15];
  const float* Wr2  = (const float*)d_in[16];
  const float* br2  = (const float*)d_in[17];
  const float* att2 = (const float*)d_in[18];
  const float* b2   = (const float*)d_in[19];

  const int N = in_sizes[0] / 128;  // 50000
  const int E = in_sizes[1] / 2;    // 400000
  const int Npad = ((N + 63) / 64) * 64;  // 50048
  const int* srcp = ei;
  const int* dstp = ei + E;

  // workspace layout
  char* w = (char*)d_ws;
  size_t off = 0;
  int* deg     = (int*)(w + off); off = align_up(off + (size_t)N * 4, 256);
  int* offs    = (int*)(w + off); off = align_up(off + (size_t)(N + 1) * 4, 256);
  int* cursor  = (int*)(w + off); off = align_up(off + (size_t)N * 4, 256);
  int* csr_src = (int*)(w + off); off = align_up(off + (size_t)E * 4, 256);
  int* bsum    = (int*)(w + off); off = align_up(off + (size_t)256 * 4, 256);
  unsigned short* xh_g = (unsigned short*)(w + off); off = align_up(off + (size_t)Npad * 128 * 2, 256);
  unsigned short* xl_g = (unsigned short*)(w + off); off = align_up(off + (size_t)Npad * 128 * 2, 256);
  unsigned short* hh   = (unsigned short*)(w + off); off = align_up(off + (size_t)Npad * 256 * 2, 256);
  unsigned short* hl   = (unsigned short*)(w + off); off = align_up(off + (size_t)Npad * 256 * 2, 256);
  unsigned short* xlbf = (unsigned short*)(w + off); off = align_up(off + (size_t)N * 256 * 2, 256);
  unsigned short* xrbf = (unsigned short*)(w + off); off = align_up(off + (size_t)N * 256 * 2, 256);
  float* xlr3  = (float*)(w + off); off = align_up(off + (size_t)N * 4 * 4, 256);
  unsigned short* Bt1h = (unsigned short*)(w + off); off = align_up(off + (size_t)512 * 128 * 2, 256);
  unsigned short* Bt1l = (unsigned short*)(w + off); off = align_up(off + (size_t)512 * 128 * 2, 256);
  unsigned short* Bt2h = (unsigned short*)(w + off); off = align_up(off + (size_t)512 * 256 * 2, 256);
  unsigned short* Bt2l = (unsigned short*)(w + off); off = align_up(off + (size_t)512 * 256 * 2, 256);
  (void)ws_size;

  const int nb = (N + 1023) / 1024;

  // ---- build CSR (incoming edges per dst), reused by all 3 layers ----
  hipMemsetAsync(deg, 0, (size_t)N * 4, stream);
  k_count<<<(E + 255) / 256, 256, 0, stream>>>(dstp, deg, E);
  k_bsum<<<nb, 256, 0, stream>>>(deg, N, bsum);
  k_offsets<<<nb, 256, 0, stream>>>(deg, bsum, nb, N, offs, cursor);
  k_scatter<<<(E + 255) / 256, 256, 0, stream>>>(srcp, dstp, cursor, csr_src, E);

  // ---- pre-split weights and x ----
  k_split<<<(512 * 128 + 255) / 256, 256, 0, stream>>>(Wl1, Wr1, 128, 7, Bt1h, Bt1l);
  k_split<<<(512 * 256 + 255) / 256, 256, 0, stream>>>(Wl3, Wr3, 256, 8, Bt2h, Bt2l);
  {
    int total4 = Npad * 128 / 4;
    k_splitA<<<(total4 + 255) / 256, 256, 0, stream>>>(x, N, total4, xh_g, xl_g);
  }
  // zero the pad rows of the h planes (written by k_edge only for rows < N)
  hipMemsetAsync(hh + (size_t)N * 256, 0, (size_t)(Npad - N) * 256 * 2, stream);
  hipMemsetAsync(hl + (size_t)N * 256, 0, (size_t)(Npad - N) * 256 * 2, stream);

  dim3 ggrid(Npad / 64, 2);
  int nodeBlocks = (N + 3) / 4;  // 4 waves (nodes) per 256-thread block

  // ---- layer 1: 128 -> 8x32, concat, ELU ----
  k_gemm_mfma<<<ggrid, 256, 0, stream>>>(xh_g, xl_g, N, 128, Bt1h, Bt1l, bl1, br1, xlbf, xrbf);
  k_edge<<<nodeBlocks, 256, 0, stream>>>(xlbf, xrbf, offs, csr_src, att1, b1, hh, hl, N);

  // ---- layer 2: 256 -> 8x32, concat, ELU ----
  k_gemm_mfma<<<ggrid, 256, 0, stream>>>(hh, hl, N, 256, Bt2h, Bt2l, bl3, br3, xlbf, xrbf);
  k_edge<<<nodeBlocks, 256, 0, stream>>>(xlbf, xrbf, offs, csr_src, att3, b3, hh, hl, N);

  // ---- layer 3: 256 -> 1x2, mean(=identity), log_softmax ----
  k_lin3<<<nodeBlocks, 256, 0, stream>>>(hh, hl, Wl2, bl2, Wr2, br2, xlr3, N);
  k_edge3<<<(N + 255) / 256, 256, 0, stream>>>(xlr3, offs, csr_src, att2, b2,
                                               (float*)d_out, N);
}

// Round 6
// 278.942 us; speedup vs baseline: 2.2408x; 1.2525x over previous
//
#include <hip/hip_runtime.h>
#include <cstdint>
#include <cstddef>

// ---------------------------------------------------------------------------
// GATv2 3-layer forward on MI355X.
//   Activations bf16 (validated error budget); weights bf16 hi+lo.
//   k_gemm_mfma : 2-product MFMA (A_hi x (B_hi + B_lo)), tile 64x256,
//                 global_load_lds staging (source pre-swizzled), LDS-transpose
//                 vectorized bf16 epilogue.
//   k_edge      : branchless online-softmax, 2-edge pairwise merge,
//                 self-loop as initial state; single bf16 h plane out.
// Graph CSR built once (device-wide scan), reused 3x.
// ---------------------------------------------------------------------------

typedef __attribute__((ext_vector_type(8))) short v8s;
typedef __attribute__((ext_vector_type(4))) float v4f;

__device__ __forceinline__ float lrelu(float v) { return fmaxf(v, 0.2f * v); }
__device__ __forceinline__ float elu1(float v)  { return v > 0.f ? v : expm1f(v); }

__device__ __forceinline__ unsigned short f2bf(float f) {  // RTNE fp32->bf16
  unsigned int u = __float_as_uint(f);
  unsigned int r = (u + 0x7FFFu + ((u >> 16) & 1u)) >> 16;
  return (unsigned short)r;
}
__device__ __forceinline__ float bf2f(unsigned short s) {
  return __uint_as_float(((unsigned int)s) << 16);
}

__device__ __forceinline__ void gl_lds16(const void* g, void* l) {
  __builtin_amdgcn_global_load_lds(
      (const __attribute__((address_space(1))) unsigned int*)g,
      (__attribute__((address_space(3))) unsigned int*)l, 16, 0, 0);
}

// ---------------- CSR build ----------------

__global__ void k_count(const int* __restrict__ dst, int* __restrict__ deg, int E) {
  int e = blockIdx.x * blockDim.x + threadIdx.x;
  if (e < E) atomicAdd(&deg[dst[e]], 1);
}

__global__ __launch_bounds__(256) void k_bsum(const int* __restrict__ deg, int n,
                                              int* __restrict__ bsum) {
  __shared__ int red[256];
  int t = threadIdx.x, bid = blockIdx.x;
  int i0 = bid * 1024 + t * 4;
  int s = 0;
  if (i0 + 3 < n) {
    int4 v = *(const int4*)&deg[i0];
    s = v.x + v.y + v.z + v.w;
  } else {
#pragma unroll
    for (int j = 0; j < 4; ++j)
      if (i0 + j < n) s += deg[i0 + j];
  }
  red[t] = s;
  __syncthreads();
  for (int off = 128; off > 0; off >>= 1) {
    if (t < off) red[t] += red[t + off];
    __syncthreads();
  }
  if (t == 0) bsum[bid] = red[0];
}

__global__ __launch_bounds__(256) void k_offsets(const int* __restrict__ deg,
                                                 const int* __restrict__ bsum,
                                                 int nb, int n,
                                                 int* __restrict__ offs,
                                                 int* __restrict__ cursor) {
  __shared__ int sc[256];
  int t = threadIdx.x, bid = blockIdx.x;
  int base = 0;
  for (int b = 0; b < bid; ++b) base += bsum[b];
  int i0 = bid * 1024 + t * 4;
  int v0 = 0, v1 = 0, v2 = 0, v3 = 0;
  if (i0 + 3 < n) {
    int4 v = *(const int4*)&deg[i0];
    v0 = v.x; v1 = v.y; v2 = v.z; v3 = v.w;
  } else {
    if (i0 < n)     v0 = deg[i0];
    if (i0 + 1 < n) v1 = deg[i0 + 1];
    if (i0 + 2 < n) v2 = deg[i0 + 2];
    if (i0 + 3 < n) v3 = deg[i0 + 3];
  }
  int s = v0 + v1 + v2 + v3;
  sc[t] = s;
  __syncthreads();
  for (int off = 1; off < 256; off <<= 1) {
    int x = (t >= off) ? sc[t - off] : 0;
    __syncthreads();
    sc[t] += x;
    __syncthreads();
  }
  int run = base + sc[t] - s;
  int o0 = run, o1 = run + v0, o2 = o1 + v1, o3 = o2 + v2;
  if (i0 + 3 < n) {
    *(int4*)&offs[i0] = make_int4(o0, o1, o2, o3);
    *(int4*)&cursor[i0] = make_int4(o0, o1, o2, o3);
  } else {
    if (i0 < n)     { offs[i0] = o0;     cursor[i0] = o0; }
    if (i0 + 1 < n) { offs[i0 + 1] = o1; cursor[i0 + 1] = o1; }
    if (i0 + 2 < n) { offs[i0 + 2] = o2; cursor[i0 + 2] = o2; }
    if (i0 + 3 < n) { offs[i0 + 3] = o3; cursor[i0 + 3] = o3; }
  }
  if (bid == nb - 1 && t == 255) offs[n] = base + sc[255];
}

__global__ void k_scatter(const int* __restrict__ src, const int* __restrict__ dst,
                          int* __restrict__ cursor, int* __restrict__ csr_src, int E) {
  int e = blockIdx.x * blockDim.x + threadIdx.x;
  if (e < E) {
    int pos = atomicAdd(&cursor[dst[e]], 1);
    csr_src[pos] = src[e];
  }
}

// ---------------- weight pre-split: Bt[n][k] = W[k][n] as bf16 hi/lo --------

__global__ void k_split(const float* __restrict__ Wl, const float* __restrict__ Wr,
                        int K, int logK,
                        unsigned short* __restrict__ Bth,
                        unsigned short* __restrict__ Btl) {
  int idx = blockIdx.x * blockDim.x + threadIdx.x;
  if (idx >= 512 * K) return;
  int n = idx >> logK;
  int k = idx & (K - 1);
  float w = (n < 256) ? Wl[(size_t)k * 256 + n] : Wr[(size_t)k * 256 + (n - 256)];
  unsigned short h = f2bf(w);
  Bth[idx] = h;
  Btl[idx] = f2bf(w - bf2f(h));
}

// ---------------- input quantize: x[N,128] fp32 -> bf16 plane [Npad,128] ----

__global__ void k_quantA(const float* __restrict__ X, int Nreal, int total4,
                         unsigned short* __restrict__ Hh) {
  int idx = blockIdx.x * blockDim.x + threadIdx.x;  // 4 elems each
  if (idx >= total4) return;
  int row = idx >> 5;  // (idx*4)>>7, K=128
  ushort4 uh;
  if (row < Nreal) {
    float4 v = *(const float4*)&X[(size_t)idx * 4];
    uh.x = f2bf(v.x); uh.y = f2bf(v.y); uh.z = f2bf(v.z); uh.w = f2bf(v.w);
  } else {
    uh = make_ushort4(0, 0, 0, 0);
  }
  *(ushort4*)&Hh[(size_t)idx * 4] = uh;
}

// ---------------- 2-product MFMA GEMM, tile 64x256 --------------------------
// grid (Npad/64, 2): y=0 -> xl half (cols 0..255), y=1 -> xr half.
// acc += A_hi*B_hi; acc += A_hi*B_lo.
// Staging: global_load_lds(16B), linear LDS dest, slot-XOR on global source.

__global__ __launch_bounds__(256) void k_gemm_mfma(
    const unsigned short* __restrict__ Ah_g,  // [Npad,K] bf16
    int Nreal, int K,
    const unsigned short* __restrict__ Bth, const unsigned short* __restrict__ Btl,
    const float* __restrict__ bl, const float* __restrict__ br,
    unsigned short* __restrict__ xl_bf, unsigned short* __restrict__ xr_bf) {
  __shared__ __align__(16) short Ah[64 * 32];
  __shared__ __align__(16) short Bh[256 * 32];
  __shared__ __align__(16) short Bl[256 * 32];

  const int tid = threadIdx.x;
  const int lane = tid & 63;
  const int wid = tid >> 6;
  const int l15 = lane & 15, g = lane >> 4;
  const int bm = blockIdx.x * 64;
  const int half = blockIdx.y;           // 0: xl, 1: xr
  const int bn = half * 256;

  v4f acc[4][4];
#pragma unroll
  for (int m = 0; m < 4; ++m)
#pragma unroll
    for (int n = 0; n < 4; ++n) acc[m][n] = (v4f)(0.f);

  const int arow = tid >> 2, aslot = tid & 3;
  const int aoct = aslot ^ ((arow >> 1) & 3);
  const size_t gaBase = (size_t)(bm + arow) * K + aoct * 8;
  short* AhW = Ah + wid * 512;  // linear dest: wave base + lane*16B

  for (int k0 = 0; k0 < K; k0 += 32) {
    gl_lds16(Ah_g + gaBase + k0, AhW);
#pragma unroll
    for (int it = 0; it < 4; ++it) {
      int task = it * 256 + tid;
      int col = task >> 2, slot = task & 3;
      int oct = slot ^ ((col >> 1) & 3);
      size_t gb = (size_t)(bn + col) * K + k0 + oct * 8;
      gl_lds16(Bth + gb, Bh + it * 2048 + wid * 512);
      gl_lds16(Btl + gb, Bl + it * 2048 + wid * 512);
    }
    __syncthreads();

    v8s a_h[4], b_h[4], b_l[4];
#pragma unroll
    for (int m = 0; m < 4; ++m) {
      int r = m * 16 + l15;
      int s = g ^ ((r >> 1) & 3);
      a_h[m] = *(const v8s*)&Ah[r * 32 + s * 8];
    }
#pragma unroll
    for (int n = 0; n < 4; ++n) {
      int c = wid * 64 + n * 16 + l15;
      int s = g ^ ((c >> 1) & 3);
      b_h[n] = *(const v8s*)&Bh[c * 32 + s * 8];
    }
#pragma unroll
    for (int m = 0; m < 4; ++m)
#pragma unroll
      for (int n = 0; n < 4; ++n)
        acc[m][n] = __builtin_amdgcn_mfma_f32_16x16x32_bf16(a_h[m], b_h[n], acc[m][n], 0, 0, 0);
#pragma unroll
    for (int n = 0; n < 4; ++n) {
      int c = wid * 64 + n * 16 + l15;
      int s = g ^ ((c >> 1) & 3);
      b_l[n] = *(const v8s*)&Bl[c * 32 + s * 8];
    }
#pragma unroll
    for (int m = 0; m < 4; ++m)
#pragma unroll
      for (int n = 0; n < 4; ++n)
        acc[m][n] = __builtin_amdgcn_mfma_f32_16x16x32_bf16(a_h[m], b_l[n], acc[m][n], 0, 0, 0);
    __syncthreads();
  }

  // ---- epilogue: per-wave LDS transpose, vectorized bf16 stores ----
  float* scr = (float*)Bh + wid * 320;       // 16 rows x stride 20 floats
  const int erow = lane >> 2, ecq = lane & 3;
  unsigned short* outp = half ? xr_bf : xl_bf;
  const float* bias = half ? br : bl;
#pragma unroll
  for (int m = 0; m < 4; ++m) {
#pragma unroll
    for (int n = 0; n < 4; ++n) {
#pragma unroll
      for (int r = 0; r < 4; ++r) scr[(g * 4 + r) * 20 + l15] = acc[m][n][r];
      float4 v = *(const float4*)&scr[erow * 20 + ecq * 4];
      int row = bm + m * 16 + erow;
      if (row < Nreal) {
        int col = wid * 64 + n * 16 + ecq * 4;
        float4 bv = *(const float4*)&bias[col];
        ushort4 u;
        u.x = f2bf(v.x + bv.x); u.y = f2bf(v.y + bv.y);
        u.z = f2bf(v.z + bv.z); u.w = f2bf(v.w + bv.w);
        *(ushort4*)&outp[(size_t)row * 256 + col] = u;
      }
    }
  }
}

// ---------------- fused GATv2 edge pass (H=8, C=32), wave per dst node ------
// Branchless online softmax, 2-edge pairwise merge, self-loop = initial state.

__global__ __launch_bounds__(256) void k_edge(
    const unsigned short* __restrict__ xl_bf,  // [N,256] bf16
    const unsigned short* __restrict__ xr_bf,  // [N,256] bf16
    const int* __restrict__ offs, const int* __restrict__ csr_src,
    const float* __restrict__ att,   // [8*32]
    const float* __restrict__ bias,  // [256]
    unsigned short* __restrict__ hout,  // [Npad,256] bf16
    int n) {
  int lane = threadIdx.x & 63;
  int node = blockIdx.x * (blockDim.x >> 6) + (threadIdx.x >> 6);
  if (node >= n) return;

  float4 att4 = *(const float4*)&att[lane * 4];
  ushort4 ur = *(const ushort4*)&xr_bf[(size_t)node * 256 + lane * 4];
  float xr0 = bf2f(ur.x), xr1 = bf2f(ur.y), xr2 = bf2f(ur.z), xr3 = bf2f(ur.w);

  // self-loop as initial state: m = p_self, d = 1, acc = xl(node)
  ushort4 us = *(const ushort4*)&xl_bf[(size_t)node * 256 + lane * 4];
  float ax = bf2f(us.x), ay = bf2f(us.y), az = bf2f(us.z), aw = bf2f(us.w);
  float p = lrelu(ax + xr0) * att4.x + lrelu(ay + xr1) * att4.y
          + lrelu(az + xr2) * att4.z + lrelu(aw + xr3) * att4.w;
  p += __shfl_xor(p, 1);
  p += __shfl_xor(p, 2);
  p += __shfl_xor(p, 4);
  float m = p, d = 1.f;

  int e0 = offs[node], e1 = offs[node + 1];
  int e = e0;
  for (; e + 1 < e1; e += 2) {
    int j1 = csr_src[e], j2 = csr_src[e + 1];
    ushort4 u1 = *(const ushort4*)&xl_bf[(size_t)j1 * 256 + lane * 4];
    ushort4 u2 = *(const ushort4*)&xl_bf[(size_t)j2 * 256 + lane * 4];
    float x10 = bf2f(u1.x), x11 = bf2f(u1.y), x12 = bf2f(u1.z), x13 = bf2f(u1.w);
    float x20 = bf2f(u2.x), x21 = bf2f(u2.y), x22 = bf2f(u2.z), x23 = bf2f(u2.w);
    float p1 = lrelu(x10 + xr0) * att4.x + lrelu(x11 + xr1) * att4.y
             + lrelu(x12 + xr2) * att4.z + lrelu(x13 + xr3) * att4.w;
    float p2 = lrelu(x20 + xr0) * att4.x + lrelu(x21 + xr1) * att4.y
             + lrelu(x22 + xr2) * att4.z + lrelu(x23 + xr3) * att4.w;
    p1 += __shfl_xor(p1, 1); p2 += __shfl_xor(p2, 1);
    p1 += __shfl_xor(p1, 2); p2 += __shfl_xor(p2, 2);
    p1 += __shfl_xor(p1, 4); p2 += __shfl_xor(p2, 4);
    // pair-local softmax state
    float m12 = fmaxf(p1, p2);
    float w1 = __expf(p1 - m12), w2 = __expf(p2 - m12);
    float d12 = w1 + w2;
    float c0 = fmaf(w1, x10, w2 * x20);
    float c1 = fmaf(w1, x11, w2 * x21);
    float c2 = fmaf(w1, x12, w2 * x22);
    float c3 = fmaf(w1, x13, w2 * x23);
    // merge into running state (branchless)
    float mN = fmaxf(m, m12);
    float r  = __expf(m - mN);
    float r2 = __expf(m12 - mN);
    d  = fmaf(d, r, d12 * r2);
    ax = fmaf(ax, r, c0 * r2);
    ay = fmaf(ay, r, c1 * r2);
    az = fmaf(az, r, c2 * r2);
    aw = fmaf(aw, r, c3 * r2);
    m = mN;
  }
  if (e < e1) {  // tail edge
    int j = csr_src[e];
    ushort4 u = *(const ushort4*)&xl_bf[(size_t)j * 256 + lane * 4];
    float x0 = bf2f(u.x), x1 = bf2f(u.y), x2 = bf2f(u.z), x3 = bf2f(u.w);
    float p1 = lrelu(x0 + xr0) * att4.x + lrelu(x1 + xr1) * att4.y
             + lrelu(x2 + xr2) * att4.z + lrelu(x3 + xr3) * att4.w;
    p1 += __shfl_xor(p1, 1);
    p1 += __shfl_xor(p1, 2);
    p1 += __shfl_xor(p1, 4);
    float mN = fmaxf(m, p1);
    float r = __expf(m - mN), w1 = __expf(p1 - mN);
    d  = fmaf(d, r, w1);
    ax = fmaf(ax, r, w1 * x0);
    ay = fmaf(ay, r, w1 * x1);
    az = fmaf(az, r, w1 * x2);
    aw = fmaf(aw, r, w1 * x3);
  }

  float inv = 1.f / (d + 1e-16f);
  float4 b4 = *(const float4*)&bias[lane * 4];
  float o0 = elu1(fmaf(ax, inv, b4.x));
  float o1 = elu1(fmaf(ay, inv, b4.y));
  float o2 = elu1(fmaf(az, inv, b4.z));
  float o3 = elu1(fmaf(aw, inv, b4.w));
  ushort4 uo;
  uo.x = f2bf(o0); uo.y = f2bf(o1); uo.z = f2bf(o2); uo.w = f2bf(o3);
  *(ushort4*)&hout[(size_t)node * 256 + lane * 4] = uo;
}

// ---------------- layer 3: skinny linear (256->2 twice), wave per node ------

__global__ __launch_bounds__(256) void k_lin3(
    const unsigned short* __restrict__ hbf,
    const float* __restrict__ Wl, const float* __restrict__ bl,
    const float* __restrict__ Wr, const float* __restrict__ br,
    float* __restrict__ xlr3,  // [N,4] = {xl0,xl1,xr0,xr1}
    int n) {
  int lane = threadIdx.x & 63;
  int node = blockIdx.x * (blockDim.x >> 6) + (threadIdx.x >> 6);
  if (node >= n) return;
  ushort4 uh = *(const ushort4*)&hbf[(size_t)node * 256 + lane * 4];
  float hv[4] = {bf2f(uh.x), bf2f(uh.y), bf2f(uh.z), bf2f(uh.w)};
  float al0 = 0.f, al1 = 0.f, ar0 = 0.f, ar1 = 0.f;
#pragma unroll
  for (int j = 0; j < 4; ++j) {
    int k = lane * 4 + j;
    al0 = fmaf(hv[j], Wl[k * 2 + 0], al0);
    al1 = fmaf(hv[j], Wl[k * 2 + 1], al1);
    ar0 = fmaf(hv[j], Wr[k * 2 + 0], ar0);
    ar1 = fmaf(hv[j], Wr[k * 2 + 1], ar1);
  }
#pragma unroll
  for (int s = 1; s < 64; s <<= 1) {
    al0 += __shfl_xor(al0, s);
    al1 += __shfl_xor(al1, s);
    ar0 += __shfl_xor(ar0, s);
    ar1 += __shfl_xor(ar1, s);
  }
  if (lane == 0) {
    float4 o = make_float4(al0 + bl[0], al1 + bl[1], ar0 + br[0], ar1 + br[1]);
    *(float4*)&xlr3[(size_t)node * 4] = o;
  }
}

// ---------------- layer 3 edge pass + log_softmax, thread per node ----------

__global__ void k_edge3(const float* __restrict__ xlr3,
                        const int* __restrict__ offs, const int* __restrict__ csr_src,
                        const float* __restrict__ att,  // [2]
                        const float* __restrict__ b,    // [2]
                        float* __restrict__ out, int n) {
  int i = blockIdx.x * blockDim.x + threadIdx.x;
  if (i >= n) return;
  float a0 = att[0], a1 = att[1];
  float xr0 = xlr3[(size_t)i * 4 + 2], xr1 = xlr3[(size_t)i * 4 + 3];
  // self-loop first
  float sl0 = xlr3[(size_t)i * 4 + 0], sl1 = xlr3[(size_t)i * 4 + 1];
  float m = lrelu(sl0 + xr0) * a0 + lrelu(sl1 + xr1) * a1;
  float d = 1.f, ac0 = sl0, ac1 = sl1;
  int e0 = offs[i], e1 = offs[i + 1];
  for (int e = e0; e < e1; ++e) {
    int j = csr_src[e];
    float xl0 = xlr3[(size_t)j * 4 + 0], xl1 = xlr3[(size_t)j * 4 + 1];
    float p = lrelu(xl0 + xr0) * a0 + lrelu(xl1 + xr1) * a1;
    float mN = fmaxf(m, p);
    float r = __expf(m - mN), w = __expf(p - mN);
    d = fmaf(d, r, w);
    ac0 = fmaf(ac0, r, w * xl0);
    ac1 = fmaf(ac1, r, w * xl1);
    m = mN;
  }
  float inv = 1.f / (d + 1e-16f);
  float o0 = fmaf(ac0, inv, b[0]);
  float o1 = fmaf(ac1, inv, b[1]);
  float mx = fmaxf(o0, o1);
  float lse = mx + logf(expf(o0 - mx) + expf(o1 - mx));
  out[(size_t)i * 2 + 0] = o0 - lse;
  out[(size_t)i * 2 + 1] = o1 - lse;
}

// ---------------------------------------------------------------------------

static inline size_t align_up(size_t v, size_t a) { return (v + a - 1) & ~(a - 1); }

extern "C" void kernel_launch(void* const* d_in, const int* in_sizes, int n_in,
                              void* d_out, int out_size, void* d_ws, size_t ws_size,
                              hipStream_t stream) {
  const float* x    = (const float*)d_in[0];
  const int*   ei   = (const int*)d_in[1];
  const float* Wl1  = (const float*)d_in[2];
  const float* bl1  = (const float*)d_in[3];
  const float* Wr1  = (const float*)d_in[4];
  const float* br1  = (const float*)d_in[5];
  const float* att1 = (const float*)d_in[6];
  const float* b1   = (const float*)d_in[7];
  const float* Wl3  = (const float*)d_in[8];
  const float* bl3  = (const float*)d_in[9];
  const float* Wr3  = (const float*)d_in[10];
  const float* br3  = (const float*)d_in[11];
  const float* att3 = (const float*)d_in[12];
  const float* b3   = (const float*)d_in[13];
  const float* Wl2  = (const float*)d_in[14];
  const float* bl2  = (const float*)d_in[15];
  const float* Wr2  = (const float*)d_in[16];
  const float* br2  = (const float*)d_in[17];
  const float* att2 = (const float*)d_in[18];
  const float* b2   = (const float*)d_in[19];

  const int N = in_sizes[0] / 128;  // 50000
  const int E = in_sizes[1] / 2;    // 400000
  const int Npad = ((N + 63) / 64) * 64;  // 50048
  const int* srcp = ei;
  const int* dstp = ei + E;

  // workspace layout
  char* w = (char*)d_ws;
  size_t off = 0;
  int* deg     = (int*)(w + off); off = align_up(off + (size_t)N * 4, 256);
  int* offs    = (int*)(w + off); off = align_up(off + (size_t)(N + 1) * 4, 256);
  int* cursor  = (int*)(w + off); off = align_up(off + (size_t)N * 4, 256);
  int* csr_src = (int*)(w + off); off = align_up(off + (size_t)E * 4, 256);
  int* bsum    = (int*)(w + off); off = align_up(off + (size_t)256 * 4, 256);
  unsigned short* x_bf = (unsigned short*)(w + off); off = align_up(off + (size_t)Npad * 128 * 2, 256);
  unsigned short* h_bf = (unsigned short*)(w + off); off = align_up(off + (size_t)Npad * 256 * 2, 256);
  unsigned short* xlbf = (unsigned short*)(w + off); off = align_up(off + (size_t)N * 256 * 2, 256);
  unsigned short* xrbf = (unsigned short*)(w + off); off = align_up(off + (size_t)N * 256 * 2, 256);
  float* xlr3  = (float*)(w + off); off = align_up(off + (size_t)N * 4 * 4, 256);
  unsigned short* Bt1h = (unsigned short*)(w + off); off = align_up(off + (size_t)512 * 128 * 2, 256);
  unsigned short* Bt1l = (unsigned short*)(w + off); off = align_up(off + (size_t)512 * 128 * 2, 256);
  unsigned short* Bt2h = (unsigned short*)(w + off); off = align_up(off + (size_t)512 * 256 * 2, 256);
  unsigned short* Bt2l = (unsigned short*)(w + off); off = align_up(off + (size_t)512 * 256 * 2, 256);
  (void)ws_size;

  const int nb = (N + 1023) / 1024;

  // ---- build CSR (incoming edges per dst), reused by all 3 layers ----
  hipMemsetAsync(deg, 0, (size_t)N * 4, stream);
  k_count<<<(E + 255) / 256, 256, 0, stream>>>(dstp, deg, E);
  k_bsum<<<nb, 256, 0, stream>>>(deg, N, bsum);
  k_offsets<<<nb, 256, 0, stream>>>(deg, bsum, nb, N, offs, cursor);
  k_scatter<<<(E + 255) / 256, 256, 0, stream>>>(srcp, dstp, cursor, csr_src, E);

  // ---- pre-split weights; quantize x ----
  k_split<<<(512 * 128 + 255) / 256, 256, 0, stream>>>(Wl1, Wr1, 128, 7, Bt1h, Bt1l);
  k_split<<<(512 * 256 + 255) / 256, 256, 0, stream>>>(Wl3, Wr3, 256, 8, Bt2h, Bt2l);
  {
    int total4 = Npad * 128 / 4;
    k_quantA<<<(total4 + 255) / 256, 256, 0, stream>>>(x, N, total4, x_bf);
  }
  // zero pad rows of h plane (k_edge writes only rows < N)
  hipMemsetAsync(h_bf + (size_t)N * 256, 0, (size_t)(Npad - N) * 256 * 2, stream);

  dim3 ggrid(Npad / 64, 2);
  int nodeBlocks = (N + 3) / 4;  // 4 waves (nodes) per 256-thread block

  // ---- layer 1: 128 -> 8x32, concat, ELU ----
  k_gemm_mfma<<<ggrid, 256, 0, stream>>>(x_bf, N, 128, Bt1h, Bt1l, bl1, br1, xlbf, xrbf);
  k_edge<<<nodeBlocks, 256, 0, stream>>>(xlbf, xrbf, offs, csr_src, att1, b1, h_bf, N);

  // ---- layer 2: 256 -> 8x32, concat, ELU ----
  k_gemm_mfma<<<ggrid, 256, 0, stream>>>(h_bf, N, 256, Bt2h, Bt2l, bl3, br3, xlbf, xrbf);
  k_edge<<<nodeBlocks, 256, 0, stream>>>(xlbf, xrbf, offs, csr_src, att3, b3, h_bf, N);

  // ---- layer 3: 256 -> 1x2, mean(=identity), log_softmax ----
  k_lin3<<<nodeBlocks, 256, 0, stream>>>(h_bf, Wl2, bl2, Wr2, br2, xlr3, N);
  k_edge3<<<(N + 255) / 256, 256, 0, stream>>>(xlr3, offs, csr_src, att2, b2,
                                               (float*)d_out, N);
}

// Round 7
// 252.251 us; speedup vs baseline: 2.4779x; 1.1058x over previous
//
#include <hip/hip_runtime.h>
#include <cstdint>
#include <cstddef>

// ---------------------------------------------------------------------------
// GATv2 3-layer forward on MI355X.
//   All GEMM operands fp16 (rel err 5e-4, validated budget), fp32 accumulate:
//   k_gemm_mfma : single-product mfma_f32_16x16x32_f16, tile 64x256,
//                 global_load_lds staging (source pre-swizzled), LDS-transpose
//                 vectorized fp16 epilogue. 20 KB LDS.
//   k_edge      : branchless online-softmax, 2-edge pairwise merge,
//                 self-loop as initial state; fp16 h plane out.
// Graph CSR built once (device-wide scan), reused 3x.
// ---------------------------------------------------------------------------

typedef __attribute__((ext_vector_type(8))) _Float16 v8h;
typedef __attribute__((ext_vector_type(4))) float v4f;

__device__ __forceinline__ float lrelu(float v) { return fmaxf(v, 0.2f * v); }
__device__ __forceinline__ float elu1(float v)  { return v > 0.f ? v : expm1f(v); }

__device__ __forceinline__ unsigned short f2h(float f) {
  _Float16 h = (_Float16)f;
  return __builtin_bit_cast(unsigned short, h);
}
__device__ __forceinline__ float h2f(unsigned short s) {
  return (float)__builtin_bit_cast(_Float16, s);
}

__device__ __forceinline__ void gl_lds16(const void* g, void* l) {
  __builtin_amdgcn_global_load_lds(
      (const __attribute__((address_space(1))) unsigned int*)g,
      (__attribute__((address_space(3))) unsigned int*)l, 16, 0, 0);
}

// ---------------- CSR build ----------------

__global__ void k_count(const int* __restrict__ dst, int* __restrict__ deg, int E) {
  int e = blockIdx.x * blockDim.x + threadIdx.x;
  if (e < E) atomicAdd(&deg[dst[e]], 1);
}

__global__ __launch_bounds__(256) void k_bsum(const int* __restrict__ deg, int n,
                                              int* __restrict__ bsum) {
  __shared__ int red[256];
  int t = threadIdx.x, bid = blockIdx.x;
  int i0 = bid * 1024 + t * 4;
  int s = 0;
  if (i0 + 3 < n) {
    int4 v = *(const int4*)&deg[i0];
    s = v.x + v.y + v.z + v.w;
  } else {
#pragma unroll
    for (int j = 0; j < 4; ++j)
      if (i0 + j < n) s += deg[i0 + j];
  }
  red[t] = s;
  __syncthreads();
  for (int off = 128; off > 0; off >>= 1) {
    if (t < off) red[t] += red[t + off];
    __syncthreads();
  }
  if (t == 0) bsum[bid] = red[0];
}

__global__ __launch_bounds__(256) void k_offsets(const int* __restrict__ deg,
                                                 const int* __restrict__ bsum,
                                                 int nb, int n,
                                                 int* __restrict__ offs,
                                                 int* __restrict__ cursor) {
  __shared__ int sc[256];
  int t = threadIdx.x, bid = blockIdx.x;
  int base = 0;
  for (int b = 0; b < bid; ++b) base += bsum[b];
  int i0 = bid * 1024 + t * 4;
  int v0 = 0, v1 = 0, v2 = 0, v3 = 0;
  if (i0 + 3 < n) {
    int4 v = *(const int4*)&deg[i0];
    v0 = v.x; v1 = v.y; v2 = v.z; v3 = v.w;
  } else {
    if (i0 < n)     v0 = deg[i0];
    if (i0 + 1 < n) v1 = deg[i0 + 1];
    if (i0 + 2 < n) v2 = deg[i0 + 2];
    if (i0 + 3 < n) v3 = deg[i0 + 3];
  }
  int s = v0 + v1 + v2 + v3;
  sc[t] = s;
  __syncthreads();
  for (int off = 1; off < 256; off <<= 1) {
    int x = (t >= off) ? sc[t - off] : 0;
    __syncthreads();
    sc[t] += x;
    __syncthreads();
  }
  int run = base + sc[t] - s;
  int o0 = run, o1 = run + v0, o2 = o1 + v1, o3 = o2 + v2;
  if (i0 + 3 < n) {
    *(int4*)&offs[i0] = make_int4(o0, o1, o2, o3);
    *(int4*)&cursor[i0] = make_int4(o0, o1, o2, o3);
  } else {
    if (i0 < n)     { offs[i0] = o0;     cursor[i0] = o0; }
    if (i0 + 1 < n) { offs[i0 + 1] = o1; cursor[i0 + 1] = o1; }
    if (i0 + 2 < n) { offs[i0 + 2] = o2; cursor[i0 + 2] = o2; }
    if (i0 + 3 < n) { offs[i0 + 3] = o3; cursor[i0 + 3] = o3; }
  }
  if (bid == nb - 1 && t == 255) offs[n] = base + sc[255];
}

__global__ void k_scatter(const int* __restrict__ src, const int* __restrict__ dst,
                          int* __restrict__ cursor, int* __restrict__ csr_src, int E) {
  int e = blockIdx.x * blockDim.x + threadIdx.x;
  if (e < E) {
    int pos = atomicAdd(&cursor[dst[e]], 1);
    csr_src[pos] = src[e];
  }
}

// ---------------- weight transpose+quantize: Bt[n][k] = fp16(W[k][n]) -------

__global__ void k_split(const float* __restrict__ Wl, const float* __restrict__ Wr,
                        int K, int logK, unsigned short* __restrict__ Bt) {
  int idx = blockIdx.x * blockDim.x + threadIdx.x;
  if (idx >= 512 * K) return;
  int n = idx >> logK;
  int k = idx & (K - 1);
  float w = (n < 256) ? Wl[(size_t)k * 256 + n] : Wr[(size_t)k * 256 + (n - 256)];
  Bt[idx] = f2h(w);
}

// ---------------- input quantize: x[N,128] fp32 -> fp16 plane [Npad,128] ----

__global__ void k_quantA(const float* __restrict__ X, int Nreal, int total4,
                         unsigned short* __restrict__ Hh) {
  int idx = blockIdx.x * blockDim.x + threadIdx.x;  // 4 elems each
  if (idx >= total4) return;
  int row = idx >> 5;  // (idx*4)>>7, K=128
  ushort4 uh;
  if (row < Nreal) {
    float4 v = *(const float4*)&X[(size_t)idx * 4];
    uh.x = f2h(v.x); uh.y = f2h(v.y); uh.z = f2h(v.z); uh.w = f2h(v.w);
  } else {
    uh = make_ushort4(0, 0, 0, 0);
  }
  *(ushort4*)&Hh[(size_t)idx * 4] = uh;
}

// ---------------- fp16 MFMA GEMM, tile 64x256 -------------------------------
// grid (Npad/64, 2): y=0 -> xl half (cols 0..255), y=1 -> xr half.
// Staging: global_load_lds(16B), linear LDS dest, slot-XOR on global source.

__global__ __launch_bounds__(256) void k_gemm_mfma(
    const unsigned short* __restrict__ A_g,  // [Npad,K] fp16
    int Nreal, int K,
    const unsigned short* __restrict__ Bt,   // [512,K] fp16 (transposed W)
    const float* __restrict__ bl, const float* __restrict__ br,
    unsigned short* __restrict__ xl_h, unsigned short* __restrict__ xr_h) {
  __shared__ __align__(16) short Ah[64 * 32];    // 4 KB
  __shared__ __align__(16) short Bh[256 * 32];   // 16 KB

  const int tid = threadIdx.x;
  const int lane = tid & 63;
  const int wid = tid >> 6;
  const int l15 = lane & 15, g = lane >> 4;
  const int bm = blockIdx.x * 64;
  const int half = blockIdx.y;           // 0: xl, 1: xr
  const int bn = half * 256;

  v4f acc[4][4];
#pragma unroll
  for (int m = 0; m < 4; ++m)
#pragma unroll
    for (int n = 0; n < 4; ++n) acc[m][n] = (v4f)(0.f);

  const int arow = tid >> 2, aslot = tid & 3;
  const int aoct = aslot ^ ((arow >> 1) & 3);
  const size_t gaBase = (size_t)(bm + arow) * K + aoct * 8;
  short* AhW = Ah + wid * 512;  // linear dest: wave base + lane*16B

  for (int k0 = 0; k0 < K; k0 += 32) {
    gl_lds16(A_g + gaBase + k0, AhW);
#pragma unroll
    for (int it = 0; it < 4; ++it) {
      int task = it * 256 + tid;
      int col = task >> 2, slot = task & 3;
      int oct = slot ^ ((col >> 1) & 3);
      size_t gb = (size_t)(bn + col) * K + k0 + oct * 8;
      gl_lds16(Bt + gb, Bh + it * 2048 + wid * 512);
    }
    __syncthreads();

    v8h a_h[4], b_h[4];
#pragma unroll
    for (int m = 0; m < 4; ++m) {
      int r = m * 16 + l15;
      int s = g ^ ((r >> 1) & 3);
      a_h[m] = *(const v8h*)&Ah[r * 32 + s * 8];
    }
#pragma unroll
    for (int n = 0; n < 4; ++n) {
      int c = wid * 64 + n * 16 + l15;
      int s = g ^ ((c >> 1) & 3);
      b_h[n] = *(const v8h*)&Bh[c * 32 + s * 8];
    }
#pragma unroll
    for (int m = 0; m < 4; ++m)
#pragma unroll
      for (int n = 0; n < 4; ++n)
        acc[m][n] = __builtin_amdgcn_mfma_f32_16x16x32_f16(a_h[m], b_h[n], acc[m][n], 0, 0, 0);
    __syncthreads();
  }

  // ---- epilogue: per-wave LDS transpose (reuses Bh), fp16 stores ----
  float* scr = (float*)Bh + wid * 320;       // 16 rows x stride 20 floats
  const int erow = lane >> 2, ecq = lane & 3;
  unsigned short* outp = half ? xr_h : xl_h;
  const float* bias = half ? br : bl;
#pragma unroll
  for (int m = 0; m < 4; ++m) {
#pragma unroll
    for (int n = 0; n < 4; ++n) {
#pragma unroll
      for (int r = 0; r < 4; ++r) scr[(g * 4 + r) * 20 + l15] = acc[m][n][r];
      float4 v = *(const float4*)&scr[erow * 20 + ecq * 4];
      int row = bm + m * 16 + erow;
      if (row < Nreal) {
        int col = wid * 64 + n * 16 + ecq * 4;
        float4 bv = *(const float4*)&bias[col];
        ushort4 u;
        u.x = f2h(v.x + bv.x); u.y = f2h(v.y + bv.y);
        u.z = f2h(v.z + bv.z); u.w = f2h(v.w + bv.w);
        *(ushort4*)&outp[(size_t)row * 256 + col] = u;
      }
    }
  }
}

// ---------------- fused GATv2 edge pass (H=8, C=32), wave per dst node ------
// Branchless online softmax, 2-edge pairwise merge, self-loop = initial state.

__global__ __launch_bounds__(256) void k_edge(
    const unsigned short* __restrict__ xl_h,  // [N,256] fp16
    const unsigned short* __restrict__ xr_h,  // [N,256] fp16
    const int* __restrict__ offs, const int* __restrict__ csr_src,
    const float* __restrict__ att,   // [8*32]
    const float* __restrict__ bias,  // [256]
    unsigned short* __restrict__ hout,  // [Npad,256] fp16
    int n) {
  int lane = threadIdx.x & 63;
  int node = blockIdx.x * (blockDim.x >> 6) + (threadIdx.x >> 6);
  if (node >= n) return;

  float4 att4 = *(const float4*)&att[lane * 4];
  ushort4 ur = *(const ushort4*)&xr_h[(size_t)node * 256 + lane * 4];
  float xr0 = h2f(ur.x), xr1 = h2f(ur.y), xr2 = h2f(ur.z), xr3 = h2f(ur.w);

  // self-loop as initial state: m = p_self, d = 1, acc = xl(node)
  ushort4 us = *(const ushort4*)&xl_h[(size_t)node * 256 + lane * 4];
  float ax = h2f(us.x), ay = h2f(us.y), az = h2f(us.z), aw = h2f(us.w);
  float p = lrelu(ax + xr0) * att4.x + lrelu(ay + xr1) * att4.y
          + lrelu(az + xr2) * att4.z + lrelu(aw + xr3) * att4.w;
  p += __shfl_xor(p, 1);
  p += __shfl_xor(p, 2);
  p += __shfl_xor(p, 4);
  float m = p, d = 1.f;

  int e0 = offs[node], e1 = offs[node + 1];
  int e = e0;
  for (; e + 1 < e1; e += 2) {
    int j1 = csr_src[e], j2 = csr_src[e + 1];
    ushort4 u1 = *(const ushort4*)&xl_h[(size_t)j1 * 256 + lane * 4];
    ushort4 u2 = *(const ushort4*)&xl_h[(size_t)j2 * 256 + lane * 4];
    float x10 = h2f(u1.x), x11 = h2f(u1.y), x12 = h2f(u1.z), x13 = h2f(u1.w);
    float x20 = h2f(u2.x), x21 = h2f(u2.y), x22 = h2f(u2.z), x23 = h2f(u2.w);
    float p1 = lrelu(x10 + xr0) * att4.x + lrelu(x11 + xr1) * att4.y
             + lrelu(x12 + xr2) * att4.z + lrelu(x13 + xr3) * att4.w;
    float p2 = lrelu(x20 + xr0) * att4.x + lrelu(x21 + xr1) * att4.y
             + lrelu(x22 + xr2) * att4.z + lrelu(x23 + xr3) * att4.w;
    p1 += __shfl_xor(p1, 1); p2 += __shfl_xor(p2, 1);
    p1 += __shfl_xor(p1, 2); p2 += __shfl_xor(p2, 2);
    p1 += __shfl_xor(p1, 4); p2 += __shfl_xor(p2, 4);
    // pair-local softmax state
    float m12 = fmaxf(p1, p2);
    float w1 = __expf(p1 - m12), w2 = __expf(p2 - m12);
    float d12 = w1 + w2;
    float c0 = fmaf(w1, x10, w2 * x20);
    float c1 = fmaf(w1, x11, w2 * x21);
    float c2 = fmaf(w1, x12, w2 * x22);
    float c3 = fmaf(w1, x13, w2 * x23);
    // merge into running state (branchless)
    float mN = fmaxf(m, m12);
    float r  = __expf(m - mN);
    float r2 = __expf(m12 - mN);
    d  = fmaf(d, r, d12 * r2);
    ax = fmaf(ax, r, c0 * r2);
    ay = fmaf(ay, r, c1 * r2);
    az = fmaf(az, r, c2 * r2);
    aw = fmaf(aw, r, c3 * r2);
    m = mN;
  }
  if (e < e1) {  // tail edge
    int j = csr_src[e];
    ushort4 u = *(const ushort4*)&xl_h[(size_t)j * 256 + lane * 4];
    float x0 = h2f(u.x), x1 = h2f(u.y), x2 = h2f(u.z), x3 = h2f(u.w);
    float p1 = lrelu(x0 + xr0) * att4.x + lrelu(x1 + xr1) * att4.y
             + lrelu(x2 + xr2) * att4.z + lrelu(x3 + xr3) * att4.w;
    p1 += __shfl_xor(p1, 1);
    p1 += __shfl_xor(p1, 2);
    p1 += __shfl_xor(p1, 4);
    float mN = fmaxf(m, p1);
    float r = __expf(m - mN), w1 = __expf(p1 - mN);
    d  = fmaf(d, r, w1);
    ax = fmaf(ax, r, w1 * x0);
    ay = fmaf(ay, r, w1 * x1);
    az = fmaf(az, r, w1 * x2);
    aw = fmaf(aw, r, w1 * x3);
  }

  float inv = 1.f / (d + 1e-16f);
  float4 b4 = *(const float4*)&bias[lane * 4];
  float o0 = elu1(fmaf(ax, inv, b4.x));
  float o1 = elu1(fmaf(ay, inv, b4.y));
  float o2 = elu1(fmaf(az, inv, b4.z));
  float o3 = elu1(fmaf(aw, inv, b4.w));
  ushort4 uo;
  uo.x = f2h(o0); uo.y = f2h(o1); uo.z = f2h(o2); uo.w = f2h(o3);
  *(ushort4*)&hout[(size_t)node * 256 + lane * 4] = uo;
}

// ---------------- layer 3: skinny linear (256->2 twice), wave per node ------

__global__ __launch_bounds__(256) void k_lin3(
    const unsigned short* __restrict__ hq,
    const float* __restrict__ Wl, const float* __restrict__ bl,
    const float* __restrict__ Wr, const float* __restrict__ br,
    float* __restrict__ xlr3,  // [N,4] = {xl0,xl1,xr0,xr1}
    int n) {
  int lane = threadIdx.x & 63;
  int node = blockIdx.x * (blockDim.x >> 6) + (threadIdx.x >> 6);
  if (node >= n) return;
  ushort4 uh = *(const ushort4*)&hq[(size_t)node * 256 + lane * 4];
  float hv[4] = {h2f(uh.x), h2f(uh.y), h2f(uh.z), h2f(uh.w)};
  float al0 = 0.f, al1 = 0.f, ar0 = 0.f, ar1 = 0.f;
#pragma unroll
  for (int j = 0; j < 4; ++j) {
    int k = lane * 4 + j;
    al0 = fmaf(hv[j], Wl[k * 2 + 0], al0);
    al1 = fmaf(hv[j], Wl[k * 2 + 1], al1);
    ar0 = fmaf(hv[j], Wr[k * 2 + 0], ar0);
    ar1 = fmaf(hv[j], Wr[k * 2 + 1], ar1);
  }
#pragma unroll
  for (int s = 1; s < 64; s <<= 1) {
    al0 += __shfl_xor(al0, s);
    al1 += __shfl_xor(al1, s);
    ar0 += __shfl_xor(ar0, s);
    ar1 += __shfl_xor(ar1, s);
  }
  if (lane == 0) {
    float4 o = make_float4(al0 + bl[0], al1 + bl[1], ar0 + br[0], ar1 + br[1]);
    *(float4*)&xlr3[(size_t)node * 4] = o;
  }
}

// ---------------- layer 3 edge pass + log_softmax, thread per node ----------

__global__ void k_edge3(const float* __restrict__ xlr3,
                        const int* __restrict__ offs, const int* __restrict__ csr_src,
                        const float* __restrict__ att,  // [2]
                        const float* __restrict__ b,    // [2]
                        float* __restrict__ out, int n) {
  int i = blockIdx.x * blockDim.x + threadIdx.x;
  if (i >= n) return;
  float a0 = att[0], a1 = att[1];
  float xr0 = xlr3[(size_t)i * 4 + 2], xr1 = xlr3[(size_t)i * 4 + 3];
  // self-loop first
  float sl0 = xlr3[(size_t)i * 4 + 0], sl1 = xlr3[(size_t)i * 4 + 1];
  float m = lrelu(sl0 + xr0) * a0 + lrelu(sl1 + xr1) * a1;
  float d = 1.f, ac0 = sl0, ac1 = sl1;
  int e0 = offs[i], e1 = offs[i + 1];
  for (int e = e0; e < e1; ++e) {
    int j = csr_src[e];
    float xl0 = xlr3[(size_t)j * 4 + 0], xl1 = xlr3[(size_t)j * 4 + 1];
    float p = lrelu(xl0 + xr0) * a0 + lrelu(xl1 + xr1) * a1;
    float mN = fmaxf(m, p);
    float r = __expf(m - mN), w = __expf(p - mN);
    d = fmaf(d, r, w);
    ac0 = fmaf(ac0, r, w * xl0);
    ac1 = fmaf(ac1, r, w * xl1);
    m = mN;
  }
  float inv = 1.f / (d + 1e-16f);
  float o0 = fmaf(ac0, inv, b[0]);
  float o1 = fmaf(ac1, inv, b[1]);
  float mx = fmaxf(o0, o1);
  float lse = mx + logf(expf(o0 - mx) + expf(o1 - mx));
  out[(size_t)i * 2 + 0] = o0 - lse;
  out[(size_t)i * 2 + 1] = o1 - lse;
}

// ---------------------------------------------------------------------------

static inline size_t align_up(size_t v, size_t a) { return (v + a - 1) & ~(a - 1); }

extern "C" void kernel_launch(void* const* d_in, const int* in_sizes, int n_in,
                              void* d_out, int out_size, void* d_ws, size_t ws_size,
                              hipStream_t stream) {
  const float* x    = (const float*)d_in[0];
  const int*   ei   = (const int*)d_in[1];
  const float* Wl1  = (const float*)d_in[2];
  const float* bl1  = (const float*)d_in[3];
  const float* Wr1  = (const float*)d_in[4];
  const float* br1  = (const float*)d_in[5];
  const float* att1 = (const float*)d_in[6];
  const float* b1   = (const float*)d_in[7];
  const float* Wl3  = (const float*)d_in[8];
  const float* bl3  = (const float*)d_in[9];
  const float* Wr3  = (const float*)d_in[10];
  const float* br3  = (const float*)d_in[11];
  const float* att3 = (const float*)d_in[12];
  const float* b3   = (const float*)d_in[13];
  const float* Wl2  = (const float*)d_in[14];
  const float* bl2  = (const float*)d_in[15];
  const float* Wr2  = (const float*)d_in[16];
  const float* br2  = (const float*)d_in[17];
  const float* att2 = (const float*)d_in[18];
  const float* b2   = (const float*)d_in[19];

  const int N = in_sizes[0] / 128;  // 50000
  const int E = in_sizes[1] / 2;    // 400000
  const int Npad = ((N + 63) / 64) * 64;  // 50048
  const int* srcp = ei;
  const int* dstp = ei + E;

  // workspace layout
  char* w = (char*)d_ws;
  size_t off = 0;
  int* deg     = (int*)(w + off); off = align_up(off + (size_t)N * 4, 256);
  int* offs    = (int*)(w + off); off = align_up(off + (size_t)(N + 1) * 4, 256);
  int* cursor  = (int*)(w + off); off = align_up(off + (size_t)N * 4, 256);
  int* csr_src = (int*)(w + off); off = align_up(off + (size_t)E * 4, 256);
  int* bsum    = (int*)(w + off); off = align_up(off + (size_t)256 * 4, 256);
  unsigned short* x_h  = (unsigned short*)(w + off); off = align_up(off + (size_t)Npad * 128 * 2, 256);
  unsigned short* h_h  = (unsigned short*)(w + off); off = align_up(off + (size_t)Npad * 256 * 2, 256);
  unsigned short* xlh  = (unsigned short*)(w + off); off = align_up(off + (size_t)N * 256 * 2, 256);
  unsigned short* xrh  = (unsigned short*)(w + off); off = align_up(off + (size_t)N * 256 * 2, 256);
  float* xlr3  = (float*)(w + off); off = align_up(off + (size_t)N * 4 * 4, 256);
  unsigned short* Bt1 = (unsigned short*)(w + off); off = align_up(off + (size_t)512 * 128 * 2, 256);
  unsigned short* Bt2 = (unsigned short*)(w + off); off = align_up(off + (size_t)512 * 256 * 2, 256);
  (void)ws_size;

  const int nb = (N + 1023) / 1024;

  // ---- build CSR (incoming edges per dst), reused by all 3 layers ----
  hipMemsetAsync(deg, 0, (size_t)N * 4, stream);
  k_count<<<(E + 255) / 256, 256, 0, stream>>>(dstp, deg, E);
  k_bsum<<<nb, 256, 0, stream>>>(deg, N, bsum);
  k_offsets<<<nb, 256, 0, stream>>>(deg, bsum, nb, N, offs, cursor);
  k_scatter<<<(E + 255) / 256, 256, 0, stream>>>(srcp, dstp, cursor, csr_src, E);

  // ---- quantize weights (transposed) and x to fp16 ----
  k_split<<<(512 * 128 + 255) / 256, 256, 0, stream>>>(Wl1, Wr1, 128, 7, Bt1);
  k_split<<<(512 * 256 + 255) / 256, 256, 0, stream>>>(Wl3, Wr3, 256, 8, Bt2);
  {
    int total4 = Npad * 128 / 4;
    k_quantA<<<(total4 + 255) / 256, 256, 0, stream>>>(x, N, total4, x_h);
  }
  // zero pad rows of h plane (k_edge writes only rows < N)
  hipMemsetAsync(h_h + (size_t)N * 256, 0, (size_t)(Npad - N) * 256 * 2, stream);

  dim3 ggrid(Npad / 64, 2);
  int nodeBlocks = (N + 3) / 4;  // 4 waves (nodes) per 256-thread block

  // ---- layer 1: 128 -> 8x32, concat, ELU ----
  k_gemm_mfma<<<ggrid, 256, 0, stream>>>(x_h, N, 128, Bt1, bl1, br1, xlh, xrh);
  k_edge<<<nodeBlocks, 256, 0, stream>>>(xlh, xrh, offs, csr_src, att1, b1, h_h, N);

  // ---- layer 2: 256 -> 8x32, concat, ELU ----
  k_gemm_mfma<<<ggrid, 256, 0, stream>>>(h_h, N, 256, Bt2, bl3, br3, xlh, xrh);
  k_edge<<<nodeBlocks, 256, 0, stream>>>(xlh, xrh, offs, csr_src, att3, b3, h_h, N);

  // ---- layer 3: 256 -> 1x2, mean(=identity), log_softmax ----
  k_lin3<<<nodeBlocks, 256, 0, stream>>>(h_h, Wl2, bl2, Wr2, br2, xlr3, N);
  k_edge3<<<(N + 255) / 256, 256, 0, stream>>>(xlr3, offs, csr_src, att2, b2,
                                               (float*)d_out, N);
}

// Round 9
// 249.300 us; speedup vs baseline: 2.5072x; 1.0118x over previous
//
#include <hip/hip_runtime.h>
#include <cstdint>
#include <cstddef>

// ---------------------------------------------------------------------------
// GATv2 3-layer forward on MI355X.
//   All GEMM operands fp16 (rel err 5e-4), fp32 accumulate MFMA.
//   k_edge uses packed-fp16 VALU: v_dot2_f32_f16 scores, pk_fma aggregation,
//   branchless online-softmax with 2-edge pairwise merge.
// Graph CSR built once (device-wide scan), reused 3x.
// ---------------------------------------------------------------------------

typedef __attribute__((ext_vector_type(8))) _Float16 v8h;
typedef __attribute__((ext_vector_type(2))) _Float16 h2;
typedef __attribute__((ext_vector_type(2))) __fp16 h2r;  // intrinsic ret type
typedef __attribute__((ext_vector_type(4))) float v4f;

__device__ __forceinline__ float lrelu(float v) { return fmaxf(v, 0.2f * v); }
__device__ __forceinline__ float elu1(float v)  { return v > 0.f ? v : expm1f(v); }

__device__ __forceinline__ unsigned short f2h(float f) {
  _Float16 h = (_Float16)f;
  return __builtin_bit_cast(unsigned short, h);
}
__device__ __forceinline__ float h2f(unsigned short s) {
  return (float)__builtin_bit_cast(_Float16, s);
}

__device__ __forceinline__ h2 cvt_pk(float a, float b) {  // f32x2 -> half2
  h2r t = __builtin_amdgcn_cvt_pkrtz(a, b);
  return __builtin_bit_cast(h2, t);
}
__device__ __forceinline__ h2 pk2(float a) { return cvt_pk(a, a); }

// packed lrelu: lrelu(v) = 0.6*v + 0.4*|v|  (|.| is a bitwise AND on the pair)
__device__ __forceinline__ h2 lrelu_pk(h2 v) {
  unsigned int u = __builtin_bit_cast(unsigned int, v) & 0x7FFF7FFFu;
  h2 av = __builtin_bit_cast(h2, u);
  h2 c6 = {(_Float16)0.6f, (_Float16)0.6f};
  h2 c4 = {(_Float16)0.4f, (_Float16)0.4f};
  return v * c6 + av * c4;
}

__device__ __forceinline__ float dot2(h2 a, h2 b, float c) {
#if __has_builtin(__builtin_amdgcn_fdot2)
  return __builtin_amdgcn_fdot2(__builtin_bit_cast(h2r, a),
                                __builtin_bit_cast(h2r, b), c, false);
#else
  return fmaf((float)a[0], (float)b[0], fmaf((float)a[1], (float)b[1], c));
#endif
}

__device__ __forceinline__ void gl_lds16(const void* g, void* l) {
  __builtin_amdgcn_global_load_lds(
      (const __attribute__((address_space(1))) unsigned int*)g,
      (__attribute__((address_space(3))) unsigned int*)l, 16, 0, 0);
}

// ---------------- CSR build ----------------

__global__ void k_count(const int* __restrict__ dst, int* __restrict__ deg, int E) {
  int e = blockIdx.x * blockDim.x + threadIdx.x;
  if (e < E) atomicAdd(&deg[dst[e]], 1);
}

__global__ __launch_bounds__(256) void k_bsum(const int* __restrict__ deg, int n,
                                              int* __restrict__ bsum) {
  __shared__ int red[256];
  int t = threadIdx.x, bid = blockIdx.x;
  int i0 = bid * 1024 + t * 4;
  int s = 0;
  if (i0 + 3 < n) {
    int4 v = *(const int4*)&deg[i0];
    s = v.x + v.y + v.z + v.w;
  } else {
#pragma unroll
    for (int j = 0; j < 4; ++j)
      if (i0 + j < n) s += deg[i0 + j];
  }
  red[t] = s;
  __syncthreads();
  for (int off = 128; off > 0; off >>= 1) {
    if (t < off) red[t] += red[t + off];
    __syncthreads();
  }
  if (t == 0) bsum[bid] = red[0];
}

__global__ __launch_bounds__(256) void k_offsets(const int* __restrict__ deg,
                                                 const int* __restrict__ bsum,
                                                 int nb, int n,
                                                 int* __restrict__ offs,
                                                 int* __restrict__ cursor) {
  __shared__ int sc[256];
  int t = threadIdx.x, bid = blockIdx.x;
  int base = 0;
  for (int b = 0; b < bid; ++b) base += bsum[b];
  int i0 = bid * 1024 + t * 4;
  int v0 = 0, v1 = 0, v2 = 0, v3 = 0;
  if (i0 + 3 < n) {
    int4 v = *(const int4*)&deg[i0];
    v0 = v.x; v1 = v.y; v2 = v.z; v3 = v.w;
  } else {
    if (i0 < n)     v0 = deg[i0];
    if (i0 + 1 < n) v1 = deg[i0 + 1];
    if (i0 + 2 < n) v2 = deg[i0 + 2];
    if (i0 + 3 < n) v3 = deg[i0 + 3];
  }
  int s = v0 + v1 + v2 + v3;
  sc[t] = s;
  __syncthreads();
  for (int off = 1; off < 256; off <<= 1) {
    int x = (t >= off) ? sc[t - off] : 0;
    __syncthreads();
    sc[t] += x;
    __syncthreads();
  }
  int run = base + sc[t] - s;
  int o0 = run, o1 = run + v0, o2 = o1 + v1, o3 = o2 + v2;
  if (i0 + 3 < n) {
    *(int4*)&offs[i0] = make_int4(o0, o1, o2, o3);
    *(int4*)&cursor[i0] = make_int4(o0, o1, o2, o3);
  } else {
    if (i0 < n)     { offs[i0] = o0;     cursor[i0] = o0; }
    if (i0 + 1 < n) { offs[i0 + 1] = o1; cursor[i0 + 1] = o1; }
    if (i0 + 2 < n) { offs[i0 + 2] = o2; cursor[i0 + 2] = o2; }
    if (i0 + 3 < n) { offs[i0 + 3] = o3; cursor[i0 + 3] = o3; }
  }
  if (bid == nb - 1 && t == 255) offs[n] = base + sc[255];
}

__global__ void k_scatter(const int* __restrict__ src, const int* __restrict__ dst,
                          int* __restrict__ cursor, int* __restrict__ csr_src, int E) {
  int e = blockIdx.x * blockDim.x + threadIdx.x;
  if (e < E) {
    int pos = atomicAdd(&cursor[dst[e]], 1);
    csr_src[pos] = src[e];
  }
}

// ---------------- weight transpose+quantize: Bt[n][k] = fp16(W[k][n]) -------

__global__ void k_split(const float* __restrict__ Wl, const float* __restrict__ Wr,
                        int K, int logK, unsigned short* __restrict__ Bt) {
  int idx = blockIdx.x * blockDim.x + threadIdx.x;
  if (idx >= 512 * K) return;
  int n = idx >> logK;
  int k = idx & (K - 1);
  float w = (n < 256) ? Wl[(size_t)k * 256 + n] : Wr[(size_t)k * 256 + (n - 256)];
  Bt[idx] = f2h(w);
}

// ---------------- input quantize: x[N,128] fp32 -> fp16 plane [Npad,128] ----

__global__ void k_quantA(const float* __restrict__ X, int Nreal, int total4,
                         unsigned short* __restrict__ Hh) {
  int idx = blockIdx.x * blockDim.x + threadIdx.x;  // 4 elems each
  if (idx >= total4) return;
  int row = idx >> 5;  // (idx*4)>>7, K=128
  ushort4 uh;
  if (row < Nreal) {
    float4 v = *(const float4*)&X[(size_t)idx * 4];
    uh.x = f2h(v.x); uh.y = f2h(v.y); uh.z = f2h(v.z); uh.w = f2h(v.w);
  } else {
    uh = make_ushort4(0, 0, 0, 0);
  }
  *(ushort4*)&Hh[(size_t)idx * 4] = uh;
}

// ---------------- fp16 MFMA GEMM, tile 64x256 -------------------------------
// grid (Npad/64, 2): y=0 -> xl half (cols 0..255), y=1 -> xr half.
// Staging: global_load_lds(16B), linear LDS dest, slot-XOR on global source.

__global__ __launch_bounds__(256) void k_gemm_mfma(
    const unsigned short* __restrict__ A_g,  // [Npad,K] fp16
    int Nreal, int K,
    const unsigned short* __restrict__ Bt,   // [512,K] fp16 (transposed W)
    const float* __restrict__ bl, const float* __restrict__ br,
    unsigned short* __restrict__ xl_h, unsigned short* __restrict__ xr_h) {
  __shared__ __align__(16) short Ah[64 * 32];    // 4 KB
  __shared__ __align__(16) short Bh[256 * 32];   // 16 KB

  const int tid = threadIdx.x;
  const int lane = tid & 63;
  const int wid = tid >> 6;
  const int l15 = lane & 15, g = lane >> 4;
  const int bm = blockIdx.x * 64;
  const int half = blockIdx.y;           // 0: xl, 1: xr
  const int bn = half * 256;

  v4f acc[4][4];
#pragma unroll
  for (int m = 0; m < 4; ++m)
#pragma unroll
    for (int n = 0; n < 4; ++n) acc[m][n] = (v4f)(0.f);

  const int arow = tid >> 2, aslot = tid & 3;
  const int aoct = aslot ^ ((arow >> 1) & 3);
  const size_t gaBase = (size_t)(bm + arow) * K + aoct * 8;
  short* AhW = Ah + wid * 512;  // linear dest: wave base + lane*16B

  for (int k0 = 0; k0 < K; k0 += 32) {
    gl_lds16(A_g + gaBase + k0, AhW);
#pragma unroll
    for (int it = 0; it < 4; ++it) {
      int task = it * 256 + tid;
      int col = task >> 2, slot = task & 3;
      int oct = slot ^ ((col >> 1) & 3);
      size_t gb = (size_t)(bn + col) * K + k0 + oct * 8;
      gl_lds16(Bt + gb, Bh + it * 2048 + wid * 512);
    }
    __syncthreads();

    v8h a_h[4], b_h[4];
#pragma unroll
    for (int m = 0; m < 4; ++m) {
      int r = m * 16 + l15;
      int s = g ^ ((r >> 1) & 3);
      a_h[m] = *(const v8h*)&Ah[r * 32 + s * 8];
    }
#pragma unroll
    for (int n = 0; n < 4; ++n) {
      int c = wid * 64 + n * 16 + l15;
      int s = g ^ ((c >> 1) & 3);
      b_h[n] = *(const v8h*)&Bh[c * 32 + s * 8];
    }
#pragma unroll
    for (int m = 0; m < 4; ++m)
#pragma unroll
      for (int n = 0; n < 4; ++n)
        acc[m][n] = __builtin_amdgcn_mfma_f32_16x16x32_f16(a_h[m], b_h[n], acc[m][n], 0, 0, 0);
    __syncthreads();
  }

  // ---- epilogue: per-wave LDS transpose (reuses Bh), fp16 stores ----
  float* scr = (float*)Bh + wid * 320;       // 16 rows x stride 20 floats
  const int erow = lane >> 2, ecq = lane & 3;
  unsigned short* outp = half ? xr_h : xl_h;
  const float* bias = half ? br : bl;
#pragma unroll
  for (int m = 0; m < 4; ++m) {
#pragma unroll
    for (int n = 0; n < 4; ++n) {
#pragma unroll
      for (int r = 0; r < 4; ++r) scr[(g * 4 + r) * 20 + l15] = acc[m][n][r];
      float4 v = *(const float4*)&scr[erow * 20 + ecq * 4];
      int row = bm + m * 16 + erow;
      if (row < Nreal) {
        int col = wid * 64 + n * 16 + ecq * 4;
        float4 bv = *(const float4*)&bias[col];
        ushort4 u;
        u.x = f2h(v.x + bv.x); u.y = f2h(v.y + bv.y);
        u.z = f2h(v.z + bv.z); u.w = f2h(v.w + bv.w);
        *(ushort4*)&outp[(size_t)row * 256 + col] = u;
      }
    }
  }
}

// ---------------- fused GATv2 edge pass (H=8, C=32), wave per dst node ------
// Packed-fp16 VALU: dot2 scores, pk aggregation. Branchless online softmax,
// 2-edge pairwise merge, self-loop = initial state.

__global__ __launch_bounds__(256) void k_edge(
    const unsigned short* __restrict__ xl_h,  // [N,256] fp16
    const unsigned short* __restrict__ xr_h,  // [N,256] fp16
    const int* __restrict__ offs, const int* __restrict__ csr_src,
    const float* __restrict__ att,   // [8*32]
    const float* __restrict__ bias,  // [256]
    unsigned short* __restrict__ hout,  // [Npad,256] fp16
    int n) {
  int lane = threadIdx.x & 63;
  int node = blockIdx.x * (blockDim.x >> 6) + (threadIdx.x >> 6);
  if (node >= n) return;

  float4 attf = *(const float4*)&att[lane * 4];
  h2 atta = cvt_pk(attf.x, attf.y);
  h2 attb = cvt_pk(attf.z, attf.w);
  uint2 urx = *(const uint2*)&xr_h[(size_t)node * 256 + lane * 4];
  h2 xra = __builtin_bit_cast(h2, urx.x), xrb = __builtin_bit_cast(h2, urx.y);

  // self-loop as initial state: m = p_self, d = 1, acc = xl(node)
  uint2 us = *(const uint2*)&xl_h[(size_t)node * 256 + lane * 4];
  h2 acca = __builtin_bit_cast(h2, us.x), accb = __builtin_bit_cast(h2, us.y);
  float p = dot2(lrelu_pk(acca + xra), atta, 0.f);
  p = dot2(lrelu_pk(accb + xrb), attb, p);
  p += __shfl_xor(p, 1);
  p += __shfl_xor(p, 2);
  p += __shfl_xor(p, 4);
  float m = p, d = 1.f;

  int e0 = offs[node], e1 = offs[node + 1];
  int e = e0;
  for (; e + 1 < e1; e += 2) {
    int j1 = csr_src[e], j2 = csr_src[e + 1];
    uint2 u1 = *(const uint2*)&xl_h[(size_t)j1 * 256 + lane * 4];
    uint2 u2 = *(const uint2*)&xl_h[(size_t)j2 * 256 + lane * 4];
    h2 x1a = __builtin_bit_cast(h2, u1.x), x1b = __builtin_bit_cast(h2, u1.y);
    h2 x2a = __builtin_bit_cast(h2, u2.x), x2b = __builtin_bit_cast(h2, u2.y);
    float p1 = dot2(lrelu_pk(x1a + xra), atta, 0.f);
    p1 = dot2(lrelu_pk(x1b + xrb), attb, p1);
    float p2 = dot2(lrelu_pk(x2a + xra), atta, 0.f);
    p2 = dot2(lrelu_pk(x2b + xrb), attb, p2);
    p1 += __shfl_xor(p1, 1); p2 += __shfl_xor(p2, 1);
    p1 += __shfl_xor(p1, 2); p2 += __shfl_xor(p2, 2);
    p1 += __shfl_xor(p1, 4); p2 += __shfl_xor(p2, 4);
    // pair-local softmax state
    float m12 = fmaxf(p1, p2);
    float w1 = __expf(p1 - m12), w2 = __expf(p2 - m12);
    float d12 = w1 + w2;
    h2 w1p = pk2(w1), w2p = pk2(w2);
    h2 ca = x1a * w1p + x2a * w2p;
    h2 cb = x1b * w1p + x2b * w2p;
    // merge into running state (branchless)
    float mN = fmaxf(m, m12);
    float r  = __expf(m - mN);
    float r2 = __expf(m12 - mN);
    d = fmaf(d, r, d12 * r2);
    h2 rp = pk2(r), r2p = pk2(r2);
    acca = acca * rp + ca * r2p;
    accb = accb * rp + cb * r2p;
    m = mN;
  }
  if (e < e1) {  // tail edge
    int j = csr_src[e];
    uint2 u = *(const uint2*)&xl_h[(size_t)j * 256 + lane * 4];
    h2 xa = __builtin_bit_cast(h2, u.x), xb = __builtin_bit_cast(h2, u.y);
    float p1 = dot2(lrelu_pk(xa + xra), atta, 0.f);
    p1 = dot2(lrelu_pk(xb + xrb), attb, p1);
    p1 += __shfl_xor(p1, 1);
    p1 += __shfl_xor(p1, 2);
    p1 += __shfl_xor(p1, 4);
    float mN = fmaxf(m, p1);
    float r = __expf(m - mN), w1 = __expf(p1 - mN);
    d = fmaf(d, r, w1);
    h2 rp = pk2(r), w1p = pk2(w1);
    acca = acca * rp + xa * w1p;
    accb = accb * rp + xb * w1p;
  }

  float inv = 1.f / (d + 1e-16f);
  float4 b4 = *(const float4*)&bias[lane * 4];
  float o0 = elu1(fmaf((float)acca[0], inv, b4.x));
  float o1 = elu1(fmaf((float)acca[1], inv, b4.y));
  float o2 = elu1(fmaf((float)accb[0], inv, b4.z));
  float o3 = elu1(fmaf((float)accb[1], inv, b4.w));
  ushort4 uo;
  uo.x = f2h(o0); uo.y = f2h(o1); uo.z = f2h(o2); uo.w = f2h(o3);
  *(ushort4*)&hout[(size_t)node * 256 + lane * 4] = uo;
}

// ---------------- layer 3: skinny linear (256->2 twice), wave per node ------

__global__ __launch_bounds__(256) void k_lin3(
    const unsigned short* __restrict__ hq,
    const float* __restrict__ Wl, const float* __restrict__ bl,
    const float* __restrict__ Wr, const float* __restrict__ br,
    float* __restrict__ xlr3,  // [N,4] = {xl0,xl1,xr0,xr1}
    int n) {
  int lane = threadIdx.x & 63;
  int node = blockIdx.x * (blockDim.x >> 6) + (threadIdx.x >> 6);
  if (node >= n) return;
  ushort4 uh = *(const ushort4*)&hq[(size_t)node * 256 + lane * 4];
  float hv[4] = {h2f(uh.x), h2f(uh.y), h2f(uh.z), h2f(uh.w)};
  float al0 = 0.f, al1 = 0.f, ar0 = 0.f, ar1 = 0.f;
#pragma unroll
  for (int j = 0; j < 4; ++j) {
    int k = lane * 4 + j;
    al0 = fmaf(hv[j], Wl[k * 2 + 0], al0);
    al1 = fmaf(hv[j], Wl[k * 2 + 1], al1);
    ar0 = fmaf(hv[j], Wr[k * 2 + 0], ar0);
    ar1 = fmaf(hv[j], Wr[k * 2 + 1], ar1);
  }
#pragma unroll
  for (int s = 1; s < 64; s <<= 1) {
    al0 += __shfl_xor(al0, s);
    al1 += __shfl_xor(al1, s);
    ar0 += __shfl_xor(ar0, s);
    ar1 += __shfl_xor(ar1, s);
  }
  if (lane == 0) {
    float4 o = make_float4(al0 + bl[0], al1 + bl[1], ar0 + br[0], ar1 + br[1]);
    *(float4*)&xlr3[(size_t)node * 4] = o;
  }
}

// ---------------- layer 3 edge pass + log_softmax, thread per node ----------

__global__ void k_edge3(const float* __restrict__ xlr3,
                        const int* __restrict__ offs, const int* __restrict__ csr_src,
                        const float* __restrict__ att,  // [2]
                        const float* __restrict__ b,    // [2]
                        float* __restrict__ out, int n) {
  int i = blockIdx.x * blockDim.x + threadIdx.x;
  if (i >= n) return;
  float a0 = att[0], a1 = att[1];
  float xr0 = xlr3[(size_t)i * 4 + 2], xr1 = xlr3[(size_t)i * 4 + 3];
  // self-loop first
  float sl0 = xlr3[(size_t)i * 4 + 0], sl1 = xlr3[(size_t)i * 4 + 1];
  float m = lrelu(sl0 + xr0) * a0 + lrelu(sl1 + xr1) * a1;
  float d = 1.f, ac0 = sl0, ac1 = sl1;
  int e0 = offs[i], e1 = offs[i + 1];
  for (int e = e0; e < e1; ++e) {
    int j = csr_src[e];
    float xl0 = xlr3[(size_t)j * 4 + 0], xl1 = xlr3[(size_t)j * 4 + 1];
    float p = lrelu(xl0 + xr0) * a0 + lrelu(xl1 + xr1) * a1;
    float mN = fmaxf(m, p);
    float r = __expf(m - mN), w = __expf(p - mN);
    d = fmaf(d, r, w);
    ac0 = fmaf(ac0, r, w * xl0);
    ac1 = fmaf(ac1, r, w * xl1);
    m = mN;
  }
  float inv = 1.f / (d + 1e-16f);
  float o0 = fmaf(ac0, inv, b[0]);
  float o1 = fmaf(ac1, inv, b[1]);
  float mx = fmaxf(o0, o1);
  float lse = mx + logf(expf(o0 - mx) + expf(o1 - mx));
  out[(size_t)i * 2 + 0] = o0 - lse;
  out[(size_t)i * 2 + 1] = o1 - lse;
}

// ---------------------------------------------------------------------------

static inline size_t align_up(size_t v, size_t a) { return (v + a - 1) & ~(a - 1); }

extern "C" void kernel_launch(void* const* d_in, const int* in_sizes, int n_in,
                              void* d_out, int out_size, void* d_ws, size_t ws_size,
                              hipStream_t stream) {
  const float* x    = (const float*)d_in[0];
  const int*   ei   = (const int*)d_in[1];
  const float* Wl1  = (const float*)d_in[2];
  const float* bl1  = (const float*)d_in[3];
  const float* Wr1  = (const float*)d_in[4];
  const float* br1  = (const float*)d_in[5];
  const float* att1 = (const float*)d_in[6];
  const float* b1   = (const float*)d_in[7];
  const float* Wl3  = (const float*)d_in[8];
  const float* bl3  = (const float*)d_in[9];
  const float* Wr3  = (const float*)d_in[10];
  const float* br3  = (const float*)d_in[11];
  const float* att3 = (const float*)d_in[12];
  const float* b3   = (const float*)d_in[13];
  const float* Wl2  = (const float*)d_in[14];
  const float* bl2  = (const float*)d_in[15];
  const float* Wr2  = (const float*)d_in[16];
  const float* br2  = (const float*)d_in[17];
  const float* att2 = (const float*)d_in[18];
  const float* b2   = (const float*)d_in[19];

  const int N = in_sizes[0] / 128;  // 50000
  const int E = in_sizes[1] / 2;    // 400000
  const int Npad = ((N + 63) / 64) * 64;  // 50048
  const int* srcp = ei;
  const int* dstp = ei + E;

  // workspace layout
  char* w = (char*)d_ws;
  size_t off = 0;
  int* deg     = (int*)(w + off); off = align_up(off + (size_t)N * 4, 256);
  int* offs    = (int*)(w + off); off = align_up(off + (size_t)(N + 1) * 4, 256);
  int* cursor  = (int*)(w + off); off = align_up(off + (size_t)N * 4, 256);
  int* csr_src = (int*)(w + off); off = align_up(off + (size_t)E * 4, 256);
  int* bsum    = (int*)(w + off); off = align_up(off + (size_t)256 * 4, 256);
  unsigned short* x_h  = (unsigned short*)(w + off); off = align_up(off + (size_t)Npad * 128 * 2, 256);
  unsigned short* h_h  = (unsigned short*)(w + off); off = align_up(off + (size_t)Npad * 256 * 2, 256);
  unsigned short* xlh  = (unsigned short*)(w + off); off = align_up(off + (size_t)N * 256 * 2, 256);
  unsigned short* xrh  = (unsigned short*)(w + off); off = align_up(off + (size_t)N * 256 * 2, 256);
  float* xlr3  = (float*)(w + off); off = align_up(off + (size_t)N * 4 * 4, 256);
  unsigned short* Bt1 = (unsigned short*)(w + off); off = align_up(off + (size_t)512 * 128 * 2, 256);
  unsigned short* Bt2 = (unsigned short*)(w + off); off = align_up(off + (size_t)512 * 256 * 2, 256);
  (void)ws_size;

  const int nb = (N + 1023) / 1024;

  // ---- build CSR (incoming edges per dst), reused by all 3 layers ----
  hipMemsetAsync(deg, 0, (size_t)N * 4, stream);
  k_count<<<(E + 255) / 256, 256, 0, stream>>>(dstp, deg, E);
  k_bsum<<<nb, 256, 0, stream>>>(deg, N, bsum);
  k_offsets<<<nb, 256, 0, stream>>>(deg, bsum, nb, N, offs, cursor);
  k_scatter<<<(E + 255) / 256, 256, 0, stream>>>(srcp, dstp, cursor, csr_src, E);

  // ---- quantize weights (transposed) and x to fp16 ----
  k_split<<<(512 * 128 + 255) / 256, 256, 0, stream>>>(Wl1, Wr1, 128, 7, Bt1);
  k_split<<<(512 * 256 + 255) / 256, 256, 0, stream>>>(Wl3, Wr3, 256, 8, Bt2);
  {
    int total4 = Npad * 128 / 4;
    k_quantA<<<(total4 + 255) / 256, 256, 0, stream>>>(x, N, total4, x_h);
  }
  // zero pad rows of h plane (k_edge writes only rows < N)
  hipMemsetAsync(h_h + (size_t)N * 256, 0, (size_t)(Npad - N) * 256 * 2, stream);

  dim3 ggrid(Npad / 64, 2);
  int nodeBlocks = (N + 3) / 4;  // 4 waves (nodes) per 256-thread block

  // ---- layer 1: 128 -> 8x32, concat, ELU ----
  k_gemm_mfma<<<ggrid, 256, 0, stream>>>(x_h, N, 128, Bt1, bl1, br1, xlh, xrh);
  k_edge<<<nodeBlocks, 256, 0, stream>>>(xlh, xrh, offs, csr_src, att1, b1, h_h, N);

  // ---- layer 2: 256 -> 8x32, concat, ELU ----
  k_gemm_mfma<<<ggrid, 256, 0, stream>>>(h_h, N, 256, Bt2, bl3, br3, xlh, xrh);
  k_edge<<<nodeBlocks, 256, 0, stream>>>(xlh, xrh, offs, csr_src, att3, b3, h_h, N);

  // ---- layer 3: 256 -> 1x2, mean(=identity), log_softmax ----
  k_lin3<<<nodeBlocks, 256, 0, stream>>>(h_h, Wl2, bl2, Wr2, br2, xlr3, N);
  k_edge3<<<(N + 255) / 256, 256, 0, stream>>>(xlr3, offs, csr_src, att2, b2,
                                               (float*)d_out, N);
}

// Round 10
// 240.648 us; speedup vs baseline: 2.5973x; 1.0360x over previous
//
#include <hip/hip_runtime.h>
#include <cstdint>
#include <cstddef>

// ---------------------------------------------------------------------------
// GATv2 3-layer forward on MI355X.
//   All GEMM operands fp16 (rel err 5e-4), fp32 accumulate MFMA.
//   k_gemm_mfma : tile 64x256, DOUBLE-BUFFERED global_load_lds staging with
//                 counted vmcnt (never 0 in loop), 32-bit addressing.
//   k_edge      : packed-fp16 VALU (dot2 + pk fma), branchless online softmax,
//                 2-edge pairwise merge, 32-bit gather offsets.
// Graph CSR built once (device-wide scan), reused 3x.
// ---------------------------------------------------------------------------

typedef __attribute__((ext_vector_type(8))) _Float16 v8h;
typedef __attribute__((ext_vector_type(2))) _Float16 h2;
typedef __attribute__((ext_vector_type(2))) __fp16 h2r;  // intrinsic ret type
typedef __attribute__((ext_vector_type(4))) float v4f;

__device__ __forceinline__ float lrelu(float v) { return fmaxf(v, 0.2f * v); }
__device__ __forceinline__ float elu1(float v)  { return v > 0.f ? v : expm1f(v); }

__device__ __forceinline__ unsigned short f2h(float f) {
  _Float16 h = (_Float16)f;
  return __builtin_bit_cast(unsigned short, h);
}
__device__ __forceinline__ float h2f(unsigned short s) {
  return (float)__builtin_bit_cast(_Float16, s);
}

__device__ __forceinline__ h2 cvt_pk(float a, float b) {  // f32x2 -> half2
  h2r t = __builtin_amdgcn_cvt_pkrtz(a, b);
  return __builtin_bit_cast(h2, t);
}
__device__ __forceinline__ h2 pk2(float a) { return cvt_pk(a, a); }

// packed lrelu: lrelu(v) = 0.6*v + 0.4*|v|  (|.| is a bitwise AND on the pair)
__device__ __forceinline__ h2 lrelu_pk(h2 v) {
  unsigned int u = __builtin_bit_cast(unsigned int, v) & 0x7FFF7FFFu;
  h2 av = __builtin_bit_cast(h2, u);
  h2 c6 = {(_Float16)0.6f, (_Float16)0.6f};
  h2 c4 = {(_Float16)0.4f, (_Float16)0.4f};
  return v * c6 + av * c4;
}

__device__ __forceinline__ float dot2(h2 a, h2 b, float c) {
#if __has_builtin(__builtin_amdgcn_fdot2)
  return __builtin_amdgcn_fdot2(__builtin_bit_cast(h2r, a),
                                __builtin_bit_cast(h2r, b), c, false);
#else
  return fmaf((float)a[0], (float)b[0], fmaf((float)a[1], (float)b[1], c));
#endif
}

__device__ __forceinline__ void gl_lds16(const void* g, void* l) {
  __builtin_amdgcn_global_load_lds(
      (const __attribute__((address_space(1))) unsigned int*)g,
      (__attribute__((address_space(3))) unsigned int*)l, 16, 0, 0);
}

// ---------------- CSR build ----------------

__global__ void k_count(const int* __restrict__ dst, int* __restrict__ deg, int E) {
  int e = blockIdx.x * blockDim.x + threadIdx.x;
  if (e < E) atomicAdd(&deg[dst[e]], 1);
}

__global__ __launch_bounds__(256) void k_bsum(const int* __restrict__ deg, int n,
                                              int* __restrict__ bsum) {
  __shared__ int red[256];
  int t = threadIdx.x, bid = blockIdx.x;
  int i0 = bid * 1024 + t * 4;
  int s = 0;
  if (i0 + 3 < n) {
    int4 v = *(const int4*)&deg[i0];
    s = v.x + v.y + v.z + v.w;
  } else {
#pragma unroll
    for (int j = 0; j < 4; ++j)
      if (i0 + j < n) s += deg[i0 + j];
  }
  red[t] = s;
  __syncthreads();
  for (int off = 128; off > 0; off >>= 1) {
    if (t < off) red[t] += red[t + off];
    __syncthreads();
  }
  if (t == 0) bsum[bid] = red[0];
}

__global__ __launch_bounds__(256) void k_offsets(const int* __restrict__ deg,
                                                 const int* __restrict__ bsum,
                                                 int nb, int n,
                                                 int* __restrict__ offs,
                                                 int* __restrict__ cursor) {
  __shared__ int sc[256];
  int t = threadIdx.x, bid = blockIdx.x;
  int base = 0;
  for (int b = 0; b < bid; ++b) base += bsum[b];
  int i0 = bid * 1024 + t * 4;
  int v0 = 0, v1 = 0, v2 = 0, v3 = 0;
  if (i0 + 3 < n) {
    int4 v = *(const int4*)&deg[i0];
    v0 = v.x; v1 = v.y; v2 = v.z; v3 = v.w;
  } else {
    if (i0 < n)     v0 = deg[i0];
    if (i0 + 1 < n) v1 = deg[i0 + 1];
    if (i0 + 2 < n) v2 = deg[i0 + 2];
    if (i0 + 3 < n) v3 = deg[i0 + 3];
  }
  int s = v0 + v1 + v2 + v3;
  sc[t] = s;
  __syncthreads();
  for (int off = 1; off < 256; off <<= 1) {
    int x = (t >= off) ? sc[t - off] : 0;
    __syncthreads();
    sc[t] += x;
    __syncthreads();
  }
  int run = base + sc[t] - s;
  int o0 = run, o1 = run + v0, o2 = o1 + v1, o3 = o2 + v2;
  if (i0 + 3 < n) {
    *(int4*)&offs[i0] = make_int4(o0, o1, o2, o3);
    *(int4*)&cursor[i0] = make_int4(o0, o1, o2, o3);
  } else {
    if (i0 < n)     { offs[i0] = o0;     cursor[i0] = o0; }
    if (i0 + 1 < n) { offs[i0 + 1] = o1; cursor[i0 + 1] = o1; }
    if (i0 + 2 < n) { offs[i0 + 2] = o2; cursor[i0 + 2] = o2; }
    if (i0 + 3 < n) { offs[i0 + 3] = o3; cursor[i0 + 3] = o3; }
  }
  if (bid == nb - 1 && t == 255) offs[n] = base + sc[255];
}

__global__ void k_scatter(const int* __restrict__ src, const int* __restrict__ dst,
                          int* __restrict__ cursor, int* __restrict__ csr_src, int E) {
  int e = blockIdx.x * blockDim.x + threadIdx.x;
  if (e < E) {
    int pos = atomicAdd(&cursor[dst[e]], 1);
    csr_src[pos] = src[e];
  }
}

// ---------------- weight transpose+quantize: Bt[n][k] = fp16(W[k][n]) -------

__global__ void k_split(const float* __restrict__ Wl, const float* __restrict__ Wr,
                        int K, int logK, unsigned short* __restrict__ Bt) {
  int idx = blockIdx.x * blockDim.x + threadIdx.x;
  if (idx >= 512 * K) return;
  int n = idx >> logK;
  int k = idx & (K - 1);
  float w = (n < 256) ? Wl[(size_t)k * 256 + n] : Wr[(size_t)k * 256 + (n - 256)];
  Bt[idx] = f2h(w);
}

// ---------------- input quantize: x[N,128] fp32 -> fp16 plane [Npad,128] ----

__global__ void k_quantA(const float* __restrict__ X, int Nreal, int total4,
                         unsigned short* __restrict__ Hh) {
  int idx = blockIdx.x * blockDim.x + threadIdx.x;  // 4 elems each
  if (idx >= total4) return;
  int row = idx >> 5;  // (idx*4)>>7, K=128
  ushort4 uh;
  if (row < Nreal) {
    float4 v = *(const float4*)&X[(size_t)idx * 4];
    uh.x = f2h(v.x); uh.y = f2h(v.y); uh.z = f2h(v.z); uh.w = f2h(v.w);
  } else {
    uh = make_ushort4(0, 0, 0, 0);
  }
  *(ushort4*)&Hh[(size_t)idx * 4] = uh;
}

// ---------------- fp16 MFMA GEMM, tile 64x256, double-buffered --------------
// grid (Npad/64, 2): y=0 -> xl half (cols 0..255), y=1 -> xr half.
// Per k-step: 5 gl_lds/thread. Loop waits vmcnt(5) (next buf in flight),
// never drains to 0 until the last step. 2 barriers/iter (stage-visible,
// read-done). 32-bit offsets (A <= 26 MB, Bt <= 256 KB).

__global__ __launch_bounds__(256) void k_gemm_mfma(
    const unsigned short* __restrict__ A_g,  // [Npad,K] fp16
    int Nreal, int K,
    const unsigned short* __restrict__ Bt,   // [512,K] fp16 (transposed W)
    const float* __restrict__ bl, const float* __restrict__ br,
    unsigned short* __restrict__ xl_h, unsigned short* __restrict__ xr_h) {
  __shared__ __align__(16) short Ah[2][64 * 32];    // 8 KB
  __shared__ __align__(16) short Bh[2][256 * 32];   // 32 KB

  const int tid = threadIdx.x;
  const int lane = tid & 63;
  const int wid = tid >> 6;
  const int l15 = lane & 15, g = lane >> 4;
  const int bm = blockIdx.x * 64;
  const int half = blockIdx.y;           // 0: xl, 1: xr
  const int bn = half * 256;

  v4f acc[4][4];
#pragma unroll
  for (int m = 0; m < 4; ++m)
#pragma unroll
    for (int n = 0; n < 4; ++n) acc[m][n] = (v4f)(0.f);

  const int arow = tid >> 2, aslot = tid & 3;
  const int aoct = aslot ^ ((arow >> 1) & 3);
  const unsigned gaBase = (unsigned)(bm + arow) * K + aoct * 8;

  auto STAGE = [&](int buf, int k0) {
    gl_lds16(A_g + (gaBase + k0), &Ah[buf][wid * 512]);
#pragma unroll
    for (int it = 0; it < 4; ++it) {
      int task = it * 256 + tid;
      int col = task >> 2, slot = task & 3;
      int oct = slot ^ ((col >> 1) & 3);
      unsigned gb = (unsigned)(bn + col) * K + k0 + oct * 8;
      gl_lds16(Bt + gb, &Bh[buf][it * 2048 + wid * 512]);
    }
  };

  const int nt = K >> 5;
  STAGE(0, 0);
  for (int t = 0; t < nt; ++t) {
    const int cur = t & 1;
    if (t + 1 < nt) {
      STAGE(cur ^ 1, (t + 1) << 5);
      asm volatile("s_waitcnt vmcnt(5)" ::: "memory");  // cur's loads landed
    } else {
      asm volatile("s_waitcnt vmcnt(0)" ::: "memory");
    }
    __builtin_amdgcn_sched_barrier(0);
    __builtin_amdgcn_s_barrier();  // cur buf staged by ALL waves

    v8h a_h[4], b_h[4];
#pragma unroll
    for (int m = 0; m < 4; ++m) {
      int r = m * 16 + l15;
      int s = g ^ ((r >> 1) & 3);
      a_h[m] = *(const v8h*)&Ah[cur][r * 32 + s * 8];
    }
#pragma unroll
    for (int n = 0; n < 4; ++n) {
      int c = wid * 64 + n * 16 + l15;
      int s = g ^ ((c >> 1) & 3);
      b_h[n] = *(const v8h*)&Bh[cur][c * 32 + s * 8];
    }
#pragma unroll
    for (int m = 0; m < 4; ++m)
#pragma unroll
      for (int n = 0; n < 4; ++n)
        acc[m][n] = __builtin_amdgcn_mfma_f32_16x16x32_f16(a_h[m], b_h[n], acc[m][n], 0, 0, 0);
    __builtin_amdgcn_s_barrier();  // cur reads done before re-stage of cur
  }

  // ---- epilogue: per-wave LDS transpose (reuses Bh[0]), fp16 stores ----
  float* scr = (float*)&Bh[0][0] + wid * 320;  // 16 rows x stride 20 floats
  const int erow = lane >> 2, ecq = lane & 3;
  unsigned short* outp = half ? xr_h : xl_h;
  const float* bias = half ? br : bl;
#pragma unroll
  for (int m = 0; m < 4; ++m) {
#pragma unroll
    for (int n = 0; n < 4; ++n) {
#pragma unroll
      for (int r = 0; r < 4; ++r) scr[(g * 4 + r) * 20 + l15] = acc[m][n][r];
      float4 v = *(const float4*)&scr[erow * 20 + ecq * 4];
      int row = bm + m * 16 + erow;
      if (row < Nreal) {
        int col = wid * 64 + n * 16 + ecq * 4;
        float4 bv = *(const float4*)&bias[col];
        ushort4 u;
        u.x = f2h(v.x + bv.x); u.y = f2h(v.y + bv.y);
        u.z = f2h(v.z + bv.z); u.w = f2h(v.w + bv.w);
        *(ushort4*)&outp[(size_t)row * 256 + col] = u;
      }
    }
  }
}

// ---------------- fused GATv2 edge pass (H=8, C=32), wave per dst node ------
// Packed-fp16 VALU, 32-bit gather offsets. Branchless online softmax,
// 2-edge pairwise merge, self-loop = initial state.

__global__ __launch_bounds__(256) void k_edge(
    const unsigned short* __restrict__ xl_h,  // [N,256] fp16
    const unsigned short* __restrict__ xr_h,  // [N,256] fp16
    const int* __restrict__ offs, const int* __restrict__ csr_src,
    const float* __restrict__ att,   // [8*32]
    const float* __restrict__ bias,  // [256]
    unsigned short* __restrict__ hout,  // [Npad,256] fp16
    int n) {
  int lane = threadIdx.x & 63;
  int node = blockIdx.x * (blockDim.x >> 6) + (threadIdx.x >> 6);
  if (node >= n) return;

  const unsigned lb = (unsigned)(lane << 2);
  float4 attf = *(const float4*)&att[lb];
  h2 atta = cvt_pk(attf.x, attf.y);
  h2 attb = cvt_pk(attf.z, attf.w);
  const unsigned noff = ((unsigned)node << 8) + lb;
  uint2 urx = *(const uint2*)(xr_h + noff);
  h2 xra = __builtin_bit_cast(h2, urx.x), xrb = __builtin_bit_cast(h2, urx.y);

  // self-loop as initial state: m = p_self, d = 1, acc = xl(node)
  uint2 us = *(const uint2*)(xl_h + noff);
  h2 acca = __builtin_bit_cast(h2, us.x), accb = __builtin_bit_cast(h2, us.y);
  float p = dot2(lrelu_pk(acca + xra), atta, 0.f);
  p = dot2(lrelu_pk(accb + xrb), attb, p);
  p += __shfl_xor(p, 1);
  p += __shfl_xor(p, 2);
  p += __shfl_xor(p, 4);
  float m = p, d = 1.f;

  int e0 = offs[node], e1 = offs[node + 1];
  int e = e0;
  for (; e + 1 < e1; e += 2) {
    int j1 = csr_src[e], j2 = csr_src[e + 1];
    uint2 u1 = *(const uint2*)(xl_h + (((unsigned)j1 << 8) + lb));
    uint2 u2 = *(const uint2*)(xl_h + (((unsigned)j2 << 8) + lb));
    h2 x1a = __builtin_bit_cast(h2, u1.x), x1b = __builtin_bit_cast(h2, u1.y);
    h2 x2a = __builtin_bit_cast(h2, u2.x), x2b = __builtin_bit_cast(h2, u2.y);
    float p1 = dot2(lrelu_pk(x1a + xra), atta, 0.f);
    p1 = dot2(lrelu_pk(x1b + xrb), attb, p1);
    float p2 = dot2(lrelu_pk(x2a + xra), atta, 0.f);
    p2 = dot2(lrelu_pk(x2b + xrb), attb, p2);
    p1 += __shfl_xor(p1, 1); p2 += __shfl_xor(p2, 1);
    p1 += __shfl_xor(p1, 2); p2 += __shfl_xor(p2, 2);
    p1 += __shfl_xor(p1, 4); p2 += __shfl_xor(p2, 4);
    // pair-local softmax state
    float m12 = fmaxf(p1, p2);
    float w1 = __expf(p1 - m12), w2 = __expf(p2 - m12);
    float d12 = w1 + w2;
    h2 w1p = pk2(w1), w2p = pk2(w2);
    h2 ca = x1a * w1p + x2a * w2p;
    h2 cb = x1b * w1p + x2b * w2p;
    // merge into running state (branchless)
    float mN = fmaxf(m, m12);
    float r  = __expf(m - mN);
    float r2 = __expf(m12 - mN);
    d = fmaf(d, r, d12 * r2);
    h2 rp = pk2(r), r2p = pk2(r2);
    acca = acca * rp + ca * r2p;
    accb = accb * rp + cb * r2p;
    m = mN;
  }
  if (e < e1) {  // tail edge
    int j = csr_src[e];
    uint2 u = *(const uint2*)(xl_h + (((unsigned)j << 8) + lb));
    h2 xa = __builtin_bit_cast(h2, u.x), xb = __builtin_bit_cast(h2, u.y);
    float p1 = dot2(lrelu_pk(xa + xra), atta, 0.f);
    p1 = dot2(lrelu_pk(xb + xrb), attb, p1);
    p1 += __shfl_xor(p1, 1);
    p1 += __shfl_xor(p1, 2);
    p1 += __shfl_xor(p1, 4);
    float mN = fmaxf(m, p1);
    float r = __expf(m - mN), w1 = __expf(p1 - mN);
    d = fmaf(d, r, w1);
    h2 rp = pk2(r), w1p = pk2(w1);
    acca = acca * rp + xa * w1p;
    accb = accb * rp + xb * w1p;
  }

  float inv = 1.f / (d + 1e-16f);
  float4 b4 = *(const float4*)&bias[lb];
  float o0 = elu1(fmaf((float)acca[0], inv, b4.x));
  float o1 = elu1(fmaf((float)acca[1], inv, b4.y));
  float o2 = elu1(fmaf((float)accb[0], inv, b4.z));
  float o3 = elu1(fmaf((float)accb[1], inv, b4.w));
  ushort4 uo;
  uo.x = f2h(o0); uo.y = f2h(o1); uo.z = f2h(o2); uo.w = f2h(o3);
  *(ushort4*)(hout + noff) = uo;
}

// ---------------- layer 3: skinny linear (256->2 twice), wave per node ------

__global__ __launch_bounds__(256) void k_lin3(
    const unsigned short* __restrict__ hq,
    const float* __restrict__ Wl, const float* __restrict__ bl,
    const float* __restrict__ Wr, const float* __restrict__ br,
    float* __restrict__ xlr3,  // [N,4] = {xl0,xl1,xr0,xr1}
    int n) {
  int lane = threadIdx.x & 63;
  int node = blockIdx.x * (blockDim.x >> 6) + (threadIdx.x >> 6);
  if (node >= n) return;
  ushort4 uh = *(const ushort4*)(hq + (((unsigned)node << 8) + (lane << 2)));
  float hv[4] = {h2f(uh.x), h2f(uh.y), h2f(uh.z), h2f(uh.w)};
  float al0 = 0.f, al1 = 0.f, ar0 = 0.f, ar1 = 0.f;
#pragma unroll
  for (int j = 0; j < 4; ++j) {
    int k = lane * 4 + j;
    al0 = fmaf(hv[j], Wl[k * 2 + 0], al0);
    al1 = fmaf(hv[j], Wl[k * 2 + 1], al1);
    ar0 = fmaf(hv[j], Wr[k * 2 + 0], ar0);
    ar1 = fmaf(hv[j], Wr[k * 2 + 1], ar1);
  }
#pragma unroll
  for (int s = 1; s < 64; s <<= 1) {
    al0 += __shfl_xor(al0, s);
    al1 += __shfl_xor(al1, s);
    ar0 += __shfl_xor(ar0, s);
    ar1 += __shfl_xor(ar1, s);
  }
  if (lane == 0) {
    float4 o = make_float4(al0 + bl[0], al1 + bl[1], ar0 + br[0], ar1 + br[1]);
    *(float4*)&xlr3[(size_t)node * 4] = o;
  }
}

// ---------------- layer 3 edge pass + log_softmax, thread per node ----------

__global__ void k_edge3(const float* __restrict__ xlr3,
                        const int* __restrict__ offs, const int* __restrict__ csr_src,
                        const float* __restrict__ att,  // [2]
                        const float* __restrict__ b,    // [2]
                        float* __restrict__ out, int n) {
  int i = blockIdx.x * blockDim.x + threadIdx.x;
  if (i >= n) return;
  float a0 = att[0], a1 = att[1];
  float xr0 = xlr3[(size_t)i * 4 + 2], xr1 = xlr3[(size_t)i * 4 + 3];
  // self-loop first
  float sl0 = xlr3[(size_t)i * 4 + 0], sl1 = xlr3[(size_t)i * 4 + 1];
  float m = lrelu(sl0 + xr0) * a0 + lrelu(sl1 + xr1) * a1;
  float d = 1.f, ac0 = sl0, ac1 = sl1;
  int e0 = offs[i], e1 = offs[i + 1];
  for (int e = e0; e < e1; ++e) {
    int j = csr_src[e];
    float xl0 = xlr3[(size_t)j * 4 + 0], xl1 = xlr3[(size_t)j * 4 + 1];
    float p = lrelu(xl0 + xr0) * a0 + lrelu(xl1 + xr1) * a1;
    float mN = fmaxf(m, p);
    float r = __expf(m - mN), w = __expf(p - mN);
    d = fmaf(d, r, w);
    ac0 = fmaf(ac0, r, w * xl0);
    ac1 = fmaf(ac1, r, w * xl1);
    m = mN;
  }
  float inv = 1.f / (d + 1e-16f);
  float o0 = fmaf(ac0, inv, b[0]);
  float o1 = fmaf(ac1, inv, b[1]);
  float mx = fmaxf(o0, o1);
  float lse = mx + logf(expf(o0 - mx) + expf(o1 - mx));
  out[(size_t)i * 2 + 0] = o0 - lse;
  out[(size_t)i * 2 + 1] = o1 - lse;
}

// ---------------------------------------------------------------------------

static inline size_t align_up(size_t v, size_t a) { return (v + a - 1) & ~(a - 1); }

extern "C" void kernel_launch(void* const* d_in, const int* in_sizes, int n_in,
                              void* d_out, int out_size, void* d_ws, size_t ws_size,
                              hipStream_t stream) {
  const float* x    = (const float*)d_in[0];
  const int*   ei   = (const int*)d_in[1];
  const float* Wl1  = (const float*)d_in[2];
  const float* bl1  = (const float*)d_in[3];
  const float* Wr1  = (const float*)d_in[4];
  const float* br1  = (const float*)d_in[5];
  const float* att1 = (const float*)d_in[6];
  const float* b1   = (const float*)d_in[7];
  const float* Wl3  = (const float*)d_in[8];
  const float* bl3  = (const float*)d_in[9];
  const float* Wr3  = (const float*)d_in[10];
  const float* br3  = (const float*)d_in[11];
  const float* att3 = (const float*)d_in[12];
  const float* b3   = (const float*)d_in[13];
  const float* Wl2  = (const float*)d_in[14];
  const float* bl2  = (const float*)d_in[15];
  const float* Wr2  = (const float*)d_in[16];
  const float* br2  = (const float*)d_in[17];
  const float* att2 = (const float*)d_in[18];
  const float* b2   = (const float*)d_in[19];

  const int N = in_sizes[0] / 128;  // 50000
  const int E = in_sizes[1] / 2;    // 400000
  const int Npad = ((N + 63) / 64) * 64;  // 50048
  const int* srcp = ei;
  const int* dstp = ei + E;

  // workspace layout
  char* w = (char*)d_ws;
  size_t off = 0;
  int* deg     = (int*)(w + off); off = align_up(off + (size_t)N * 4, 256);
  int* offs    = (int*)(w + off); off = align_up(off + (size_t)(N + 1) * 4, 256);
  int* cursor  = (int*)(w + off); off = align_up(off + (size_t)N * 4, 256);
  int* csr_src = (int*)(w + off); off = align_up(off + (size_t)E * 4, 256);
  int* bsum    = (int*)(w + off); off = align_up(off + (size_t)256 * 4, 256);
  unsigned short* x_h  = (unsigned short*)(w + off); off = align_up(off + (size_t)Npad * 128 * 2, 256);
  unsigned short* h_h  = (unsigned short*)(w + off); off = align_up(off + (size_t)Npad * 256 * 2, 256);
  unsigned short* xlh  = (unsigned short*)(w + off); off = align_up(off + (size_t)N * 256 * 2, 256);
  unsigned short* xrh  = (unsigned short*)(w + off); off = align_up(off + (size_t)N * 256 * 2, 256);
  float* xlr3  = (float*)(w + off); off = align_up(off + (size_t)N * 4 * 4, 256);
  unsigned short* Bt1 = (unsigned short*)(w + off); off = align_up(off + (size_t)512 * 128 * 2, 256);
  unsigned short* Bt2 = (unsigned short*)(w + off); off = align_up(off + (size_t)512 * 256 * 2, 256);
  (void)ws_size;

  const int nb = (N + 1023) / 1024;

  // ---- build CSR (incoming edges per dst), reused by all 3 layers ----
  hipMemsetAsync(deg, 0, (size_t)N * 4, stream);
  k_count<<<(E + 255) / 256, 256, 0, stream>>>(dstp, deg, E);
  k_bsum<<<nb, 256, 0, stream>>>(deg, N, bsum);
  k_offsets<<<nb, 256, 0, stream>>>(deg, bsum, nb, N, offs, cursor);
  k_scatter<<<(E + 255) / 256, 256, 0, stream>>>(srcp, dstp, cursor, csr_src, E);

  // ---- quantize weights (transposed) and x to fp16 ----
  k_split<<<(512 * 128 + 255) / 256, 256, 0, stream>>>(Wl1, Wr1, 128, 7, Bt1);
  k_split<<<(512 * 256 + 255) / 256, 256, 0, stream>>>(Wl3, Wr3, 256, 8, Bt2);
  {
    int total4 = Npad * 128 / 4;
    k_quantA<<<(total4 + 255) / 256, 256, 0, stream>>>(x, N, total4, x_h);
  }
  // zero pad rows of h plane (k_edge writes only rows < N)
  hipMemsetAsync(h_h + (size_t)N * 256, 0, (size_t)(Npad - N) * 256 * 2, stream);

  dim3 ggrid(Npad / 64, 2);
  int nodeBlocks = (N + 3) / 4;  // 4 waves (nodes) per 256-thread block

  // ---- layer 1: 128 -> 8x32, concat, ELU ----
  k_gemm_mfma<<<ggrid, 256, 0, stream>>>(x_h, N, 128, Bt1, bl1, br1, xlh, xrh);
  k_edge<<<nodeBlocks, 256, 0, stream>>>(xlh, xrh, offs, csr_src, att1, b1, h_h, N);

  // ---- layer 2: 256 -> 8x32, concat, ELU ----
  k_gemm_mfma<<<ggrid, 256, 0, stream>>>(h_h, N, 256, Bt2, bl3, br3, xlh, xrh);
  k_edge<<<nodeBlocks, 256, 0, stream>>>(xlh, xrh, offs, csr_src, att3, b3, h_h, N);

  // ---- layer 3: 256 -> 1x2, mean(=identity), log_softmax ----
  k_lin3<<<nodeBlocks, 256, 0, stream>>>(h_h, Wl2, bl2, Wr2, br2, xlr3, N);
  k_edge3<<<(N + 255) / 256, 256, 0, stream>>>(xlr3, offs, csr_src, att2, b2,
                                               (float*)d_out, N);
}

// Round 11
// 230.799 us; speedup vs baseline: 2.7082x; 1.0427x over previous
//
#include <hip/hip_runtime.h>
#include <cstdint>
#include <cstddef>

// ---------------------------------------------------------------------------
// GATv2 3-layer forward on MI355X.
//   All GEMM operands fp16 (rel err 5e-4), fp32 accumulate MFMA.
//   k_gemm_mfma : tile 64x256, double-buffered global_load_lds staging with
//                 counted vmcnt (never 0 in loop), 32-bit addressing.
//   k_edge      : packed-fp16 VALU, 4-edge unroll (4 gathers in flight),
//                 merge-tree online softmax, self-loop = initial state.
// Graph CSR built once (device-wide scan), reused 3x.
// ---------------------------------------------------------------------------

typedef __attribute__((ext_vector_type(8))) _Float16 v8h;
typedef __attribute__((ext_vector_type(2))) _Float16 h2;
typedef __attribute__((ext_vector_type(2))) __fp16 h2r;  // intrinsic ret type
typedef __attribute__((ext_vector_type(4))) float v4f;

__device__ __forceinline__ float lrelu(float v) { return fmaxf(v, 0.2f * v); }
__device__ __forceinline__ float elu1(float v)  { return v > 0.f ? v : expm1f(v); }

__device__ __forceinline__ unsigned short f2h(float f) {
  _Float16 h = (_Float16)f;
  return __builtin_bit_cast(unsigned short, h);
}
__device__ __forceinline__ float h2f(unsigned short s) {
  return (float)__builtin_bit_cast(_Float16, s);
}

__device__ __forceinline__ h2 cvt_pk(float a, float b) {  // f32x2 -> half2
  h2r t = __builtin_amdgcn_cvt_pkrtz(a, b);
  return __builtin_bit_cast(h2, t);
}
__device__ __forceinline__ h2 pk2(float a) { return cvt_pk(a, a); }

// packed lrelu: lrelu(v) = 0.6*v + 0.4*|v|  (|.| is a bitwise AND on the pair)
__device__ __forceinline__ h2 lrelu_pk(h2 v) {
  unsigned int u = __builtin_bit_cast(unsigned int, v) & 0x7FFF7FFFu;
  h2 av = __builtin_bit_cast(h2, u);
  h2 c6 = {(_Float16)0.6f, (_Float16)0.6f};
  h2 c4 = {(_Float16)0.4f, (_Float16)0.4f};
  return v * c6 + av * c4;
}

__device__ __forceinline__ float dot2(h2 a, h2 b, float c) {
#if __has_builtin(__builtin_amdgcn_fdot2)
  return __builtin_amdgcn_fdot2(__builtin_bit_cast(h2r, a),
                                __builtin_bit_cast(h2r, b), c, false);
#else
  return fmaf((float)a[0], (float)b[0], fmaf((float)a[1], (float)b[1], c));
#endif
}

__device__ __forceinline__ void gl_lds16(const void* g, void* l) {
  __builtin_amdgcn_global_load_lds(
      (const __attribute__((address_space(1))) unsigned int*)g,
      (__attribute__((address_space(3))) unsigned int*)l, 16, 0, 0);
}

// ---------------- CSR build ----------------

__global__ void k_count(const int* __restrict__ dst, int* __restrict__ deg, int E) {
  int e = blockIdx.x * blockDim.x + threadIdx.x;
  if (e < E) atomicAdd(&deg[dst[e]], 1);
}

__global__ __launch_bounds__(256) void k_bsum(const int* __restrict__ deg, int n,
                                              int* __restrict__ bsum) {
  __shared__ int red[256];
  int t = threadIdx.x, bid = blockIdx.x;
  int i0 = bid * 1024 + t * 4;
  int s = 0;
  if (i0 + 3 < n) {
    int4 v = *(const int4*)&deg[i0];
    s = v.x + v.y + v.z + v.w;
  } else {
#pragma unroll
    for (int j = 0; j < 4; ++j)
      if (i0 + j < n) s += deg[i0 + j];
  }
  red[t] = s;
  __syncthreads();
  for (int off = 128; off > 0; off >>= 1) {
    if (t < off) red[t] += red[t + off];
    __syncthreads();
  }
  if (t == 0) bsum[bid] = red[0];
}

__global__ __launch_bounds__(256) void k_offsets(const int* __restrict__ deg,
                                                 const int* __restrict__ bsum,
                                                 int nb, int n,
                                                 int* __restrict__ offs,
                                                 int* __restrict__ cursor) {
  __shared__ int sc[256];
  int t = threadIdx.x, bid = blockIdx.x;
  int base = 0;
  for (int b = 0; b < bid; ++b) base += bsum[b];
  int i0 = bid * 1024 + t * 4;
  int v0 = 0, v1 = 0, v2 = 0, v3 = 0;
  if (i0 + 3 < n) {
    int4 v = *(const int4*)&deg[i0];
    v0 = v.x; v1 = v.y; v2 = v.z; v3 = v.w;
  } else {
    if (i0 < n)     v0 = deg[i0];
    if (i0 + 1 < n) v1 = deg[i0 + 1];
    if (i0 + 2 < n) v2 = deg[i0 + 2];
    if (i0 + 3 < n) v3 = deg[i0 + 3];
  }
  int s = v0 + v1 + v2 + v3;
  sc[t] = s;
  __syncthreads();
  for (int off = 1; off < 256; off <<= 1) {
    int x = (t >= off) ? sc[t - off] : 0;
    __syncthreads();
    sc[t] += x;
    __syncthreads();
  }
  int run = base + sc[t] - s;
  int o0 = run, o1 = run + v0, o2 = o1 + v1, o3 = o2 + v2;
  if (i0 + 3 < n) {
    *(int4*)&offs[i0] = make_int4(o0, o1, o2, o3);
    *(int4*)&cursor[i0] = make_int4(o0, o1, o2, o3);
  } else {
    if (i0 < n)     { offs[i0] = o0;     cursor[i0] = o0; }
    if (i0 + 1 < n) { offs[i0 + 1] = o1; cursor[i0 + 1] = o1; }
    if (i0 + 2 < n) { offs[i0 + 2] = o2; cursor[i0 + 2] = o2; }
    if (i0 + 3 < n) { offs[i0 + 3] = o3; cursor[i0 + 3] = o3; }
  }
  if (bid == nb - 1 && t == 255) offs[n] = base + sc[255];
}

__global__ void k_scatter(const int* __restrict__ src, const int* __restrict__ dst,
                          int* __restrict__ cursor, int* __restrict__ csr_src, int E) {
  int e = blockIdx.x * blockDim.x + threadIdx.x;
  if (e < E) {
    int pos = atomicAdd(&cursor[dst[e]], 1);
    csr_src[pos] = src[e];
  }
}

// ---------------- weight transpose+quantize: Bt[n][k] = fp16(W[k][n]) -------

__global__ void k_split(const float* __restrict__ Wl, const float* __restrict__ Wr,
                        int K, int logK, unsigned short* __restrict__ Bt) {
  int idx = blockIdx.x * blockDim.x + threadIdx.x;
  if (idx >= 512 * K) return;
  int n = idx >> logK;
  int k = idx & (K - 1);
  float w = (n < 256) ? Wl[(size_t)k * 256 + n] : Wr[(size_t)k * 256 + (n - 256)];
  Bt[idx] = f2h(w);
}

// ---------------- input quantize: x[N,128] fp32 -> fp16 plane [Npad,128] ----

__global__ void k_quantA(const float* __restrict__ X, int Nreal, int total4,
                         unsigned short* __restrict__ Hh) {
  int idx = blockIdx.x * blockDim.x + threadIdx.x;  // 4 elems each
  if (idx >= total4) return;
  int row = idx >> 5;  // (idx*4)>>7, K=128
  ushort4 uh;
  if (row < Nreal) {
    float4 v = *(const float4*)&X[(size_t)idx * 4];
    uh.x = f2h(v.x); uh.y = f2h(v.y); uh.z = f2h(v.z); uh.w = f2h(v.w);
  } else {
    uh = make_ushort4(0, 0, 0, 0);
  }
  *(ushort4*)&Hh[(size_t)idx * 4] = uh;
}

// ---------------- fp16 MFMA GEMM, tile 64x256, double-buffered --------------

__global__ __launch_bounds__(256) void k_gemm_mfma(
    const unsigned short* __restrict__ A_g,  // [Npad,K] fp16
    int Nreal, int K,
    const unsigned short* __restrict__ Bt,   // [512,K] fp16 (transposed W)
    const float* __restrict__ bl, const float* __restrict__ br,
    unsigned short* __restrict__ xl_h, unsigned short* __restrict__ xr_h) {
  __shared__ __align__(16) short Ah[2][64 * 32];    // 8 KB
  __shared__ __align__(16) short Bh[2][256 * 32];   // 32 KB

  const int tid = threadIdx.x;
  const int lane = tid & 63;
  const int wid = tid >> 6;
  const int l15 = lane & 15, g = lane >> 4;
  const int bm = blockIdx.x * 64;
  const int half = blockIdx.y;           // 0: xl, 1: xr
  const int bn = half * 256;

  v4f acc[4][4];
#pragma unroll
  for (int m = 0; m < 4; ++m)
#pragma unroll
    for (int n = 0; n < 4; ++n) acc[m][n] = (v4f)(0.f);

  const int arow = tid >> 2, aslot = tid & 3;
  const int aoct = aslot ^ ((arow >> 1) & 3);
  const unsigned gaBase = (unsigned)(bm + arow) * K + aoct * 8;

  auto STAGE = [&](int buf, int k0) {
    gl_lds16(A_g + (gaBase + k0), &Ah[buf][wid * 512]);
#pragma unroll
    for (int it = 0; it < 4; ++it) {
      int task = it * 256 + tid;
      int col = task >> 2, slot = task & 3;
      int oct = slot ^ ((col >> 1) & 3);
      unsigned gb = (unsigned)(bn + col) * K + k0 + oct * 8;
      gl_lds16(Bt + gb, &Bh[buf][it * 2048 + wid * 512]);
    }
  };

  const int nt = K >> 5;
  STAGE(0, 0);
  for (int t = 0; t < nt; ++t) {
    const int cur = t & 1;
    if (t + 1 < nt) {
      STAGE(cur ^ 1, (t + 1) << 5);
      asm volatile("s_waitcnt vmcnt(5)" ::: "memory");  // cur's loads landed
    } else {
      asm volatile("s_waitcnt vmcnt(0)" ::: "memory");
    }
    __builtin_amdgcn_sched_barrier(0);
    __builtin_amdgcn_s_barrier();  // cur buf staged by ALL waves

    v8h a_h[4], b_h[4];
#pragma unroll
    for (int m = 0; m < 4; ++m) {
      int r = m * 16 + l15;
      int s = g ^ ((r >> 1) & 3);
      a_h[m] = *(const v8h*)&Ah[cur][r * 32 + s * 8];
    }
#pragma unroll
    for (int n = 0; n < 4; ++n) {
      int c = wid * 64 + n * 16 + l15;
      int s = g ^ ((c >> 1) & 3);
      b_h[n] = *(const v8h*)&Bh[cur][c * 32 + s * 8];
    }
#pragma unroll
    for (int m = 0; m < 4; ++m)
#pragma unroll
      for (int n = 0; n < 4; ++n)
        acc[m][n] = __builtin_amdgcn_mfma_f32_16x16x32_f16(a_h[m], b_h[n], acc[m][n], 0, 0, 0);
    __builtin_amdgcn_s_barrier();  // cur reads done before re-stage of cur
  }

  // ---- epilogue: per-wave LDS transpose (reuses Bh[0]), fp16 stores ----
  float* scr = (float*)&Bh[0][0] + wid * 320;  // 16 rows x stride 20 floats
  const int erow = lane >> 2, ecq = lane & 3;
  unsigned short* outp = half ? xr_h : xl_h;
  const float* bias = half ? br : bl;
#pragma unroll
  for (int m = 0; m < 4; ++m) {
#pragma unroll
    for (int n = 0; n < 4; ++n) {
#pragma unroll
      for (int r = 0; r < 4; ++r) scr[(g * 4 + r) * 20 + l15] = acc[m][n][r];
      float4 v = *(const float4*)&scr[erow * 20 + ecq * 4];
      int row = bm + m * 16 + erow;
      if (row < Nreal) {
        int col = wid * 64 + n * 16 + ecq * 4;
        float4 bv = *(const float4*)&bias[col];
        ushort4 u;
        u.x = f2h(v.x + bv.x); u.y = f2h(v.y + bv.y);
        u.z = f2h(v.z + bv.z); u.w = f2h(v.w + bv.w);
        *(ushort4*)&outp[(size_t)row * 256 + col] = u;
      }
    }
  }
}

// ---------------- fused GATv2 edge pass (H=8, C=32), wave per dst node ------
// 4-edge unroll: 4 gathers in flight, merge-tree softmax combine.

__global__ __launch_bounds__(256) void k_edge(
    const unsigned short* __restrict__ xl_h,  // [N,256] fp16
    const unsigned short* __restrict__ xr_h,  // [N,256] fp16
    const int* __restrict__ offs, const int* __restrict__ csr_src,
    const float* __restrict__ att,   // [8*32]
    const float* __restrict__ bias,  // [256]
    unsigned short* __restrict__ hout,  // [Npad,256] fp16
    int n) {
  int lane = threadIdx.x & 63;
  int node = blockIdx.x * (blockDim.x >> 6) + (threadIdx.x >> 6);
  if (node >= n) return;

  const unsigned lb = (unsigned)(lane << 2);
  float4 attf = *(const float4*)&att[lb];
  h2 atta = cvt_pk(attf.x, attf.y);
  h2 attb = cvt_pk(attf.z, attf.w);
  const unsigned noff = ((unsigned)node << 8) + lb;
  uint2 urx = *(const uint2*)(xr_h + noff);
  h2 xra = __builtin_bit_cast(h2, urx.x), xrb = __builtin_bit_cast(h2, urx.y);
  const unsigned short* xlb = xl_h + lb;  // lane-offset base

  // score of edge with loaded row (xa,xb), fully ILP-friendly
  auto score = [&](h2 xa, h2 xb) -> float {
    float p = dot2(lrelu_pk(xa + xra), atta, 0.f);
    p = dot2(lrelu_pk(xb + xrb), attb, p);
    p += __shfl_xor(p, 1);
    p += __shfl_xor(p, 2);
    p += __shfl_xor(p, 4);
    return p;
  };

  // self-loop as initial state: m = p_self, d = 1, acc = xl(node)
  uint2 us = *(const uint2*)(xl_h + noff);
  h2 acca = __builtin_bit_cast(h2, us.x), accb = __builtin_bit_cast(h2, us.y);
  float m = score(acca, accb), d = 1.f;

  int e0 = offs[node], e1 = offs[node + 1];
  int e = e0;
  for (; e + 3 < e1; e += 4) {
    int j1 = csr_src[e], j2 = csr_src[e + 1];
    int j3 = csr_src[e + 2], j4 = csr_src[e + 3];
    uint2 u1 = *(const uint2*)(xlb + ((unsigned)j1 << 8));
    uint2 u2 = *(const uint2*)(xlb + ((unsigned)j2 << 8));
    uint2 u3 = *(const uint2*)(xlb + ((unsigned)j3 << 8));
    uint2 u4 = *(const uint2*)(xlb + ((unsigned)j4 << 8));
    h2 x1a = __builtin_bit_cast(h2, u1.x), x1b = __builtin_bit_cast(h2, u1.y);
    h2 x2a = __builtin_bit_cast(h2, u2.x), x2b = __builtin_bit_cast(h2, u2.y);
    h2 x3a = __builtin_bit_cast(h2, u3.x), x3b = __builtin_bit_cast(h2, u3.y);
    h2 x4a = __builtin_bit_cast(h2, u4.x), x4b = __builtin_bit_cast(h2, u4.y);
    float p1 = score(x1a, x1b), p2 = score(x2a, x2b);
    float p3 = score(x3a, x3b), p4 = score(x4a, x4b);
    // pair-local states
    float m12 = fmaxf(p1, p2);
    float w1 = __expf(p1 - m12), w2 = __expf(p2 - m12);
    float d12 = w1 + w2;
    h2 w1p = pk2(w1), w2p = pk2(w2);
    h2 c12a = x1a * w1p + x2a * w2p;
    h2 c12b = x1b * w1p + x2b * w2p;
    float m34 = fmaxf(p3, p4);
    float w3 = __expf(p3 - m34), w4 = __expf(p4 - m34);
    float d34 = w3 + w4;
    h2 w3p = pk2(w3), w4p = pk2(w4);
    h2 c34a = x3a * w3p + x4a * w4p;
    h2 c34b = x3b * w3p + x4b * w4p;
    // tree merge: S = S12 + S34
    float mS = fmaxf(m12, m34);
    float rA = __expf(m12 - mS), rB = __expf(m34 - mS);
    float dS = fmaf(d12, rA, d34 * rB);
    h2 rAp = pk2(rA), rBp = pk2(rB);
    h2 cSa = c12a * rAp + c34a * rBp;
    h2 cSb = c12b * rAp + c34b * rBp;
    // merge S into running state
    float mN = fmaxf(m, mS);
    float r = __expf(m - mN), rS = __expf(mS - mN);
    d = fmaf(d, r, dS * rS);
    h2 rp = pk2(r), rSp = pk2(rS);
    acca = acca * rp + cSa * rSp;
    accb = accb * rp + cSb * rSp;
    m = mN;
  }
  for (; e + 1 < e1; e += 2) {  // pair remainder
    int j1 = csr_src[e], j2 = csr_src[e + 1];
    uint2 u1 = *(const uint2*)(xlb + ((unsigned)j1 << 8));
    uint2 u2 = *(const uint2*)(xlb + ((unsigned)j2 << 8));
    h2 x1a = __builtin_bit_cast(h2, u1.x), x1b = __builtin_bit_cast(h2, u1.y);
    h2 x2a = __builtin_bit_cast(h2, u2.x), x2b = __builtin_bit_cast(h2, u2.y);
    float p1 = score(x1a, x1b), p2 = score(x2a, x2b);
    float m12 = fmaxf(p1, p2);
    float w1 = __expf(p1 - m12), w2 = __expf(p2 - m12);
    float d12 = w1 + w2;
    h2 w1p = pk2(w1), w2p = pk2(w2);
    h2 ca = x1a * w1p + x2a * w2p;
    h2 cb = x1b * w1p + x2b * w2p;
    float mN = fmaxf(m, m12);
    float r = __expf(m - mN), r2 = __expf(m12 - mN);
    d = fmaf(d, r, d12 * r2);
    h2 rp = pk2(r), r2p = pk2(r2);
    acca = acca * rp + ca * r2p;
    accb = accb * rp + cb * r2p;
    m = mN;
  }
  if (e < e1) {  // tail edge
    int j = csr_src[e];
    uint2 u = *(const uint2*)(xlb + ((unsigned)j << 8));
    h2 xa = __builtin_bit_cast(h2, u.x), xb = __builtin_bit_cast(h2, u.y);
    float p1 = score(xa, xb);
    float mN = fmaxf(m, p1);
    float r = __expf(m - mN), w1 = __expf(p1 - mN);
    d = fmaf(d, r, w1);
    h2 rp = pk2(r), w1p = pk2(w1);
    acca = acca * rp + xa * w1p;
    accb = accb * rp + xb * w1p;
  }

  float inv = 1.f / (d + 1e-16f);
  float4 b4 = *(const float4*)&bias[lb];
  float o0 = elu1(fmaf((float)acca[0], inv, b4.x));
  float o1 = elu1(fmaf((float)acca[1], inv, b4.y));
  float o2 = elu1(fmaf((float)accb[0], inv, b4.z));
  float o3 = elu1(fmaf((float)accb[1], inv, b4.w));
  ushort4 uo;
  uo.x = f2h(o0); uo.y = f2h(o1); uo.z = f2h(o2); uo.w = f2h(o3);
  *(ushort4*)(hout + noff) = uo;
}

// ---------------- layer 3: skinny linear (256->2 twice), wave per node ------

__global__ __launch_bounds__(256) void k_lin3(
    const unsigned short* __restrict__ hq,
    const float* __restrict__ Wl, const float* __restrict__ bl,
    const float* __restrict__ Wr, const float* __restrict__ br,
    float* __restrict__ xlr3,  // [N,4] = {xl0,xl1,xr0,xr1}
    int n) {
  int lane = threadIdx.x & 63;
  int node = blockIdx.x * (blockDim.x >> 6) + (threadIdx.x >> 6);
  if (node >= n) return;
  ushort4 uh = *(const ushort4*)(hq + (((unsigned)node << 8) + (lane << 2)));
  float hv[4] = {h2f(uh.x), h2f(uh.y), h2f(uh.z), h2f(uh.w)};
  float al0 = 0.f, al1 = 0.f, ar0 = 0.f, ar1 = 0.f;
#pragma unroll
  for (int j = 0; j < 4; ++j) {
    int k = lane * 4 + j;
    al0 = fmaf(hv[j], Wl[k * 2 + 0], al0);
    al1 = fmaf(hv[j], Wl[k * 2 + 1], al1);
    ar0 = fmaf(hv[j], Wr[k * 2 + 0], ar0);
    ar1 = fmaf(hv[j], Wr[k * 2 + 1], ar1);
  }
#pragma unroll
  for (int s = 1; s < 64; s <<= 1) {
    al0 += __shfl_xor(al0, s);
    al1 += __shfl_xor(al1, s);
    ar0 += __shfl_xor(ar0, s);
    ar1 += __shfl_xor(ar1, s);
  }
  if (lane == 0) {
    float4 o = make_float4(al0 + bl[0], al1 + bl[1], ar0 + br[0], ar1 + br[1]);
    *(float4*)&xlr3[(size_t)node * 4] = o;
  }
}

// ---------------- layer 3 edge pass + log_softmax, thread per node ----------

__global__ void k_edge3(const float* __restrict__ xlr3,
                        const int* __restrict__ offs, const int* __restrict__ csr_src,
                        const float* __restrict__ att,  // [2]
                        const float* __restrict__ b,    // [2]
                        float* __restrict__ out, int n) {
  int i = blockIdx.x * blockDim.x + threadIdx.x;
  if (i >= n) return;
  float a0 = att[0], a1 = att[1];
  float xr0 = xlr3[(size_t)i * 4 + 2], xr1 = xlr3[(size_t)i * 4 + 3];
  // self-loop first
  float sl0 = xlr3[(size_t)i * 4 + 0], sl1 = xlr3[(size_t)i * 4 + 1];
  float m = lrelu(sl0 + xr0) * a0 + lrelu(sl1 + xr1) * a1;
  float d = 1.f, ac0 = sl0, ac1 = sl1;
  int e0 = offs[i], e1 = offs[i + 1];
  for (int e = e0; e < e1; ++e) {
    int j = csr_src[e];
    float xl0 = xlr3[(size_t)j * 4 + 0], xl1 = xlr3[(size_t)j * 4 + 1];
    float p = lrelu(xl0 + xr0) * a0 + lrelu(xl1 + xr1) * a1;
    float mN = fmaxf(m, p);
    float r = __expf(m - mN), w = __expf(p - mN);
    d = fmaf(d, r, w);
    ac0 = fmaf(ac0, r, w * xl0);
    ac1 = fmaf(ac1, r, w * xl1);
    m = mN;
  }
  float inv = 1.f / (d + 1e-16f);
  float o0 = fmaf(ac0, inv, b[0]);
  float o1 = fmaf(ac1, inv, b[1]);
  float mx = fmaxf(o0, o1);
  float lse = mx + logf(expf(o0 - mx) + expf(o1 - mx));
  out[(size_t)i * 2 + 0] = o0 - lse;
  out[(size_t)i * 2 + 1] = o1 - lse;
}

// ---------------------------------------------------------------------------

static inline size_t align_up(size_t v, size_t a) { return (v + a - 1) & ~(a - 1); }

extern "C" void kernel_launch(void* const* d_in, const int* in_sizes, int n_in,
                              void* d_out, int out_size, void* d_ws, size_t ws_size,
                              hipStream_t stream) {
  const float* x    = (const float*)d_in[0];
  const int*   ei   = (const int*)d_in[1];
  const float* Wl1  = (const float*)d_in[2];
  const float* bl1  = (const float*)d_in[3];
  const float* Wr1  = (const float*)d_in[4];
  const float* br1  = (const float*)d_in[5];
  const float* att1 = (const float*)d_in[6];
  const float* b1   = (const float*)d_in[7];
  const float* Wl3  = (const float*)d_in[8];
  const float* bl3  = (const float*)d_in[9];
  const float* Wr3  = (const float*)d_in[10];
  const float* br3  = (const float*)d_in[11];
  const float* att3 = (const float*)d_in[12];
  const float* b3   = (const float*)d_in[13];
  const float* Wl2  = (const float*)d_in[14];
  const float* bl2  = (const float*)d_in[15];
  const float* Wr2  = (const float*)d_in[16];
  const float* br2  = (const float*)d_in[17];
  const float* att2 = (const float*)d_in[18];
  const float* b2   = (const float*)d_in[19];

  const int N = in_sizes[0] / 128;  // 50000
  const int E = in_sizes[1] / 2;    // 400000
  const int Npad = ((N + 63) / 64) * 64;  // 50048
  const int* srcp = ei;
  const int* dstp = ei + E;

  // workspace layout
  char* w = (char*)d_ws;
  size_t off = 0;
  int* deg     = (int*)(w + off); off = align_up(off + (size_t)N * 4, 256);
  int* offs    = (int*)(w + off); off = align_up(off + (size_t)(N + 1) * 4, 256);
  int* cursor  = (int*)(w + off); off = align_up(off + (size_t)N * 4, 256);
  int* csr_src = (int*)(w + off); off = align_up(off + (size_t)E * 4, 256);
  int* bsum    = (int*)(w + off); off = align_up(off + (size_t)256 * 4, 256);
  unsigned short* x_h  = (unsigned short*)(w + off); off = align_up(off + (size_t)Npad * 128 * 2, 256);
  unsigned short* h_h  = (unsigned short*)(w + off); off = align_up(off + (size_t)Npad * 256 * 2, 256);
  unsigned short* xlh  = (unsigned short*)(w + off); off = align_up(off + (size_t)N * 256 * 2, 256);
  unsigned short* xrh  = (unsigned short*)(w + off); off = align_up(off + (size_t)N * 256 * 2, 256);
  float* xlr3  = (float*)(w + off); off = align_up(off + (size_t)N * 4 * 4, 256);
  unsigned short* Bt1 = (unsigned short*)(w + off); off = align_up(off + (size_t)512 * 128 * 2, 256);
  unsigned short* Bt2 = (unsigned short*)(w + off); off = align_up(off + (size_t)512 * 256 * 2, 256);
  (void)ws_size;

  const int nb = (N + 1023) / 1024;

  // ---- build CSR (incoming edges per dst), reused by all 3 layers ----
  hipMemsetAsync(deg, 0, (size_t)N * 4, stream);
  k_count<<<(E + 255) / 256, 256, 0, stream>>>(dstp, deg, E);
  k_bsum<<<nb, 256, 0, stream>>>(deg, N, bsum);
  k_offsets<<<nb, 256, 0, stream>>>(deg, bsum, nb, N, offs, cursor);
  k_scatter<<<(E + 255) / 256, 256, 0, stream>>>(srcp, dstp, cursor, csr_src, E);

  // ---- quantize weights (transposed) and x to fp16 ----
  k_split<<<(512 * 128 + 255) / 256, 256, 0, stream>>>(Wl1, Wr1, 128, 7, Bt1);
  k_split<<<(512 * 256 + 255) / 256, 256, 0, stream>>>(Wl3, Wr3, 256, 8, Bt2);
  {
    int total4 = Npad * 128 / 4;
    k_quantA<<<(total4 + 255) / 256, 256, 0, stream>>>(x, N, total4, x_h);
  }
  // zero pad rows of h plane (k_edge writes only rows < N)
  hipMemsetAsync(h_h + (size_t)N * 256, 0, (size_t)(Npad - N) * 256 * 2, stream);

  dim3 ggrid(Npad / 64, 2);
  int nodeBlocks = (N + 3) / 4;  // 4 waves (nodes) per 256-thread block

  // ---- layer 1: 128 -> 8x32, concat, ELU ----
  k_gemm_mfma<<<ggrid, 256, 0, stream>>>(x_h, N, 128, Bt1, bl1, br1, xlh, xrh);
  k_edge<<<nodeBlocks, 256, 0, stream>>>(xlh, xrh, offs, csr_src, att1, b1, h_h, N);

  // ---- layer 2: 256 -> 8x32, concat, ELU ----
  k_gemm_mfma<<<ggrid, 256, 0, stream>>>(h_h, N, 256, Bt2, bl3, br3, xlh, xrh);
  k_edge<<<nodeBlocks, 256, 0, stream>>>(xlh, xrh, offs, csr_src, att3, b3, h_h, N);

  // ---- layer 3: 256 -> 1x2, mean(=identity), log_softmax ----
  k_lin3<<<nodeBlocks, 256, 0, stream>>>(h_h, Wl2, bl2, Wr2, br2, xlr3, N);
  k_edge3<<<(N + 255) / 256, 256, 0, stream>>>(xlr3, offs, csr_src, att2, b2,
                                               (float*)d_out, N);
}

// Round 12
// 229.749 us; speedup vs baseline: 2.7205x; 1.0046x over previous
//
#include <hip/hip_runtime.h>
#include <cstdint>
#include <cstddef>

// ---------------------------------------------------------------------------
// GATv2 3-layer forward on MI355X.
//   All GEMM operands fp16 (rel err 5e-4), fp32 accumulate MFMA.
//   k_gemm_mfma : tile 64x256, double-buffered global_load_lds staging with
//                 counted vmcnt (never 0 in loop), 32-bit addressing.
//   k_edge      : 2 nodes/wave, 8 ch/lane (quad per head), DPP quad_perm
//                 score reduce (no LDS-pipe shuffles), packed-fp16 VALU,
//                 2-edge pairwise merge online softmax.
// Graph CSR built once (device-wide scan), reused 3x.
// ---------------------------------------------------------------------------

typedef __attribute__((ext_vector_type(8))) _Float16 v8h;
typedef __attribute__((ext_vector_type(2))) _Float16 h2;
typedef __attribute__((ext_vector_type(2))) __fp16 h2r;  // intrinsic ret type
typedef __attribute__((ext_vector_type(4))) float v4f;

__device__ __forceinline__ float lrelu(float v) { return fmaxf(v, 0.2f * v); }
__device__ __forceinline__ float elu1(float v)  { return v > 0.f ? v : expm1f(v); }

__device__ __forceinline__ unsigned short f2h(float f) {
  _Float16 h = (_Float16)f;
  return __builtin_bit_cast(unsigned short, h);
}
__device__ __forceinline__ float h2f(unsigned short s) {
  return (float)__builtin_bit_cast(_Float16, s);
}

__device__ __forceinline__ h2 cvt_pk(float a, float b) {  // f32x2 -> half2
  h2r t = __builtin_amdgcn_cvt_pkrtz(a, b);
  return __builtin_bit_cast(h2, t);
}
__device__ __forceinline__ h2 pk2(float a) { return cvt_pk(a, a); }

// packed lrelu: lrelu(v) = 0.6*v + 0.4*|v|  (|.| is a bitwise AND on the pair)
__device__ __forceinline__ h2 lrelu_pk(h2 v) {
  unsigned int u = __builtin_bit_cast(unsigned int, v) & 0x7FFF7FFFu;
  h2 av = __builtin_bit_cast(h2, u);
  h2 c6 = {(_Float16)0.6f, (_Float16)0.6f};
  h2 c4 = {(_Float16)0.4f, (_Float16)0.4f};
  return v * c6 + av * c4;
}

__device__ __forceinline__ float dot2(h2 a, h2 b, float c) {
#if __has_builtin(__builtin_amdgcn_fdot2)
  return __builtin_amdgcn_fdot2(__builtin_bit_cast(h2r, a),
                                __builtin_bit_cast(h2r, b), c, false);
#else
  return fmaf((float)a[0], (float)b[0], fmaf((float)a[1], (float)b[1], c));
#endif
}

// quad reduce via DPP quad_perm (pure VALU, no LDS pipe)
__device__ __forceinline__ float quad_sum(float p) {
  int t1 = __builtin_amdgcn_update_dpp(0, __float_as_int(p), 0xB1, 0xF, 0xF, true);
  p += __int_as_float(t1);  // xor 1
  int t2 = __builtin_amdgcn_update_dpp(0, __float_as_int(p), 0x4E, 0xF, 0xF, true);
  p += __int_as_float(t2);  // xor 2
  return p;
}

__device__ __forceinline__ void gl_lds16(const void* g, void* l) {
  __builtin_amdgcn_global_load_lds(
      (const __attribute__((address_space(1))) unsigned int*)g,
      (__attribute__((address_space(3))) unsigned int*)l, 16, 0, 0);
}

// ---------------- CSR build ----------------

__global__ void k_count(const int* __restrict__ dst, int* __restrict__ deg, int E) {
  int e = blockIdx.x * blockDim.x + threadIdx.x;
  if (e < E) atomicAdd(&deg[dst[e]], 1);
}

__global__ __launch_bounds__(256) void k_bsum(const int* __restrict__ deg, int n,
                                              int* __restrict__ bsum) {
  __shared__ int red[256];
  int t = threadIdx.x, bid = blockIdx.x;
  int i0 = bid * 1024 + t * 4;
  int s = 0;
  if (i0 + 3 < n) {
    int4 v = *(const int4*)&deg[i0];
    s = v.x + v.y + v.z + v.w;
  } else {
#pragma unroll
    for (int j = 0; j < 4; ++j)
      if (i0 + j < n) s += deg[i0 + j];
  }
  red[t] = s;
  __syncthreads();
  for (int off = 128; off > 0; off >>= 1) {
    if (t < off) red[t] += red[t + off];
    __syncthreads();
  }
  if (t == 0) bsum[bid] = red[0];
}

__global__ __launch_bounds__(256) void k_offsets(const int* __restrict__ deg,
                                                 const int* __restrict__ bsum,
                                                 int nb, int n,
                                                 int* __restrict__ offs,
                                                 int* __restrict__ cursor) {
  __shared__ int sc[256];
  int t = threadIdx.x, bid = blockIdx.x;
  int base = 0;
  for (int b = 0; b < bid; ++b) base += bsum[b];
  int i0 = bid * 1024 + t * 4;
  int v0 = 0, v1 = 0, v2 = 0, v3 = 0;
  if (i0 + 3 < n) {
    int4 v = *(const int4*)&deg[i0];
    v0 = v.x; v1 = v.y; v2 = v.z; v3 = v.w;
  } else {
    if (i0 < n)     v0 = deg[i0];
    if (i0 + 1 < n) v1 = deg[i0 + 1];
    if (i0 + 2 < n) v2 = deg[i0 + 2];
    if (i0 + 3 < n) v3 = deg[i0 + 3];
  }
  int s = v0 + v1 + v2 + v3;
  sc[t] = s;
  __syncthreads();
  for (int off = 1; off < 256; off <<= 1) {
    int x = (t >= off) ? sc[t - off] : 0;
    __syncthreads();
    sc[t] += x;
    __syncthreads();
  }
  int run = base + sc[t] - s;
  int o0 = run, o1 = run + v0, o2 = o1 + v1, o3 = o2 + v2;
  if (i0 + 3 < n) {
    *(int4*)&offs[i0] = make_int4(o0, o1, o2, o3);
    *(int4*)&cursor[i0] = make_int4(o0, o1, o2, o3);
  } else {
    if (i0 < n)     { offs[i0] = o0;     cursor[i0] = o0; }
    if (i0 + 1 < n) { offs[i0 + 1] = o1; cursor[i0 + 1] = o1; }
    if (i0 + 2 < n) { offs[i0 + 2] = o2; cursor[i0 + 2] = o2; }
    if (i0 + 3 < n) { offs[i0 + 3] = o3; cursor[i0 + 3] = o3; }
  }
  if (bid == nb - 1 && t == 255) offs[n] = base + sc[255];
}

__global__ void k_scatter(const int* __restrict__ src, const int* __restrict__ dst,
                          int* __restrict__ cursor, int* __restrict__ csr_src, int E) {
  int e = blockIdx.x * blockDim.x + threadIdx.x;
  if (e < E) {
    int pos = atomicAdd(&cursor[dst[e]], 1);
    csr_src[pos] = src[e];
  }
}

// ---------------- weight transpose+quantize: Bt[n][k] = fp16(W[k][n]) -------

__global__ void k_split(const float* __restrict__ Wl, const float* __restrict__ Wr,
                        int K, int logK, unsigned short* __restrict__ Bt) {
  int idx = blockIdx.x * blockDim.x + threadIdx.x;
  if (idx >= 512 * K) return;
  int n = idx >> logK;
  int k = idx & (K - 1);
  float w = (n < 256) ? Wl[(size_t)k * 256 + n] : Wr[(size_t)k * 256 + (n - 256)];
  Bt[idx] = f2h(w);
}

// ---------------- input quantize: x[N,128] fp32 -> fp16 plane [Npad,128] ----

__global__ void k_quantA(const float* __restrict__ X, int Nreal, int total4,
                         unsigned short* __restrict__ Hh) {
  int idx = blockIdx.x * blockDim.x + threadIdx.x;  // 4 elems each
  if (idx >= total4) return;
  int row = idx >> 5;  // (idx*4)>>7, K=128
  ushort4 uh;
  if (row < Nreal) {
    float4 v = *(const float4*)&X[(size_t)idx * 4];
    uh.x = f2h(v.x); uh.y = f2h(v.y); uh.z = f2h(v.z); uh.w = f2h(v.w);
  } else {
    uh = make_ushort4(0, 0, 0, 0);
  }
  *(ushort4*)&Hh[(size_t)idx * 4] = uh;
}

// ---------------- fp16 MFMA GEMM, tile 64x256, double-buffered --------------

__global__ __launch_bounds__(256) void k_gemm_mfma(
    const unsigned short* __restrict__ A_g,  // [Npad,K] fp16
    int Nreal, int K,
    const unsigned short* __restrict__ Bt,   // [512,K] fp16 (transposed W)
    const float* __restrict__ bl, const float* __restrict__ br,
    unsigned short* __restrict__ xl_h, unsigned short* __restrict__ xr_h) {
  __shared__ __align__(16) short Ah[2][64 * 32];    // 8 KB
  __shared__ __align__(16) short Bh[2][256 * 32];   // 32 KB

  const int tid = threadIdx.x;
  const int lane = tid & 63;
  const int wid = tid >> 6;
  const int l15 = lane & 15, g = lane >> 4;
  const int bm = blockIdx.x * 64;
  const int half = blockIdx.y;           // 0: xl, 1: xr
  const int bn = half * 256;

  v4f acc[4][4];
#pragma unroll
  for (int m = 0; m < 4; ++m)
#pragma unroll
    for (int n = 0; n < 4; ++n) acc[m][n] = (v4f)(0.f);

  const int arow = tid >> 2, aslot = tid & 3;
  const int aoct = aslot ^ ((arow >> 1) & 3);
  const unsigned gaBase = (unsigned)(bm + arow) * K + aoct * 8;

  auto STAGE = [&](int buf, int k0) {
    gl_lds16(A_g + (gaBase + k0), &Ah[buf][wid * 512]);
#pragma unroll
    for (int it = 0; it < 4; ++it) {
      int task = it * 256 + tid;
      int col = task >> 2, slot = task & 3;
      int oct = slot ^ ((col >> 1) & 3);
      unsigned gb = (unsigned)(bn + col) * K + k0 + oct * 8;
      gl_lds16(Bt + gb, &Bh[buf][it * 2048 + wid * 512]);
    }
  };

  const int nt = K >> 5;
  STAGE(0, 0);
  for (int t = 0; t < nt; ++t) {
    const int cur = t & 1;
    if (t + 1 < nt) {
      STAGE(cur ^ 1, (t + 1) << 5);
      asm volatile("s_waitcnt vmcnt(5)" ::: "memory");  // cur's loads landed
    } else {
      asm volatile("s_waitcnt vmcnt(0)" ::: "memory");
    }
    __builtin_amdgcn_sched_barrier(0);
    __builtin_amdgcn_s_barrier();  // cur buf staged by ALL waves

    v8h a_h[4], b_h[4];
#pragma unroll
    for (int m = 0; m < 4; ++m) {
      int r = m * 16 + l15;
      int s = g ^ ((r >> 1) & 3);
      a_h[m] = *(const v8h*)&Ah[cur][r * 32 + s * 8];
    }
#pragma unroll
    for (int n = 0; n < 4; ++n) {
      int c = wid * 64 + n * 16 + l15;
      int s = g ^ ((c >> 1) & 3);
      b_h[n] = *(const v8h*)&Bh[cur][c * 32 + s * 8];
    }
#pragma unroll
    for (int m = 0; m < 4; ++m)
#pragma unroll
      for (int n = 0; n < 4; ++n)
        acc[m][n] = __builtin_amdgcn_mfma_f32_16x16x32_f16(a_h[m], b_h[n], acc[m][n], 0, 0, 0);
    __builtin_amdgcn_s_barrier();  // cur reads done before re-stage of cur
  }

  // ---- epilogue: per-wave LDS transpose (reuses Bh[0]), fp16 stores ----
  float* scr = (float*)&Bh[0][0] + wid * 320;  // 16 rows x stride 20 floats
  const int erow = lane >> 2, ecq = lane & 3;
  unsigned short* outp = half ? xr_h : xl_h;
  const float* bias = half ? br : bl;
#pragma unroll
  for (int m = 0; m < 4; ++m) {
#pragma unroll
    for (int n = 0; n < 4; ++n) {
#pragma unroll
      for (int r = 0; r < 4; ++r) scr[(g * 4 + r) * 20 + l15] = acc[m][n][r];
      float4 v = *(const float4*)&scr[erow * 20 + ecq * 4];
      int row = bm + m * 16 + erow;
      if (row < Nreal) {
        int col = wid * 64 + n * 16 + ecq * 4;
        float4 bv = *(const float4*)&bias[col];
        ushort4 u;
        u.x = f2h(v.x + bv.x); u.y = f2h(v.y + bv.y);
        u.z = f2h(v.z + bv.z); u.w = f2h(v.w + bv.w);
        *(ushort4*)&outp[(size_t)row * 256 + col] = u;
      }
    }
  }
}

// ---------------- fused GATv2 edge pass (H=8, C=32) -------------------------
// 2 nodes per wave (32 lanes each); lane: q=lane&3, head=(lane>>2)&7.
// Each lane owns 8 channels (head*32 + q*8). Score reduce = DPP quad_perm.

__global__ __launch_bounds__(256) void k_edge(
    const unsigned short* __restrict__ xl_h,  // [N,256] fp16
    const unsigned short* __restrict__ xr_h,  // [N,256] fp16
    const int* __restrict__ offs, const int* __restrict__ csr_src,
    const float* __restrict__ att,   // [8*32]
    const float* __restrict__ bias,  // [256]
    unsigned short* __restrict__ hout,  // [Npad,256] fp16
    int n) {
  int lane = threadIdx.x & 31;              // within 32-lane node group
  int node = blockIdx.x * (blockDim.x >> 5) + (threadIdx.x >> 5);
  if (node >= n) return;

  const unsigned cb = ((unsigned)(lane >> 2) << 5) + ((unsigned)(lane & 3) << 3);
  // att / bias for this lane's 8 channels
  float4 af0 = *(const float4*)&att[cb];
  float4 af1 = *(const float4*)&att[cb + 4];
  h2 att0 = cvt_pk(af0.x, af0.y), att1 = cvt_pk(af0.z, af0.w);
  h2 att2 = cvt_pk(af1.x, af1.y), att3 = cvt_pk(af1.z, af1.w);
  const unsigned noff = ((unsigned)node << 8) + cb;
  uint4 urx = *(const uint4*)(xr_h + noff);
  h2 xr0 = __builtin_bit_cast(h2, urx.x), xr1 = __builtin_bit_cast(h2, urx.y);
  h2 xr2 = __builtin_bit_cast(h2, urx.z), xr3 = __builtin_bit_cast(h2, urx.w);
  const unsigned short* xlb = xl_h + cb;  // lane-channel base

  auto score = [&](h2 a, h2 b, h2 c, h2 dd) -> float {
    float p = dot2(lrelu_pk(a + xr0), att0, 0.f);
    p = dot2(lrelu_pk(b + xr1), att1, p);
    p = dot2(lrelu_pk(c + xr2), att2, p);
    p = dot2(lrelu_pk(dd + xr3), att3, p);
    return quad_sum(p);
  };

  // self-loop as initial state: m = p_self, d = 1, acc = xl(node)
  uint4 us = *(const uint4*)(xl_h + noff);
  h2 a0 = __builtin_bit_cast(h2, us.x), a1 = __builtin_bit_cast(h2, us.y);
  h2 a2 = __builtin_bit_cast(h2, us.z), a3 = __builtin_bit_cast(h2, us.w);
  float m = score(a0, a1, a2, a3), d = 1.f;

  int e0 = offs[node], e1 = offs[node + 1];
  int e = e0;
  for (; e + 1 < e1; e += 2) {
    int j1 = csr_src[e], j2 = csr_src[e + 1];
    uint4 u1 = *(const uint4*)(xlb + ((unsigned)j1 << 8));
    uint4 u2 = *(const uint4*)(xlb + ((unsigned)j2 << 8));
    h2 x10 = __builtin_bit_cast(h2, u1.x), x11 = __builtin_bit_cast(h2, u1.y);
    h2 x12 = __builtin_bit_cast(h2, u1.z), x13 = __builtin_bit_cast(h2, u1.w);
    h2 x20 = __builtin_bit_cast(h2, u2.x), x21 = __builtin_bit_cast(h2, u2.y);
    h2 x22 = __builtin_bit_cast(h2, u2.z), x23 = __builtin_bit_cast(h2, u2.w);
    float p1 = score(x10, x11, x12, x13);
    float p2 = score(x20, x21, x22, x23);
    // pair-local softmax state
    float m12 = fmaxf(p1, p2);
    float w1 = __expf(p1 - m12), w2 = __expf(p2 - m12);
    float d12 = w1 + w2;
    h2 w1p = pk2(w1), w2p = pk2(w2);
    h2 c0 = x10 * w1p + x20 * w2p;
    h2 c1 = x11 * w1p + x21 * w2p;
    h2 c2 = x12 * w1p + x22 * w2p;
    h2 c3 = x13 * w1p + x23 * w2p;
    // merge into running state (branchless)
    float mN = fmaxf(m, m12);
    float r = __expf(m - mN), r2 = __expf(m12 - mN);
    d = fmaf(d, r, d12 * r2);
    h2 rp = pk2(r), r2p = pk2(r2);
    a0 = a0 * rp + c0 * r2p;
    a1 = a1 * rp + c1 * r2p;
    a2 = a2 * rp + c2 * r2p;
    a3 = a3 * rp + c3 * r2p;
    m = mN;
  }
  if (e < e1) {  // tail edge
    int j = csr_src[e];
    uint4 u = *(const uint4*)(xlb + ((unsigned)j << 8));
    h2 x0 = __builtin_bit_cast(h2, u.x), x1 = __builtin_bit_cast(h2, u.y);
    h2 x2 = __builtin_bit_cast(h2, u.z), x3 = __builtin_bit_cast(h2, u.w);
    float p1 = score(x0, x1, x2, x3);
    float mN = fmaxf(m, p1);
    float r = __expf(m - mN), w1 = __expf(p1 - mN);
    d = fmaf(d, r, w1);
    h2 rp = pk2(r), w1p = pk2(w1);
    a0 = a0 * rp + x0 * w1p;
    a1 = a1 * rp + x1 * w1p;
    a2 = a2 * rp + x2 * w1p;
    a3 = a3 * rp + x3 * w1p;
  }

  float inv = 1.f / (d + 1e-16f);
  float4 b0 = *(const float4*)&bias[cb];
  float4 b1 = *(const float4*)&bias[cb + 4];
  float o0 = elu1(fmaf((float)a0[0], inv, b0.x));
  float o1 = elu1(fmaf((float)a0[1], inv, b0.y));
  float o2 = elu1(fmaf((float)a1[0], inv, b0.z));
  float o3 = elu1(fmaf((float)a1[1], inv, b0.w));
  float o4 = elu1(fmaf((float)a2[0], inv, b1.x));
  float o5 = elu1(fmaf((float)a2[1], inv, b1.y));
  float o6 = elu1(fmaf((float)a3[0], inv, b1.z));
  float o7 = elu1(fmaf((float)a3[1], inv, b1.w));
  uint4 uo;
  uo.x = (unsigned)f2h(o0) | ((unsigned)f2h(o1) << 16);
  uo.y = (unsigned)f2h(o2) | ((unsigned)f2h(o3) << 16);
  uo.z = (unsigned)f2h(o4) | ((unsigned)f2h(o5) << 16);
  uo.w = (unsigned)f2h(o6) | ((unsigned)f2h(o7) << 16);
  *(uint4*)(hout + noff) = uo;
}

// ---------------- layer 3: skinny linear (256->2 twice), wave per node ------

__global__ __launch_bounds__(256) void k_lin3(
    const unsigned short* __restrict__ hq,
    const float* __restrict__ Wl, const float* __restrict__ bl,
    const float* __restrict__ Wr, const float* __restrict__ br,
    float* __restrict__ xlr3,  // [N,4] = {xl0,xl1,xr0,xr1}
    int n) {
  int lane = threadIdx.x & 63;
  int node = blockIdx.x * (blockDim.x >> 6) + (threadIdx.x >> 6);
  if (node >= n) return;
  ushort4 uh = *(const ushort4*)(hq + (((unsigned)node << 8) + (lane << 2)));
  float hv[4] = {h2f(uh.x), h2f(uh.y), h2f(uh.z), h2f(uh.w)};
  float al0 = 0.f, al1 = 0.f, ar0 = 0.f, ar1 = 0.f;
#pragma unroll
  for (int j = 0; j < 4; ++j) {
    int k = lane * 4 + j;
    al0 = fmaf(hv[j], Wl[k * 2 + 0], al0);
    al1 = fmaf(hv[j], Wl[k * 2 + 1], al1);
    ar0 = fmaf(hv[j], Wr[k * 2 + 0], ar0);
    ar1 = fmaf(hv[j], Wr[k * 2 + 1], ar1);
  }
#pragma unroll
  for (int s = 1; s < 64; s <<= 1) {
    al0 += __shfl_xor(al0, s);
    al1 += __shfl_xor(al1, s);
    ar0 += __shfl_xor(ar0, s);
    ar1 += __shfl_xor(ar1, s);
  }
  if (lane == 0) {
    float4 o = make_float4(al0 + bl[0], al1 + bl[1], ar0 + br[0], ar1 + br[1]);
    *(float4*)&xlr3[(size_t)node * 4] = o;
  }
}

// ---------------- layer 3 edge pass + log_softmax, thread per node ----------

__global__ void k_edge3(const float* __restrict__ xlr3,
                        const int* __restrict__ offs, const int* __restrict__ csr_src,
                        const float* __restrict__ att,  // [2]
                        const float* __restrict__ b,    // [2]
                        float* __restrict__ out, int n) {
  int i = blockIdx.x * blockDim.x + threadIdx.x;
  if (i >= n) return;
  float a0 = att[0], a1 = att[1];
  float xr0 = xlr3[(size_t)i * 4 + 2], xr1 = xlr3[(size_t)i * 4 + 3];
  // self-loop first
  float sl0 = xlr3[(size_t)i * 4 + 0], sl1 = xlr3[(size_t)i * 4 + 1];
  float m = lrelu(sl0 + xr0) * a0 + lrelu(sl1 + xr1) * a1;
  float d = 1.f, ac0 = sl0, ac1 = sl1;
  int e0 = offs[i], e1 = offs[i + 1];
  for (int e = e0; e < e1; ++e) {
    int j = csr_src[e];
    float xl0 = xlr3[(size_t)j * 4 + 0], xl1 = xlr3[(size_t)j * 4 + 1];
    float p = lrelu(xl0 + xr0) * a0 + lrelu(xl1 + xr1) * a1;
    float mN = fmaxf(m, p);
    float r = __expf(m - mN), w = __expf(p - mN);
    d = fmaf(d, r, w);
    ac0 = fmaf(ac0, r, w * xl0);
    ac1 = fmaf(ac1, r, w * xl1);
    m = mN;
  }
  float inv = 1.f / (d + 1e-16f);
  float o0 = fmaf(ac0, inv, b[0]);
  float o1 = fmaf(ac1, inv, b[1]);
  float mx = fmaxf(o0, o1);
  float lse = mx + logf(expf(o0 - mx) + expf(o1 - mx));
  out[(size_t)i * 2 + 0] = o0 - lse;
  out[(size_t)i * 2 + 1] = o1 - lse;
}

// ---------------------------------------------------------------------------

static inline size_t align_up(size_t v, size_t a) { return (v + a - 1) & ~(a - 1); }

extern "C" void kernel_launch(void* const* d_in, const int* in_sizes, int n_in,
                              void* d_out, int out_size, void* d_ws, size_t ws_size,
                              hipStream_t stream) {
  const float* x    = (const float*)d_in[0];
  const int*   ei   = (const int*)d_in[1];
  const float* Wl1  = (const float*)d_in[2];
  const float* bl1  = (const float*)d_in[3];
  const float* Wr1  = (const float*)d_in[4];
  const float* br1  = (const float*)d_in[5];
  const float* att1 = (const float*)d_in[6];
  const float* b1   = (const float*)d_in[7];
  const float* Wl3  = (const float*)d_in[8];
  const float* bl3  = (const float*)d_in[9];
  const float* Wr3  = (const float*)d_in[10];
  const float* br3  = (const float*)d_in[11];
  const float* att3 = (const float*)d_in[12];
  const float* b3   = (const float*)d_in[13];
  const float* Wl2  = (const float*)d_in[14];
  const float* bl2  = (const float*)d_in[15];
  const float* Wr2  = (const float*)d_in[16];
  const float* br2  = (const float*)d_in[17];
  const float* att2 = (const float*)d_in[18];
  const float* b2   = (const float*)d_in[19];

  const int N = in_sizes[0] / 128;  // 50000
  const int E = in_sizes[1] / 2;    // 400000
  const int Npad = ((N + 63) / 64) * 64;  // 50048
  const int* srcp = ei;
  const int* dstp = ei + E;

  // workspace layout
  char* w = (char*)d_ws;
  size_t off = 0;
  int* deg     = (int*)(w + off); off = align_up(off + (size_t)N * 4, 256);
  int* offs    = (int*)(w + off); off = align_up(off + (size_t)(N + 1) * 4, 256);
  int* cursor  = (int*)(w + off); off = align_up(off + (size_t)N * 4, 256);
  int* csr_src = (int*)(w + off); off = align_up(off + (size_t)E * 4, 256);
  int* bsum    = (int*)(w + off); off = align_up(off + (size_t)256 * 4, 256);
  unsigned short* x_h  = (unsigned short*)(w + off); off = align_up(off + (size_t)Npad * 128 * 2, 256);
  unsigned short* h_h  = (unsigned short*)(w + off); off = align_up(off + (size_t)Npad * 256 * 2, 256);
  unsigned short* xlh  = (unsigned short*)(w + off); off = align_up(off + (size_t)N * 256 * 2, 256);
  unsigned short* xrh  = (unsigned short*)(w + off); off = align_up(off + (size_t)N * 256 * 2, 256);
  float* xlr3  = (float*)(w + off); off = align_up(off + (size_t)N * 4 * 4, 256);
  unsigned short* Bt1 = (unsigned short*)(w + off); off = align_up(off + (size_t)512 * 128 * 2, 256);
  unsigned short* Bt2 = (unsigned short*)(w + off); off = align_up(off + (size_t)512 * 256 * 2, 256);
  (void)ws_size;

  const int nb = (N + 1023) / 1024;

  // ---- build CSR (incoming edges per dst), reused by all 3 layers ----
  hipMemsetAsync(deg, 0, (size_t)N * 4, stream);
  k_count<<<(E + 255) / 256, 256, 0, stream>>>(dstp, deg, E);
  k_bsum<<<nb, 256, 0, stream>>>(deg, N, bsum);
  k_offsets<<<nb, 256, 0, stream>>>(deg, bsum, nb, N, offs, cursor);
  k_scatter<<<(E + 255) / 256, 256, 0, stream>>>(srcp, dstp, cursor, csr_src, E);

  // ---- quantize weights (transposed) and x to fp16 ----
  k_split<<<(512 * 128 + 255) / 256, 256, 0, stream>>>(Wl1, Wr1, 128, 7, Bt1);
  k_split<<<(512 * 256 + 255) / 256, 256, 0, stream>>>(Wl3, Wr3, 256, 8, Bt2);
  {
    int total4 = Npad * 128 / 4;
    k_quantA<<<(total4 + 255) / 256, 256, 0, stream>>>(x, N, total4, x_h);
  }
  // zero pad rows of h plane (k_edge writes only rows < N)
  hipMemsetAsync(h_h + (size_t)N * 256, 0, (size_t)(Npad - N) * 256 * 2, stream);

  dim3 ggrid(Npad / 64, 2);
  int nodeBlocks = (N + 7) / 8;  // 8 nodes (32-lane groups) per 256-thread block

  // ---- layer 1: 128 -> 8x32, concat, ELU ----
  k_gemm_mfma<<<ggrid, 256, 0, stream>>>(x_h, N, 128, Bt1, bl1, br1, xlh, xrh);
  k_edge<<<nodeBlocks, 256, 0, stream>>>(xlh, xrh, offs, csr_src, att1, b1, h_h, N);

  // ---- layer 2: 256 -> 8x32, concat, ELU ----
  k_gemm_mfma<<<ggrid, 256, 0, stream>>>(h_h, N, 256, Bt2, bl3, br3, xlh, xrh);
  k_edge<<<nodeBlocks, 256, 0, stream>>>(xlh, xrh, offs, csr_src, att3, b3, h_h, N);

  // ---- layer 3: 256 -> 1x2, mean(=identity), log_softmax ----
  k_lin3<<<nodeBlocks * 2, 256, 0, stream>>>(h_h, Wl2, bl2, Wr2, br2, xlr3, N);
  k_edge3<<<(N + 255) / 256, 256, 0, stream>>>(xlr3, offs, csr_src, att2, b2,
                                               (float*)d_out, N);
}